// Round 1
// 733.455 us; speedup vs baseline: 1.0361x; 1.0361x over previous
//
#include <hip/hip_runtime.h>
#include <stdint.h>

#define AS1 __attribute__((address_space(1)))
#define AS3 __attribute__((address_space(3)))

typedef __bf16 bf16x8 __attribute__((ext_vector_type(8)));
typedef float f32x4 __attribute__((ext_vector_type(4)));

static __device__ __forceinline__ float bf2f(unsigned short u) {
    union { unsigned int i; float f; } x; x.i = ((unsigned int)u) << 16; return x.f;
}
static __device__ __forceinline__ unsigned short f2bf(float f) {
    union { float f; unsigned int i; } x; x.f = f;
    unsigned int u = x.i;
    unsigned int r = (u + 0x7fffu + ((u >> 16) & 1u)) >> 16;  // RNE
    return (unsigned short)r;
}

static __device__ __forceinline__ void gll16(const void* g, void* l) {
    __builtin_amdgcn_global_load_lds((const AS1 unsigned int*)g,
                                     (AS3 unsigned int*)l, 16, 0, 0);
}

// ---------------- f32 -> bf16 elementwise (vec4) ----------------
__global__ __launch_bounds__(256) void cvt_bf16_kernel(
    const float* __restrict__ src, unsigned short* __restrict__ dst, int n4) {
    int i = blockIdx.x * 256 + threadIdx.x;
    if (i >= n4) return;
    float4 v = ((const float4*)src)[i];
    ushort4 o;
    o.x = f2bf(v.x); o.y = f2bf(v.y); o.z = f2bf(v.z); o.w = f2bf(v.w);
    ((ushort4*)dst)[i] = o;
}

// ---------------- f32 [R,C] -> bf16 [C,R] transpose ----------------
__global__ __launch_bounds__(256) void transpose_cvt_kernel(
    const float* __restrict__ src, unsigned short* __restrict__ dst, int R, int C) {
    __shared__ float tile[32][33];
    int x = threadIdx.x & 31, y = threadIdx.x >> 5;
    int c0 = blockIdx.x * 32, r0 = blockIdx.y * 32;
#pragma unroll
    for (int i = 0; i < 4; i++)
        tile[y + i * 8][x] = src[(size_t)(r0 + y + i * 8) * C + (c0 + x)];
    __syncthreads();
#pragma unroll
    for (int i = 0; i < 4; i++)
        dst[(size_t)(c0 + y + i * 8) * R + (r0 + x)] = f2bf(tile[x][y + i * 8]);
}

// ---------------- 256x256 8-phase bf16 GEMM: C = A[M,K] * Bt[N,K]^T --------
// m201-class template (T2 st_16x32 LDS swizzle + T3/T4 counted-vmcnt 8-phase
// + T5 setprio). 512 thr = 8 waves (2M x 4N), BK=64, LDS 128 KiB:
//   A region [0,32768) u16 : slot(parity p, half h) = (p*2+h)*8192, each
//     half-tile = 128 rows x 64 k, stored as 16 subtiles [16][32] of 512 u16,
//     swizzled within subtile: u16off ^= ((u16off>>8)&1)<<4  (st_16x32).
//   B region [32768,65536) identical, n-major (Bt layout).
// Staging: global_load_lds writes LINEARLY (lane*16B); the st_16x32 swizzle is
// realized by inverse-swizzling the per-lane GLOBAL source address (rule #21).
// Schedule invariants (each verified against slot last-read phases):
//   phase1(q 0,0): ds A(qr0)+B(all);  stage A1(g+1)   [tenant A1(g-1): read g-1]
//   phase2(q 0,1):                    stage B0(g+2)   [tenant B0(g): read ph1]
//   phase3(q 1,0): ds A(qr1);         stage B1(g+2)   [tenant B1(g): read ph1]
//   phase4(q 1,1):                    stage A0(g+2)   [tenant A0(g): read ph3]
//   boundary s_waitcnt vmcnt(6) (3 half-tiles in flight) certifies K-tile g+1
//   complete: {A0,B0,B1}(g+1) staged in group g-1, A1(g+1) at ph1 of g.
// Prologue: 7 half-tiles (K0 full + B0,B1,A0 of K1) + vmcnt(6).
// MODE 0: bf16 store, grid 384 (48 n-tiles x 8 m-tiles, XCD-chunked).
// MODE 1: f32 partial store (split-K 4), grid 256 (zz = bid>>6).
template <int MODE>
__global__ __launch_bounds__(512, 2) void gemm256_kernel(
    const unsigned short* __restrict__ A, const unsigned short* __restrict__ Bt,
    void* __restrict__ C, int M, int N, int K, int Ksl) {
    __shared__ __align__(16) unsigned short SH[65536];  // 128 KiB
    int tid = threadIdx.x;
    int lane = tid & 63, w = tid >> 6;
    int wr = w >> 2, wc = w & 3;
    int qd = lane >> 4, rc = lane & 15;

    int m0, n0, zz = 0;
    if (MODE == 0) {
        int wg = blockIdx.x;                 // 384 = 8 XCD chunks of 48
        int xcd = wg & 7, loc = wg >> 3;
        m0 = (loc / 6) * 256;
        n0 = (xcd * 6 + loc % 6) * 256;
    } else {
        int wg = blockIdx.x;                 // 256 = 4 k-slices x 64 tiles
        zz = wg >> 6;
        int loc = wg & 63;
        m0 = (loc >> 3) * 256;
        n0 = (loc & 7) * 256;
    }
    const int NT = Ksl >> 6;                 // K-tiles in this slice (>= 3)
    const int sK = K << 7;                   // 128*K (u16 elems per half)

    // per-thread linear->logical stage mapping (inverse st_16x32 swizzle)
    size_t sr[2];
#pragma unroll
    for (int j = 0; j < 2; j++) {
        int bu = j * 4096 + tid * 8;         // u16 offset within half-tile
        int sub = bu >> 9;
        int b = bu & 511;
        int bp = b ^ (((b >> 8) & 1) << 4);
        int row = ((sub >> 1) << 4) + (bp >> 5);
        int col = ((sub & 1) << 5) + (bp & 31);
        sr[j] = (size_t)row * K + col;
    }
    const unsigned short* Ab = A + (size_t)m0 * K + (size_t)zz * Ksl;
    const unsigned short* Bb = Bt + (size_t)n0 * K + (size_t)zz * Ksl;

    // swizzled fragment read offset (u16): b = rc*32 + qd*8, bit8 = rc>>3
    const int foff = (rc * 32 + qd * 8) ^ (((rc >> 3) & 1) << 4);
    const int Ah = wr;           // this wave's A half
    const int Bh = wc >> 1;      // this wave's B half
    const int brow4 = (wc & 1) * 4;

    f32x4 acc[8][4];
#pragma unroll
    for (int i = 0; i < 8; i++)
#pragma unroll
        for (int j = 0; j < 4; j++)
#pragma unroll
            for (int r = 0; r < 4; r++) acc[i][j][r] = 0.f;

    bf16x8 aq[4][2], bq[4][2];

#define STG(mat, h, t)                                                        \
    {                                                                         \
        const unsigned short* s_ = ((mat) ? Bb : Ab) + (h) * sK + (t) * 64;   \
        int d_ = ((mat) << 15) + (((((t) & 1) * 2 + (h))) << 13) + tid * 8;   \
        gll16(s_ + sr[0], &SH[d_]);                                           \
        gll16(s_ + sr[1], &SH[d_ + 4096]);                                    \
    }

#define LDAQ(p, QR)                                                           \
    {                                                                         \
        int ab_ = ((p) * 2 + Ah) * 8192 + (QR) * 4096 + foff;                 \
        _Pragma("unroll") for (int fi = 0; fi < 4; fi++)                      \
            _Pragma("unroll") for (int ks = 0; ks < 2; ks++)                  \
                aq[fi][ks] = *(const bf16x8*)&SH[ab_ + (fi * 2 + ks) * 512];  \
    }

#define LDBQ(p)                                                               \
    {                                                                         \
        int bb_ = 32768 + ((p) * 2 + Bh) * 8192 + brow4 * 1024 + foff;        \
        _Pragma("unroll") for (int fg = 0; fg < 4; fg++)                      \
            _Pragma("unroll") for (int ks = 0; ks < 2; ks++)                  \
                bq[fg][ks] = *(const bf16x8*)&SH[bb_ + (fg * 2 + ks) * 512];  \
    }

#define MFMAQ(QR, QC)                                                         \
    {                                                                         \
        _Pragma("unroll") for (int fi = 0; fi < 4; fi++)                      \
            _Pragma("unroll") for (int fj = 0; fj < 2; fj++)                  \
                _Pragma("unroll") for (int ks = 0; ks < 2; ks++)              \
                    acc[(QR) * 4 + fi][(QC) * 2 + fj] =                       \
                        __builtin_amdgcn_mfma_f32_16x16x32_bf16(              \
                            aq[fi][ks], bq[(QC) * 2 + fj][ks],                \
                            acc[(QR) * 4 + fi][(QC) * 2 + fj], 0, 0, 0);      \
    }

#define FENCE asm volatile("" ::: "memory")
#define BARRIER { FENCE; __builtin_amdgcn_s_barrier(); FENCE; }
#define LGKM0 asm volatile("s_waitcnt lgkmcnt(0)" ::: "memory")

    // ---- prologue: K0 full + B0,B1,A0 of K1; 3 half-tiles left in flight
    STG(0, 0, 0); STG(0, 1, 0); STG(1, 0, 0); STG(1, 1, 0);
    STG(1, 0, 1); STG(1, 1, 1); STG(0, 0, 1);
    asm volatile("s_waitcnt vmcnt(6)" ::: "memory");
    BARRIER;

    for (int g = 0; g < NT; ++g) {
        const int p = g & 1;
        // phase 1: quadrant (0,0)
        LDAQ(p, 0);
        LDBQ(p);
        if (g + 1 < NT) STG(0, 1, g + 1);
        BARRIER; LGKM0;
        __builtin_amdgcn_s_setprio(1);
        MFMAQ(0, 0);
        __builtin_amdgcn_s_setprio(0);
        BARRIER;
        // phase 2: quadrant (0,1)
        if (g + 2 < NT) STG(1, 0, g + 2);
        BARRIER; LGKM0;
        __builtin_amdgcn_s_setprio(1);
        MFMAQ(0, 1);
        __builtin_amdgcn_s_setprio(0);
        BARRIER;
        // phase 3: quadrant (1,0)
        LDAQ(p, 1);
        if (g + 2 < NT) STG(1, 1, g + 2);
        BARRIER; LGKM0;
        __builtin_amdgcn_s_setprio(1);
        MFMAQ(1, 0);
        __builtin_amdgcn_s_setprio(0);
        BARRIER;
        // phase 4: quadrant (1,1) + K-tile boundary counted wait
        if (g + 2 < NT) STG(0, 0, g + 2);
        if (g < NT - 2) { asm volatile("s_waitcnt vmcnt(6)" ::: "memory"); }
        else            { asm volatile("s_waitcnt vmcnt(0)" ::: "memory"); }
        BARRIER; LGKM0;
        __builtin_amdgcn_s_setprio(1);
        MFMAQ(1, 1);
        __builtin_amdgcn_s_setprio(0);
        BARRIER;
    }

#undef STG
#undef LDAQ
#undef LDBQ
#undef MFMAQ
#undef FENCE
#undef BARRIER
#undef LGKM0

    if (MODE == 0) {
        unsigned short* Cp = (unsigned short*)C;
#pragma unroll
        for (int mi = 0; mi < 8; mi++) {
            int row = m0 + wr * 128 + mi * 16 + qd * 4;
#pragma unroll
            for (int fg = 0; fg < 4; fg++) {
                int col = n0 + wc * 64 + fg * 16 + rc;
#pragma unroll
                for (int r = 0; r < 4; r++)
                    Cp[(size_t)(row + r) * N + col] = f2bf(acc[mi][fg][r]);
            }
        }
    } else {
        float* Cf = (float*)C + (size_t)zz * M * N;
#pragma unroll
        for (int mi = 0; mi < 8; mi++) {
            int row = m0 + wr * 128 + mi * 16 + qd * 4;
#pragma unroll
            for (int fg = 0; fg < 4; fg++) {
                int col = n0 + wc * 64 + fg * 16 + rc;
#pragma unroll
                for (int r = 0; r < 4; r++)
                    Cf[(size_t)(row + r) * N + col] = acc[mi][fg][r];
            }
        }
    }
}

// ---------------- split-K partial sum: out = p[0]+p[1]+p[2]+p[3] ----------------
__global__ __launch_bounds__(256) void add_out4_kernel(
    const float* __restrict__ p, float* __restrict__ out, int n4) {
    int i = blockIdx.x * 256 + threadIdx.x;
    if (i >= n4) return;
    size_t st = (size_t)n4 * 4;
    float4 a = ((const float4*)p)[i];
    float4 b = ((const float4*)(p + st))[i];
    float4 c = ((const float4*)(p + 2 * st))[i];
    float4 d = ((const float4*)(p + 3 * st))[i];
    ((float4*)out)[i] = make_float4(a.x + b.x + c.x + d.x, a.y + b.y + c.y + d.y,
                                    a.z + b.z + c.z + d.z, a.w + b.w + c.w + d.w);
}

// ---------------- ba GEMM + beta/g computation ----------------
__global__ __launch_bounds__(256) void bag_kernel(
    const float* __restrict__ hs, const float* __restrict__ w_ba,
    const float* __restrict__ A_log, const float* __restrict__ dt_bias,
    float* __restrict__ gg, float* __restrict__ bb) {
    int w = threadIdx.x >> 6, lane = threadIdx.x & 63;
    int r0 = blockIdx.x * 8 + w * 2;
    const float* h0 = hs + (size_t)r0 * 2048;
    float a0 = 0.f, a1 = 0.f;
    for (int k = 0; k < 2048; k++) {
        float wv = w_ba[k * 64 + lane];
        a0 += h0[k] * wv;
        a1 += h0[2048 + k] * wv;
    }
    int h = lane >> 2, idx = lane & 3;
    int vh = h * 2 + (idx & 1);
    float accs[2] = {a0, a1};
#pragma unroll
    for (int j = 0; j < 2; j++) {
        int t = r0 + j;
        float acc = accs[j];
        if (idx < 2) {
            bb[t * 32 + vh] = 1.f / (1.f + expf(-acc));
        } else {
            float x = acc + dt_bias[vh];
            float sp = fmaxf(x, 0.f) + log1pf(expf(-fabsf(x)));
            gg[t * 32 + vh] = -expf(A_log[vh]) * sp;
        }
    }
}

// ---------------- depthwise causal conv(4) + silu + l2norm(q,k) ----------------
__global__ __launch_bounds__(256) void conv_kernel(
    const unsigned short* __restrict__ qkvz, const float* __restrict__ conv_w,
    unsigned short* __restrict__ qb, unsigned short* __restrict__ kb,
    float* __restrict__ vv) {
    __shared__ float xs[8192];
    __shared__ float rs[32];
    int t = blockIdx.x;
    int s = t & 1023;
    int tid = threadIdx.x;
    size_t rowbase = (size_t)t * 12288;
#pragma unroll
    for (int i = 0; i < 4; i++) {
        int c = (i * 256 + tid) * 8;
        int d = c & 127;
        int col;
        if (c < 2048) col = (c >> 7) * 768 + d;
        else if (c < 4096) col = ((c - 2048) >> 7) * 768 + 128 + d;
        else { int vh2 = (c - 4096) >> 7; col = (vh2 >> 1) * 768 + 256 + (vh2 & 1) * 128 + d; }
        float wts[8][4];
#pragma unroll
        for (int e = 0; e < 8; e++) {
            float4 t4 = *(const float4*)(conv_w + (size_t)(c + e) * 4);
            wts[e][0] = t4.x; wts[e][1] = t4.y; wts[e][2] = t4.z; wts[e][3] = t4.w;
        }
        float acc[8] = {0.f, 0.f, 0.f, 0.f, 0.f, 0.f, 0.f, 0.f};
#pragma unroll
        for (int j = 0; j < 4; j++) {
            int ss = s - 3 + j;
            if (ss >= 0) {
                uint4 u = *(const uint4*)(qkvz + rowbase + (size_t)(j - 3) * 12288 + col);
                const unsigned short* us = (const unsigned short*)&u;
#pragma unroll
                for (int e = 0; e < 8; e++) acc[e] += bf2f(us[e]) * wts[e][j];
            }
        }
#pragma unroll
        for (int e = 0; e < 8; e++) xs[c + e] = acc[e] / (1.f + expf(-acc[e]));
    }
    __syncthreads();
    {
        int seg = tid >> 3, part = tid & 7;
        const float* pp = xs + seg * 128 + part * 16;
        float s2 = 0.f;
#pragma unroll
        for (int j = 0; j < 16; j++) s2 += pp[j] * pp[j];
        s2 += __shfl_xor(s2, 1);
        s2 += __shfl_xor(s2, 2);
        s2 += __shfl_xor(s2, 4);
        if (part == 0) rs[seg] = rsqrtf(s2 + 1e-6f);
    }
    __syncthreads();
    const float QS = 0.08838834764831845f;  // 128^-0.5
#pragma unroll
    for (int i = 0; i < 4; i++) {
        int c = (i * 256 + tid) * 8;
        float x[8];
#pragma unroll
        for (int e = 0; e < 8; e++) x[e] = xs[c + e];
        if (c < 4096) {
            float sc = (c < 2048) ? rs[c >> 7] * QS : rs[((c - 2048) >> 7) + 16];
            uint4 o;
            o.x = (unsigned)f2bf(x[0] * sc) | ((unsigned)f2bf(x[1] * sc) << 16);
            o.y = (unsigned)f2bf(x[2] * sc) | ((unsigned)f2bf(x[3] * sc) << 16);
            o.z = (unsigned)f2bf(x[4] * sc) | ((unsigned)f2bf(x[5] * sc) << 16);
            o.w = (unsigned)f2bf(x[6] * sc) | ((unsigned)f2bf(x[7] * sc) << 16);
            if (c < 2048) *(uint4*)(qb + (size_t)t * 2048 + c) = o;
            else *(uint4*)(kb + (size_t)t * 2048 + c - 2048) = o;
        } else {
            float* vp = vv + (size_t)t * 4096 + c - 4096;
            *(float4*)vp = make_float4(x[0], x[1], x[2], x[3]);
            *(float4*)(vp + 4) = make_float4(x[4], x[5], x[6], x[7]);
        }
    }
}

// ---------------- delta-rule prep (parallel over 64 bh x 16 chunks) ----------------
__global__ __launch_bounds__(256, 2) void prep_kernel(
    const unsigned short* __restrict__ qb, const unsigned short* __restrict__ kb,
    const float* __restrict__ vv, const float* __restrict__ gg,
    const float* __restrict__ bb,
    unsigned short* __restrict__ Wg, unsigned short* __restrict__ DlT,
    unsigned short* __restrict__ KtT, unsigned short* __restrict__ Pt,
    float* __restrict__ lamg, float* __restrict__ l64g) {
    __shared__ __align__(16) unsigned short Tb[64 * 72];    // -beta_i E_ij A_ij (i>j)
    __shared__ __align__(16) unsigned short Xw[4][64 * 72]; // per-wave solutions [col][tok]
    __shared__ float Td[4 * 16 * 17];                       // +T diag blocks fp32
    __shared__ float RHSw[4][16 * 68];                      // per-wave stage scratch
    __shared__ float cc[64], bet[64], lam_s[64], ex64[64];

    int bid = blockIdx.x;            // bh*16 + ch
    int ch = bid & 15, bh = bid >> 4;
    int vh = bh & 31, b = bh >> 5;
    int hk = vh >> 1;
    int t0 = b * 1024 + ch * 64;
    int tid = threadIdx.x, wv = tid >> 6, lane = tid & 63;
    int qd = lane >> 4, rc = lane & 15;
    int rowb = (wv & 1) * 32;
    size_t obase = (size_t)bid * 8192;
    size_t pbase = (size_t)bid * 4096;

    // decay metadata (wave 0)
    if (tid < 64) {
        float x = gg[(size_t)(t0 + tid) * 32 + vh];
#pragma unroll
        for (int ofs = 1; ofs < 64; ofs <<= 1) {
            float up = __shfl_up(x, ofs, 64);
            if (tid >= ofs) x += up;
        }
        cc[tid] = x;
        float l = __expf(x);
        lam_s[tid] = l;
        float tot = __shfl(x, 63, 64);
        ex64[tid] = __expf(tot - x);
        bet[tid] = bb[(size_t)(t0 + tid) * 32 + vh];
        lamg[(size_t)bid * 64 + tid] = l;
        if (tid == 0) l64g[bid] = __expf(tot);
    }
    __syncthreads();

    // phase A: A = K K^T (waves 0,1) -> Tb/Td ; P = Q K^T (waves 2,3) -> Pt
    {
        const unsigned short* src = (wv >= 2) ? qb : kb;
        f32x4 acc[2][4];
#pragma unroll
        for (int tm = 0; tm < 2; tm++)
#pragma unroll
            for (int tn = 0; tn < 4; tn++)
#pragma unroll
                for (int r = 0; r < 4; r++) acc[tm][tn][r] = 0.f;
#pragma unroll
        for (int ks = 0; ks < 4; ks++) {
            bf16x8 af[2], bfr[4];
#pragma unroll
            for (int tm = 0; tm < 2; tm++) {
                int row = rowb + tm * 16 + rc;
                af[tm] = *(const bf16x8*)(src + ((size_t)(t0 + row) * 16 + hk) * 128 + ks * 32 + qd * 8);
            }
#pragma unroll
            for (int tn = 0; tn < 4; tn++)
                bfr[tn] = *(const bf16x8*)(kb + ((size_t)(t0 + tn * 16 + rc) * 16 + hk) * 128 + ks * 32 + qd * 8);
#pragma unroll
            for (int tm = 0; tm < 2; tm++)
#pragma unroll
                for (int tn = 0; tn < 4; tn++)
                    acc[tm][tn] = __builtin_amdgcn_mfma_f32_16x16x32_bf16(af[tm], bfr[tn], acc[tm][tn], 0, 0, 0);
        }
        if (wv < 2) {
#pragma unroll
            for (int tm = 0; tm < 2; tm++)
#pragma unroll
                for (int tn = 0; tn < 4; tn++)
#pragma unroll
                    for (int r = 0; r < 4; r++) {
                        int i = rowb + tm * 16 + qd * 4 + r;
                        int j = tn * 16 + rc;
                        float val = acc[tm][tn][r];
                        float tv = 0.f;
                        if (i > j) tv = bet[i] * __expf(cc[i] - cc[j]) * val;
                        Tb[i * 72 + j] = f2bf(-tv);
                        if ((i >> 4) == (j >> 4) && i > j)
                            Td[(i >> 4) * 272 + (i & 15) * 17 + (j & 15)] = tv;
                    }
        } else {
#pragma unroll
            for (int tm = 0; tm < 2; tm++)
#pragma unroll
                for (int tn = 0; tn < 4; tn++)
#pragma unroll
                    for (int r = 0; r < 4; r++) {
                        int i = rowb + tm * 16 + qd * 4 + r;
                        int j = tn * 16 + rc;
                        float ev = (i >= j) ? __expf(cc[i] - cc[j]) : 0.f;
                        Pt[pbase + i * 64 + j] = f2bf(ev * acc[tm][tn][r]);
                    }
        }
    }
    // KtT: Etil-folded K^T [dk][tok] straight from global (L2-hot)
    {
        int dk = tid >> 1, half = tid & 1;
#pragma unroll
        for (int j = 0; j < 4; j++) {
            unsigned short tmp[8];
#pragma unroll
            for (int e = 0; e < 8; e++) {
                int tok = half * 32 + j * 8 + e;
                tmp[e] = f2bf(bf2f(kb[((size_t)(t0 + tok) * 16 + hk) * 128 + dk]) * ex64[tok]);
            }
            *(uint4*)(KtT + obase + dk * 64 + half * 32 + j * 8) = *(const uint4*)tmp;
        }
    }
    __syncthreads();   // Tb/Td ready for all waves

    // per-wave forward substitution: wave wv owns col-batch cb = wv (64 cols)
    {
        int cb = wv;
        unsigned short* Xb = Xw[wv];
        float* RHS = RHSw[wv];
        for (int z = lane; z < 64 * 72 / 2; z += 64) ((unsigned int*)Xb)[z] = 0u;
#pragma unroll
        for (int B = 0; B < 4; B++) {
            f32x4 tacc[4];
#pragma unroll
            for (int cf = 0; cf < 4; cf++)
#pragma unroll
                for (int r = 0; r < 4; r++) {
                    int i = B * 16 + qd * 4 + r;
                    int c = cf * 16 + rc;
                    float v;
                    if (cb < 2)
                        v = bet[i] * vv[((size_t)(t0 + i) * 32 + vh) * 128 + cb * 64 + c];
                    else
                        v = bet[i] * lam_s[i] * bf2f(kb[((size_t)(t0 + i) * 16 + hk) * 128 + (cb - 2) * 64 + c]);
                    tacc[cf][r] = v;
                }
            __builtin_amdgcn_s_waitcnt(0xc07f);  // prior Xb writes (same wave) visible
            const int nks = (B + 1) >> 1;  // 0,1,1,2
#pragma unroll
            for (int ks = 0; ks < 2; ks++) {
                if (ks >= nks) break;
                bf16x8 af = *(const bf16x8*)&Tb[(B * 16 + rc) * 72 + ks * 32 + qd * 8];
#pragma unroll
                for (int cf = 0; cf < 4; cf++) {
                    bf16x8 bf_ = *(const bf16x8*)&Xb[(cf * 16 + rc) * 72 + ks * 32 + qd * 8];
                    tacc[cf] = __builtin_amdgcn_mfma_f32_16x16x32_bf16(af, bf_, tacc[cf], 0, 0, 0);
                }
            }
#pragma unroll
            for (int cf = 0; cf < 4; cf++)
#pragma unroll
                for (int r = 0; r < 4; r++)
                    RHS[(qd * 4 + r) * 68 + cf * 16 + rc] = tacc[cf][r];
            __builtin_amdgcn_s_waitcnt(0xc07f);  // RHS visible for transposed read
            {
                float d[16];
#pragma unroll
                for (int i2 = 0; i2 < 16; i2++) d[i2] = RHS[i2 * 68 + lane];
#pragma unroll
                for (int i2 = 1; i2 < 16; i2++)
#pragma unroll
                    for (int j2 = 0; j2 < i2; j2++)
                        d[i2] -= Td[B * 272 + i2 * 17 + j2] * d[j2];
#pragma unroll
                for (int i2 = 0; i2 < 16; i2++)
                    Xb[lane * 72 + B * 16 + i2] = f2bf(d[i2]);
            }
        }
        __builtin_amdgcn_s_waitcnt(0xc07f);
        // write out this wave's batch
        if (cb < 2) {  // Dloc^T rows [dv = cb*64+lane][tok]
#pragma unroll
            for (int j = 0; j < 8; j++) {
                uint4 u = *(const uint4*)&Xb[lane * 72 + j * 8];
                *(uint4*)(DlT + obase + (size_t)(cb * 64 + lane) * 64 + j * 8) = u;
            }
        } else {  // W rows [tok = lane][dk]: transpose from Xb
#pragma unroll
            for (int dq = 0; dq < 8; dq++) {
                unsigned short tmp[8];
#pragma unroll
                for (int e = 0; e < 8; e++)
                    tmp[e] = Xb[(dq * 8 + e) * 72 + lane];
                *(uint4*)(Wg + obase + (size_t)lane * 128 + (cb - 2) * 64 + dq * 8) = *(const uint4*)tmp;
            }
        }
    }
}

// ---------------- serial inter-chunk scan (lean) ----------------
__global__ __launch_bounds__(256, 2) void recb_kernel(
    const unsigned short* __restrict__ qb, const float* __restrict__ lamg,
    const float* __restrict__ l64g, const unsigned short* __restrict__ Wg,
    const unsigned short* __restrict__ DlT, const unsigned short* __restrict__ KtT,
    const unsigned short* __restrict__ Pt, float* __restrict__ oo) {
    __shared__ __align__(16) unsigned short St[16 * 136];  // S^T bf16 [dv][dk]
    __shared__ __align__(16) unsigned short Dls[16 * 72];  // Dloc^T -> D'^T slice
    int bid = blockIdx.x;
    int slice = bid >> 6;           // slice-major: same head -> same XCD
    int rest = bid & 63;
    int vh = rest & 31, b = rest >> 5;
    int bh = b * 32 + vh;
    int hk = vh >> 1, dvo = slice * 16, tb = b * 1024;
    int tid = threadIdx.x, wv = tid >> 6, lane = tid & 63;
    int qd = lane >> 4, rc = lane & 15;

    f32x4 sacc[2];
#pragma unroll
    for (int tm = 0; tm < 2; tm++)
#pragma unroll
        for (int r = 0; r < 4; r++) sacc[tm][r] = 0.f;
    for (int z = tid; z < 16 * 136 / 2; z += 256) ((unsigned int*)St)[z] = 0u;
    __syncthreads();

#pragma unroll 1
    for (int ch = 0; ch < 16; ch++) {
        int bhch = bh * 16 + ch;
        size_t obase = (size_t)bhch * 8192;
        size_t pbase = (size_t)bhch * 4096;
        int t0 = tb + ch * 64;
        if (tid < 128) {
            int row = tid >> 3, t8 = (tid & 7) * 8;
            uint4 u = *(const uint4*)(DlT + obase + (dvo + row) * 64 + t8);
            *(uint4*)&Dls[row * 72 + t8] = u;
        }
        __syncthreads();
        {
            f32x4 uacc;
#pragma unroll
            for (int r = 0; r < 4; r++) uacc[r] = 0.f;
#pragma unroll
            for (int ks = 0; ks < 4; ks++) {
                bf16x8 a_ = *(const bf16x8*)&St[rc * 136 + ks * 32 + qd * 8];
                bf16x8 b_ = *(const bf16x8*)(Wg + obase + (size_t)(wv * 16 + rc) * 128 + ks * 32 + qd * 8);
                uacc = __builtin_amdgcn_mfma_f32_16x16x32_bf16(a_, b_, uacc, 0, 0, 0);
            }
#pragma unroll
            for (int r = 0; r < 4; r++) {
                int idx = (qd * 4 + r) * 72 + wv * 16 + rc;
                Dls[idx] = f2bf(bf2f(Dls[idx]) - uacc[r]);
            }
        }
        __syncthreads();
        {
            f32x4 qacc;
#pragma unroll
            for (int r = 0; r < 4; r++) qacc[r] = 0.f;
#pragma unroll
            for (int ks = 0; ks < 4; ks++) {
                bf16x8 a_ = *(const bf16x8*)(qb + ((size_t)(t0 + wv * 16 + rc) * 16 + hk) * 128 + ks * 32 + qd * 8);
                bf16x8 b_ = *(const bf16x8*)&St[rc * 136 + ks * 32 + qd * 8];
                qacc = __builtin_amdgcn_mfma_f32_16x16x32_bf16(a_, b_, qacc, 0, 0, 0);
            }
            bf16x8 bd[2];
#pragma unroll
            for (int ks = 0; ks < 2; ks++)
                bd[ks] = *(const bf16x8*)&Dls[rc * 72 + ks * 32 + qd * 8];
            f32x4 oacc;
#pragma unroll
            for (int r = 0; r < 4; r++)
                oacc[r] = lamg[(size_t)bhch * 64 + wv * 16 + qd * 4 + r] * qacc[r];
#pragma unroll
            for (int ks = 0; ks < 2; ks++) {
                bf16x8 a_ = *(const bf16x8*)(Pt + pbase + (size_t)(wv * 16 + rc) * 64 + ks * 32 + qd * 8);
                oacc = __builtin_amdgcn_mfma_f32_16x16x32_bf16(a_, bd[ks], oacc, 0, 0, 0);
            }
#pragma unroll
            for (int r = 0; r < 4; r++)
                oo[((size_t)(t0 + wv * 16 + qd * 4 + r) * 32 + vh) * 128 + dvo + rc] = oacc[r];
            float l64 = l64g[bhch];
#pragma unroll
            for (int tm = 0; tm < 2; tm++) {
#pragma unroll
                for (int r = 0; r < 4; r++) sacc[tm][r] *= l64;
#pragma unroll
                for (int ks = 0; ks < 2; ks++) {
                    bf16x8 a_ = *(const bf16x8*)(KtT + obase + (size_t)(wv * 32 + tm * 16 + rc) * 64 + ks * 32 + qd * 8);
                    sacc[tm] = __builtin_amdgcn_mfma_f32_16x16x32_bf16(a_, bd[ks], sacc[tm], 0, 0, 0);
                }
            }
        }
        __syncthreads();
#pragma unroll
        for (int tm = 0; tm < 2; tm++)
#pragma unroll
            for (int r = 0; r < 4; r++)
                St[rc * 136 + wv * 32 + tm * 16 + qd * 4 + r] = f2bf(sacc[tm][r]);
        __syncthreads();
    }
}

// ---------------- gated RMSNorm + bf16 convert ----------------
__global__ __launch_bounds__(256) void norm_kernel(
    const float* __restrict__ oo, const unsigned short* __restrict__ qkvz,
    const float* __restrict__ norm_w, unsigned short* __restrict__ yb) {
    int w = threadIdx.x >> 6, lane = threadIdx.x & 63;
    int g = blockIdx.x * 4 + w;
    int t = g >> 5, vh = g & 31;
    size_t ob = (size_t)g * 128;
    size_t zb = (size_t)t * 12288 + (size_t)(vh >> 1) * 768 + 512 + (vh & 1) * 128;
    float x0 = oo[ob + lane], x1 = oo[ob + 64 + lane];
    float z0 = bf2f(qkvz[zb + lane]), z1 = bf2f(qkvz[zb + 64 + lane]);
    float xg0 = x0 * (z0 / (1.f + expf(-z0)));
    float xg1 = x1 * (z1 / (1.f + expf(-z1)));
    float s = xg0 * xg0 + xg1 * xg1;
    s += __shfl_xor(s, 1);
    s += __shfl_xor(s, 2);
    s += __shfl_xor(s, 4);
    s += __shfl_xor(s, 8);
    s += __shfl_xor(s, 16);
    s += __shfl_xor(s, 32);
    float r = rsqrtf(s * (1.f / 128.f) + 1e-6f);
    size_t y0 = (size_t)t * 4096 + (size_t)vh * 128;
    yb[y0 + lane] = f2bf(xg0 * r * norm_w[lane]);
    yb[y0 + 64 + lane] = f2bf(xg1 * r * norm_w[64 + lane]);
}

extern "C" void kernel_launch(void* const* d_in, const int* in_sizes, int n_in,
                              void* d_out, int out_size, void* d_ws, size_t ws_size,
                              hipStream_t stream) {
    const float* hs      = (const float*)d_in[0];
    const float* w_qkvz  = (const float*)d_in[1];
    const float* w_ba    = (const float*)d_in[2];
    const float* conv_w  = (const float*)d_in[3];
    const float* dt_bias = (const float*)d_in[4];
    const float* A_log   = (const float*)d_in[5];
    const float* norm_w  = (const float*)d_in[6];
    const float* w_out   = (const float*)d_in[7];
    float* out = (float*)d_out;
    (void)in_sizes; (void)n_in; (void)out_size; (void)ws_size;

    char* p = (char*)d_ws;
    auto alloc = [&](size_t b) { char* r = p; p += (b + 255) & ~(size_t)255; return r; };
    float* gg = (float*)alloc(2048ull * 32 * 4);                         // log-decay
    float* bb = (float*)alloc(2048ull * 32 * 4);                         // beta
    unsigned short* hsb  = (unsigned short*)alloc(2048ull * 2048 * 2);   // hs bf16
    unsigned short* woT  = (unsigned short*)alloc(2048ull * 4096 * 2);   // w_out^T bf16
    unsigned short* wqT  = (unsigned short*)alloc(12288ull * 2048 * 2);  // w_qkvz^T bf16
    unsigned short* qkvz = (unsigned short*)alloc(2048ull * 12288 * 2);  // projections bf16
    unsigned short* qb16 = (unsigned short*)alloc(2048ull * 2048 * 2);   // q normed bf16
    unsigned short* kb16 = (unsigned short*)alloc(2048ull * 2048 * 2);   // k normed bf16
    float* vv = (float*)alloc(2048ull * 4096 * 4);                       // v fp32
    float* oo = (float*)alloc(2048ull * 4096 * 4);                       // recurrence out
    unsigned short* yb = (unsigned short*)alloc(2048ull * 4096 * 2);     // normed bf16
    unsigned short* Wg  = (unsigned short*)alloc(1024ull * 8192 * 2);    // W [bhch][64][128]
    unsigned short* DlT = (unsigned short*)alloc(1024ull * 8192 * 2);    // Dloc^T [bhch][128][64]
    unsigned short* KtT = (unsigned short*)alloc(1024ull * 8192 * 2);    // Ktil^T [bhch][128][64]
    unsigned short* Pt  = (unsigned short*)alloc(1024ull * 4096 * 2);    // Ptil [bhch][64][64]
    float* lamg = (float*)alloc(1024ull * 64 * 4);                       // lambda per token
    float* l64g = (float*)alloc(1024ull * 4);                            // chunk decay
    // gemm2 split-K-4 partials (4 x 16.78 MB = 67.1 MB) reuse wqT (48 MB, dead
    // after gemm1) + head of qkvz (48 MB, dead after norm_kernel) — contiguous
    // because woT is allocated BEFORE wqT.
    float* gpart = (float*)wqT;

    cvt_bf16_kernel<<<4096, 256, 0, stream>>>(hs, hsb, 2048 * 2048 / 4);
    transpose_cvt_kernel<<<dim3(12288 / 32, 2048 / 32), 256, 0, stream>>>(w_qkvz, wqT, 2048, 12288);
    transpose_cvt_kernel<<<dim3(2048 / 32, 4096 / 32), 256, 0, stream>>>(w_out, woT, 4096, 2048);
    gemm256_kernel<0><<<384, 512, 0, stream>>>(hsb, wqT, qkvz, 2048, 12288, 2048, 2048);
    bag_kernel<<<256, 256, 0, stream>>>(hs, w_ba, A_log, dt_bias, gg, bb);
    conv_kernel<<<2048, 256, 0, stream>>>(qkvz, conv_w, qb16, kb16, vv);
    prep_kernel<<<1024, 256, 0, stream>>>(qb16, kb16, vv, gg, bb, Wg, DlT, KtT, Pt, lamg, l64g);
    recb_kernel<<<512, 256, 0, stream>>>(qb16, lamg, l64g, Wg, DlT, KtT, Pt, oo);
    norm_kernel<<<16384, 256, 0, stream>>>(oo, qkvz, norm_w, yb);
    gemm256_kernel<1><<<256, 512, 0, stream>>>(yb, woT, gpart, 2048, 2048, 4096, 1024);
    add_out4_kernel<<<4096, 256, 0, stream>>>(gpart, out, 2048 * 2048 / 4);
}

// Round 3
// 719.584 us; speedup vs baseline: 1.0561x; 1.0193x over previous
//
#include <hip/hip_runtime.h>
#include <stdint.h>

#define AS1 __attribute__((address_space(1)))
#define AS3 __attribute__((address_space(3)))

typedef __bf16 bf16x8 __attribute__((ext_vector_type(8)));
typedef float f32x4 __attribute__((ext_vector_type(4)));

static __device__ __forceinline__ float bf2f(unsigned short u) {
    union { unsigned int i; float f; } x; x.i = ((unsigned int)u) << 16; return x.f;
}
static __device__ __forceinline__ unsigned short f2bf(float f) {
    union { float f; unsigned int i; } x; x.f = f;
    unsigned int u = x.i;
    unsigned int r = (u + 0x7fffu + ((u >> 16) & 1u)) >> 16;  // RNE
    return (unsigned short)r;
}

static __device__ __forceinline__ void gll16(const void* g, void* l) {
    __builtin_amdgcn_global_load_lds((const AS1 unsigned int*)g,
                                     (AS3 unsigned int*)l, 16, 0, 0);
}

// ---------------- f32 -> bf16 elementwise (vec4) ----------------
__global__ __launch_bounds__(256) void cvt_bf16_kernel(
    const float* __restrict__ src, unsigned short* __restrict__ dst, int n4) {
    int i = blockIdx.x * 256 + threadIdx.x;
    if (i >= n4) return;
    float4 v = ((const float4*)src)[i];
    ushort4 o;
    o.x = f2bf(v.x); o.y = f2bf(v.y); o.z = f2bf(v.z); o.w = f2bf(v.w);
    ((ushort4*)dst)[i] = o;
}

// ---------------- f32 [R,C] -> bf16 [C,R] transpose ----------------
__global__ __launch_bounds__(256) void transpose_cvt_kernel(
    const float* __restrict__ src, unsigned short* __restrict__ dst, int R, int C) {
    __shared__ float tile[32][33];
    int x = threadIdx.x & 31, y = threadIdx.x >> 5;
    int c0 = blockIdx.x * 32, r0 = blockIdx.y * 32;
#pragma unroll
    for (int i = 0; i < 4; i++)
        tile[y + i * 8][x] = src[(size_t)(r0 + y + i * 8) * C + (c0 + x)];
    __syncthreads();
#pragma unroll
    for (int i = 0; i < 4; i++)
        dst[(size_t)(c0 + y + i * 8) * R + (r0 + x)] = f2bf(tile[x][y + i * 8]);
}

#define FENCE asm volatile("" ::: "memory")
#define BARRIER { FENCE; __builtin_amdgcn_s_barrier(); FENCE; }
#define LGKM0 asm volatile("s_waitcnt lgkmcnt(0)" ::: "memory")

// ---------------- 128x384 8-phase bf16 GEMM: C = A[M,K] * Bt[N,K]^T --------
// m201-class schedule retiled so gemm1's grid is 16 x 32 = 512 tiles =
// EXACTLY 2 full rounds on 256 CUs (256^2 had 384 tiles = 1.5 rounds).
// Half-tile unit: 128 rows x 64 k = 16 KB, 16 subtiles [16][32], st_16x32
// swizzle (u16off ^= ((u16off>>8)&1)<<4), staged linearly by global_load_lds
// with inverse-swizzled global source (rule #21).
// LDS = 8 slots x 16 KB = 128 KiB: slot(u,p) at (u*2+p)*16 KB,
//   u=0: A (128 rows), u=1..3: B0/B1/B2 (384 n-rows).
// Per K-tile (BK=64): 4 stages, one per phase:
//   ph1 (Q 0,0): ds aq(QR0)+bq(all 6);  stage A(g+1)
//   ph2 (Q 0,1):                        stage B0(g+2)
//   ph3 (Q 1,0): ds aq(QR1);            stage B1(g+2)
//   ph4 (Q 1,1): stage B2(g+2); boundary s_waitcnt vmcnt(6)
// B slots are only ds-read in ph1 (all 6 frags -> regs), so B(g+2) stages
// (same parity as g) issue safely after ph1's closing barrier. A(g+1) is
// opposite parity to the A(g) reads in ph1/ph3. vmcnt(6) = 3 stages in
// flight certifies tile g+1 complete (identical count to the 256^2 proof).
// 8 waves as 2(m) x 4(n): wave tile 64 x 96, acc[4][6], 12 MFMA/phase.
__global__ __launch_bounds__(512, 2) void gemm384_kernel(
    const unsigned short* __restrict__ A, const unsigned short* __restrict__ Bt,
    unsigned short* __restrict__ C, int M, int N, int K) {
    __shared__ __align__(16) unsigned short SH[65536];  // 128 KiB
    int tid = threadIdx.x;
    int lane = tid & 63, w = tid >> 6;
    int wr = w >> 2, wc = w & 3;
    int qd = lane >> 4, rc = lane & 15;

    int wg = blockIdx.x;                 // 512 = 8 xcd * (16 m * 4 nsub)
    int xcd = wg & 7, loc = wg >> 3;
    int m0 = (loc & 15) * 128;
    int n0 = (xcd * 4 + (loc >> 4)) * 384;

    const int NT = K >> 6;               // K-tiles
    const int sK = K << 7;               // u16 elems per 128-row half-tile

    // per-thread linear->logical stage mapping (inverse st_16x32 swizzle)
    size_t sr[2];
#pragma unroll
    for (int j = 0; j < 2; j++) {
        int bu = j * 4096 + tid * 8;     // u16 offset within half-tile
        int sub = bu >> 9;
        int b = bu & 511;
        int bp = b ^ (((b >> 8) & 1) << 4);
        int row = ((sub >> 1) << 4) + (bp >> 5);
        int col = ((sub & 1) << 5) + (bp & 31);
        sr[j] = (size_t)row * K + col;
    }
    const unsigned short* Ab = A + (size_t)m0 * K;
    const unsigned short* Bb = Bt + (size_t)n0 * K;

    const int foff = (rc * 32 + qd * 8) ^ (((rc >> 3) & 1) << 4);
    // per-fragment B base (u16): which B half-tile slot + rowgroup + swizzle
    int bC[6];
#pragma unroll
    for (int fj = 0; fj < 6; fj++) {
        int nb = wc * 96 + fj * 16;
        bC[fj] = (1 + (nb >> 7)) * 16384 + ((nb & 127) >> 4) * 1024 + foff;
    }

    f32x4 acc[4][6];
#pragma unroll
    for (int i = 0; i < 4; i++)
#pragma unroll
        for (int j = 0; j < 6; j++)
#pragma unroll
            for (int r = 0; r < 4; r++) acc[i][j][r] = 0.f;

    bf16x8 aq[2][2], bq[6][2];

#define STG(u, t)                                                             \
    {                                                                         \
        const unsigned short* s_ =                                            \
            ((u) == 0 ? Ab : Bb + (size_t)((u)-1) * sK) + (size_t)(t) * 64;   \
        int d_ = (((u)*2 + ((t)&1)) << 13) + tid * 8;                         \
        gll16(s_ + sr[0], &SH[d_]);                                           \
        gll16(s_ + sr[1], &SH[d_ + 4096]);                                    \
    }

#define LDAQ(p, QR)                                                           \
    {                                                                         \
        _Pragma("unroll") for (int fi = 0; fi < 2; fi++)                      \
            _Pragma("unroll") for (int ks = 0; ks < 2; ks++)                  \
                aq[fi][ks] = *(const bf16x8*)&SH[(p)*8192 +                   \
                    (wr * 4 + (QR)*2 + fi) * 1024 + ks * 512 + foff];         \
    }

#define LDBQ(p)                                                               \
    {                                                                         \
        _Pragma("unroll") for (int fj = 0; fj < 6; fj++)                      \
            _Pragma("unroll") for (int ks = 0; ks < 2; ks++)                  \
                bq[fj][ks] = *(const bf16x8*)&SH[bC[fj] + (p)*8192 + ks*512]; \
    }

#define MFMAQ(QR, QC)                                                         \
    {                                                                         \
        _Pragma("unroll") for (int fi = 0; fi < 2; fi++)                      \
            _Pragma("unroll") for (int fj = 0; fj < 3; fj++)                  \
                _Pragma("unroll") for (int ks = 0; ks < 2; ks++)              \
                    acc[(QR)*2 + fi][(QC)*3 + fj] =                           \
                        __builtin_amdgcn_mfma_f32_16x16x32_bf16(              \
                            aq[fi][ks], bq[(QC)*3 + fj][ks],                  \
                            acc[(QR)*2 + fi][(QC)*3 + fj], 0, 0, 0);          \
    }

    // ---- prologue: tile0 full + B0,B1,B2 of tile1; 3 stages left in flight
    STG(0, 0); STG(1, 0); STG(2, 0); STG(3, 0);
    STG(1, 1); STG(2, 1); STG(3, 1);
    asm volatile("s_waitcnt vmcnt(6)" ::: "memory");
    BARRIER;

    for (int g = 0; g < NT; ++g) {
        const int p = g & 1;
        // phase 1: quadrant (0,0)
        LDAQ(p, 0);
        LDBQ(p);
        if (g + 1 < NT) STG(0, g + 1);
        BARRIER; LGKM0;
        __builtin_amdgcn_s_setprio(1);
        MFMAQ(0, 0);
        __builtin_amdgcn_s_setprio(0);
        BARRIER;
        // phase 2: quadrant (0,1)
        if (g + 2 < NT) STG(1, g + 2);
        BARRIER; LGKM0;
        __builtin_amdgcn_s_setprio(1);
        MFMAQ(0, 1);
        __builtin_amdgcn_s_setprio(0);
        BARRIER;
        // phase 3: quadrant (1,0)
        LDAQ(p, 1);
        if (g + 2 < NT) STG(2, g + 2);
        BARRIER; LGKM0;
        __builtin_amdgcn_s_setprio(1);
        MFMAQ(1, 0);
        __builtin_amdgcn_s_setprio(0);
        BARRIER;
        // phase 4: quadrant (1,1) + K-tile boundary counted wait
        if (g + 2 < NT) STG(3, g + 2);
        if (g < NT - 2) { asm volatile("s_waitcnt vmcnt(6)" ::: "memory"); }
        else            { asm volatile("s_waitcnt vmcnt(0)" ::: "memory"); }
        BARRIER; LGKM0;
        __builtin_amdgcn_s_setprio(1);
        MFMAQ(1, 1);
        __builtin_amdgcn_s_setprio(0);
        BARRIER;
    }

#undef STG
#undef LDAQ
#undef LDBQ
#undef MFMAQ

#pragma unroll
    for (int mi = 0; mi < 4; mi++) {
        int row = m0 + wr * 64 + mi * 16 + qd * 4;
#pragma unroll
        for (int fj = 0; fj < 6; fj++) {
            int col = n0 + wc * 96 + fj * 16 + rc;
#pragma unroll
            for (int r = 0; r < 4; r++)
                C[(size_t)(row + r) * N + col] = f2bf(acc[mi][fj][r]);
        }
    }
}

// ---------------- 256x256 8-phase bf16 GEMM, split-K f32 partials ----------
// (unchanged verified schedule; used for gemm2: grid 256 = 4 k-slices x 64
// tiles = exactly one full round)
__global__ __launch_bounds__(512, 2) void gemm256_kernel(
    const unsigned short* __restrict__ A, const unsigned short* __restrict__ Bt,
    float* __restrict__ C, int M, int N, int K, int Ksl) {
    __shared__ __align__(16) unsigned short SH[65536];  // 128 KiB
    int tid = threadIdx.x;
    int lane = tid & 63, w = tid >> 6;
    int wr = w >> 2, wc = w & 3;
    int qd = lane >> 4, rc = lane & 15;

    int wg = blockIdx.x;                 // 256 = 4 k-slices x 64 tiles
    int zz = wg >> 6;
    int loc = wg & 63;
    int m0 = (loc >> 3) * 256;
    int n0 = (loc & 7) * 256;
    const int NT = Ksl >> 6;
    const int sK = K << 7;

    size_t sr[2];
#pragma unroll
    for (int j = 0; j < 2; j++) {
        int bu = j * 4096 + tid * 8;
        int sub = bu >> 9;
        int b = bu & 511;
        int bp = b ^ (((b >> 8) & 1) << 4);
        int row = ((sub >> 1) << 4) + (bp >> 5);
        int col = ((sub & 1) << 5) + (bp & 31);
        sr[j] = (size_t)row * K + col;
    }
    const unsigned short* Ab = A + (size_t)m0 * K + (size_t)zz * Ksl;
    const unsigned short* Bb = Bt + (size_t)n0 * K + (size_t)zz * Ksl;

    const int foff = (rc * 32 + qd * 8) ^ (((rc >> 3) & 1) << 4);
    const int Ah = wr;
    const int Bh = wc >> 1;
    const int brow4 = (wc & 1) * 4;

    f32x4 acc[8][4];
#pragma unroll
    for (int i = 0; i < 8; i++)
#pragma unroll
        for (int j = 0; j < 4; j++)
#pragma unroll
            for (int r = 0; r < 4; r++) acc[i][j][r] = 0.f;

    bf16x8 aq[4][2], bq[4][2];

#define STG(mat, h, t)                                                        \
    {                                                                         \
        const unsigned short* s_ = ((mat) ? Bb : Ab) + (h) * sK + (t) * 64;   \
        int d_ = ((mat) << 15) + (((((t) & 1) * 2 + (h))) << 13) + tid * 8;   \
        gll16(s_ + sr[0], &SH[d_]);                                           \
        gll16(s_ + sr[1], &SH[d_ + 4096]);                                    \
    }

#define LDAQ(p, QR)                                                           \
    {                                                                         \
        int ab_ = ((p) * 2 + Ah) * 8192 + (QR) * 4096 + foff;                 \
        _Pragma("unroll") for (int fi = 0; fi < 4; fi++)                      \
            _Pragma("unroll") for (int ks = 0; ks < 2; ks++)                  \
                aq[fi][ks] = *(const bf16x8*)&SH[ab_ + (fi * 2 + ks) * 512];  \
    }

#define LDBQ(p)                                                               \
    {                                                                         \
        int bb_ = 32768 + ((p) * 2 + Bh) * 8192 + brow4 * 1024 + foff;        \
        _Pragma("unroll") for (int fg = 0; fg < 4; fg++)                      \
            _Pragma("unroll") for (int ks = 0; ks < 2; ks++)                  \
                bq[fg][ks] = *(const bf16x8*)&SH[bb_ + (fg * 2 + ks) * 512];  \
    }

#define MFMAQ(QR, QC)                                                         \
    {                                                                         \
        _Pragma("unroll") for (int fi = 0; fi < 4; fi++)                      \
            _Pragma("unroll") for (int fj = 0; fj < 2; fj++)                  \
                _Pragma("unroll") for (int ks = 0; ks < 2; ks++)              \
                    acc[(QR) * 4 + fi][(QC) * 2 + fj] =                       \
                        __builtin_amdgcn_mfma_f32_16x16x32_bf16(              \
                            aq[fi][ks], bq[(QC) * 2 + fj][ks],                \
                            acc[(QR) * 4 + fi][(QC) * 2 + fj], 0, 0, 0);      \
    }

    STG(0, 0, 0); STG(0, 1, 0); STG(1, 0, 0); STG(1, 1, 0);
    STG(1, 0, 1); STG(1, 1, 1); STG(0, 0, 1);
    asm volatile("s_waitcnt vmcnt(6)" ::: "memory");
    BARRIER;

    for (int g = 0; g < NT; ++g) {
        const int p = g & 1;
        LDAQ(p, 0);
        LDBQ(p);
        if (g + 1 < NT) STG(0, 1, g + 1);
        BARRIER; LGKM0;
        __builtin_amdgcn_s_setprio(1);
        MFMAQ(0, 0);
        __builtin_amdgcn_s_setprio(0);
        BARRIER;
        if (g + 2 < NT) STG(1, 0, g + 2);
        BARRIER; LGKM0;
        __builtin_amdgcn_s_setprio(1);
        MFMAQ(0, 1);
        __builtin_amdgcn_s_setprio(0);
        BARRIER;
        LDAQ(p, 1);
        if (g + 2 < NT) STG(1, 1, g + 2);
        BARRIER; LGKM0;
        __builtin_amdgcn_s_setprio(1);
        MFMAQ(1, 0);
        __builtin_amdgcn_s_setprio(0);
        BARRIER;
        if (g + 2 < NT) STG(0, 0, g + 2);
        if (g < NT - 2) { asm volatile("s_waitcnt vmcnt(6)" ::: "memory"); }
        else            { asm volatile("s_waitcnt vmcnt(0)" ::: "memory"); }
        BARRIER; LGKM0;
        __builtin_amdgcn_s_setprio(1);
        MFMAQ(1, 1);
        __builtin_amdgcn_s_setprio(0);
        BARRIER;
    }

#undef STG
#undef LDAQ
#undef LDBQ
#undef MFMAQ

    float* Cf = C + (size_t)zz * M * N;
#pragma unroll
    for (int mi = 0; mi < 8; mi++) {
        int row = m0 + wr * 128 + mi * 16 + qd * 4;
#pragma unroll
        for (int fg = 0; fg < 4; fg++) {
            int col = n0 + wc * 64 + fg * 16 + rc;
#pragma unroll
            for (int r = 0; r < 4; r++)
                Cf[(size_t)(row + r) * N + col] = acc[mi][fg][r];
        }
    }
}

// ---------------- split-K partial sum: out = p[0]+p[1]+p[2]+p[3] ----------------
__global__ __launch_bounds__(256) void add_out4_kernel(
    const float* __restrict__ p, float* __restrict__ out, int n4) {
    int i = blockIdx.x * 256 + threadIdx.x;
    if (i >= n4) return;
    size_t st = (size_t)n4 * 4;
    float4 a = ((const float4*)p)[i];
    float4 b = ((const float4*)(p + st))[i];
    float4 c = ((const float4*)(p + 2 * st))[i];
    float4 d = ((const float4*)(p + 3 * st))[i];
    ((float4*)out)[i] = make_float4(a.x + b.x + c.x + d.x, a.y + b.y + c.y + d.y,
                                    a.z + b.z + c.z + d.z, a.w + b.w + c.w + d.w);
}

// ---------------- ba GEMM + beta/g computation ----------------
__global__ __launch_bounds__(256) void bag_kernel(
    const float* __restrict__ hs, const float* __restrict__ w_ba,
    const float* __restrict__ A_log, const float* __restrict__ dt_bias,
    float* __restrict__ gg, float* __restrict__ bb) {
    int w = threadIdx.x >> 6, lane = threadIdx.x & 63;
    int r0 = blockIdx.x * 8 + w * 2;
    const float* h0 = hs + (size_t)r0 * 2048;
    float a0 = 0.f, a1 = 0.f;
    for (int k = 0; k < 2048; k++) {
        float wv = w_ba[k * 64 + lane];
        a0 += h0[k] * wv;
        a1 += h0[2048 + k] * wv;
    }
    int h = lane >> 2, idx = lane & 3;
    int vh = h * 2 + (idx & 1);
    float accs[2] = {a0, a1};
#pragma unroll
    for (int j = 0; j < 2; j++) {
        int t = r0 + j;
        float acc = accs[j];
        if (idx < 2) {
            bb[t * 32 + vh] = 1.f / (1.f + expf(-acc));
        } else {
            float x = acc + dt_bias[vh];
            float sp = fmaxf(x, 0.f) + log1pf(expf(-fabsf(x)));
            gg[t * 32 + vh] = -expf(A_log[vh]) * sp;
        }
    }
}

// ---------------- depthwise causal conv(4) + silu + l2norm(q,k) ----------------
// blockIdx remapped so each XCD owns a contiguous 256-token span: the 3-row
// causal re-read of qkvz then hits the local L2 instead of re-fetching HBM.
__global__ __launch_bounds__(256) void conv_kernel(
    const unsigned short* __restrict__ qkvz, const float* __restrict__ conv_w,
    unsigned short* __restrict__ qb, unsigned short* __restrict__ kb,
    float* __restrict__ vv) {
    __shared__ float xs[8192];
    __shared__ float rs[32];
    int t = ((blockIdx.x & 7) << 8) + (blockIdx.x >> 3);  // XCD-chunked
    int s = t & 1023;
    int tid = threadIdx.x;
    size_t rowbase = (size_t)t * 12288;
#pragma unroll
    for (int i = 0; i < 4; i++) {
        int c = (i * 256 + tid) * 8;
        int d = c & 127;
        int col;
        if (c < 2048) col = (c >> 7) * 768 + d;
        else if (c < 4096) col = ((c - 2048) >> 7) * 768 + 128 + d;
        else { int vh2 = (c - 4096) >> 7; col = (vh2 >> 1) * 768 + 256 + (vh2 & 1) * 128 + d; }
        float wts[8][4];
#pragma unroll
        for (int e = 0; e < 8; e++) {
            float4 t4 = *(const float4*)(conv_w + (size_t)(c + e) * 4);
            wts[e][0] = t4.x; wts[e][1] = t4.y; wts[e][2] = t4.z; wts[e][3] = t4.w;
        }
        float acc[8] = {0.f, 0.f, 0.f, 0.f, 0.f, 0.f, 0.f, 0.f};
#pragma unroll
        for (int j = 0; j < 4; j++) {
            int ss = s - 3 + j;
            if (ss >= 0) {
                uint4 u = *(const uint4*)(qkvz + rowbase + (size_t)(j - 3) * 12288 + col);
                const unsigned short* us = (const unsigned short*)&u;
#pragma unroll
                for (int e = 0; e < 8; e++) acc[e] += bf2f(us[e]) * wts[e][j];
            }
        }
#pragma unroll
        for (int e = 0; e < 8; e++) xs[c + e] = acc[e] / (1.f + expf(-acc[e]));
    }
    __syncthreads();
    {
        int seg = tid >> 3, part = tid & 7;
        const float* pp = xs + seg * 128 + part * 16;
        float s2 = 0.f;
#pragma unroll
        for (int j = 0; j < 16; j++) s2 += pp[j] * pp[j];
        s2 += __shfl_xor(s2, 1);
        s2 += __shfl_xor(s2, 2);
        s2 += __shfl_xor(s2, 4);
        if (part == 0) rs[seg] = rsqrtf(s2 + 1e-6f);
    }
    __syncthreads();
    const float QS = 0.08838834764831845f;  // 128^-0.5
#pragma unroll
    for (int i = 0; i < 4; i++) {
        int c = (i * 256 + tid) * 8;
        float x[8];
#pragma unroll
        for (int e = 0; e < 8; e++) x[e] = xs[c + e];
        if (c < 4096) {
            float sc = (c < 2048) ? rs[c >> 7] * QS : rs[((c - 2048) >> 7) + 16];
            uint4 o;
            o.x = (unsigned)f2bf(x[0] * sc) | ((unsigned)f2bf(x[1] * sc) << 16);
            o.y = (unsigned)f2bf(x[2] * sc) | ((unsigned)f2bf(x[3] * sc) << 16);
            o.z = (unsigned)f2bf(x[4] * sc) | ((unsigned)f2bf(x[5] * sc) << 16);
            o.w = (unsigned)f2bf(x[6] * sc) | ((unsigned)f2bf(x[7] * sc) << 16);
            if (c < 2048) *(uint4*)(qb + (size_t)t * 2048 + c) = o;
            else *(uint4*)(kb + (size_t)t * 2048 + c - 2048) = o;
        } else {
            float* vp = vv + (size_t)t * 4096 + c - 4096;
            *(float4*)vp = make_float4(x[0], x[1], x[2], x[3]);
            *(float4*)(vp + 4) = make_float4(x[4], x[5], x[6], x[7]);
        }
    }
}

// ---------------- delta-rule prep (parallel over 64 bh x 16 chunks) ----------------
__global__ __launch_bounds__(256, 2) void prep_kernel(
    const unsigned short* __restrict__ qb, const unsigned short* __restrict__ kb,
    const float* __restrict__ vv, const float* __restrict__ gg,
    const float* __restrict__ bb,
    unsigned short* __restrict__ Wg, unsigned short* __restrict__ DlT,
    unsigned short* __restrict__ KtT, unsigned short* __restrict__ Pt,
    float* __restrict__ lamg, float* __restrict__ l64g) {
    __shared__ __align__(16) unsigned short Tb[64 * 72];    // -beta_i E_ij A_ij (i>j)
    __shared__ __align__(16) unsigned short Xw[4][64 * 72]; // per-wave solutions [col][tok]
    __shared__ float Td[4 * 16 * 17];                       // +T diag blocks fp32
    __shared__ float RHSw[4][16 * 68];                      // per-wave stage scratch
    __shared__ float cc[64], bet[64], lam_s[64], ex64[64];

    int bid = blockIdx.x;            // bh*16 + ch
    int ch = bid & 15, bh = bid >> 4;
    int vh = bh & 31, b = bh >> 5;
    int hk = vh >> 1;
    int t0 = b * 1024 + ch * 64;
    int tid = threadIdx.x, wv = tid >> 6, lane = tid & 63;
    int qd = lane >> 4, rc = lane & 15;
    int rowb = (wv & 1) * 32;
    size_t obase = (size_t)bid * 8192;
    size_t pbase = (size_t)bid * 4096;

    // decay metadata (wave 0)
    if (tid < 64) {
        float x = gg[(size_t)(t0 + tid) * 32 + vh];
#pragma unroll
        for (int ofs = 1; ofs < 64; ofs <<= 1) {
            float up = __shfl_up(x, ofs, 64);
            if (tid >= ofs) x += up;
        }
        cc[tid] = x;
        float l = __expf(x);
        lam_s[tid] = l;
        float tot = __shfl(x, 63, 64);
        ex64[tid] = __expf(tot - x);
        bet[tid] = bb[(size_t)(t0 + tid) * 32 + vh];
        lamg[(size_t)bid * 64 + tid] = l;
        if (tid == 0) l64g[bid] = __expf(tot);
    }
    __syncthreads();

    // phase A: A = K K^T (waves 0,1) -> Tb/Td ; P = Q K^T (waves 2,3) -> Pt
    {
        const unsigned short* src = (wv >= 2) ? qb : kb;
        f32x4 acc[2][4];
#pragma unroll
        for (int tm = 0; tm < 2; tm++)
#pragma unroll
            for (int tn = 0; tn < 4; tn++)
#pragma unroll
                for (int r = 0; r < 4; r++) acc[tm][tn][r] = 0.f;
#pragma unroll
        for (int ks = 0; ks < 4; ks++) {
            bf16x8 af[2], bfr[4];
#pragma unroll
            for (int tm = 0; tm < 2; tm++) {
                int row = rowb + tm * 16 + rc;
                af[tm] = *(const bf16x8*)(src + ((size_t)(t0 + row) * 16 + hk) * 128 + ks * 32 + qd * 8);
            }
#pragma unroll
            for (int tn = 0; tn < 4; tn++)
                bfr[tn] = *(const bf16x8*)(kb + ((size_t)(t0 + tn * 16 + rc) * 16 + hk) * 128 + ks * 32 + qd * 8);
#pragma unroll
            for (int tm = 0; tm < 2; tm++)
#pragma unroll
                for (int tn = 0; tn < 4; tn++)
                    acc[tm][tn] = __builtin_amdgcn_mfma_f32_16x16x32_bf16(af[tm], bfr[tn], acc[tm][tn], 0, 0, 0);
        }
        if (wv < 2) {
#pragma unroll
            for (int tm = 0; tm < 2; tm++)
#pragma unroll
                for (int tn = 0; tn < 4; tn++)
#pragma unroll
                    for (int r = 0; r < 4; r++) {
                        int i = rowb + tm * 16 + qd * 4 + r;
                        int j = tn * 16 + rc;
                        float val = acc[tm][tn][r];
                        float tv = 0.f;
                        if (i > j) tv = bet[i] * __expf(cc[i] - cc[j]) * val;
                        Tb[i * 72 + j] = f2bf(-tv);
                        if ((i >> 4) == (j >> 4) && i > j)
                            Td[(i >> 4) * 272 + (i & 15) * 17 + (j & 15)] = tv;
                    }
        } else {
#pragma unroll
            for (int tm = 0; tm < 2; tm++)
#pragma unroll
                for (int tn = 0; tn < 4; tn++)
#pragma unroll
                    for (int r = 0; r < 4; r++) {
                        int i = rowb + tm * 16 + qd * 4 + r;
                        int j = tn * 16 + rc;
                        float ev = (i >= j) ? __expf(cc[i] - cc[j]) : 0.f;
                        Pt[pbase + i * 64 + j] = f2bf(ev * acc[tm][tn][r]);
                    }
        }
    }
    // KtT: Etil-folded K^T [dk][tok] straight from global (L2-hot)
    {
        int dk = tid >> 1, half = tid & 1;
#pragma unroll
        for (int j = 0; j < 4; j++) {
            unsigned short tmp[8];
#pragma unroll
            for (int e = 0; e < 8; e++) {
                int tok = half * 32 + j * 8 + e;
                tmp[e] = f2bf(bf2f(kb[((size_t)(t0 + tok) * 16 + hk) * 128 + dk]) * ex64[tok]);
            }
            *(uint4*)(KtT + obase + dk * 64 + half * 32 + j * 8) = *(const uint4*)tmp;
        }
    }
    __syncthreads();   // Tb/Td ready for all waves

    // per-wave forward substitution: wave wv owns col-batch cb = wv (64 cols)
    {
        int cb = wv;
        unsigned short* Xb = Xw[wv];
        float* RHS = RHSw[wv];
        for (int z = lane; z < 64 * 72 / 2; z += 64) ((unsigned int*)Xb)[z] = 0u;
#pragma unroll
        for (int B = 0; B < 4; B++) {
            f32x4 tacc[4];
#pragma unroll
            for (int cf = 0; cf < 4; cf++)
#pragma unroll
                for (int r = 0; r < 4; r++) {
                    int i = B * 16 + qd * 4 + r;
                    int c = cf * 16 + rc;
                    float v;
                    if (cb < 2)
                        v = bet[i] * vv[((size_t)(t0 + i) * 32 + vh) * 128 + cb * 64 + c];
                    else
                        v = bet[i] * lam_s[i] * bf2f(kb[((size_t)(t0 + i) * 16 + hk) * 128 + (cb - 2) * 64 + c]);
                    tacc[cf][r] = v;
                }
            __builtin_amdgcn_s_waitcnt(0xc07f);  // prior Xb writes (same wave) visible
            const int nks = (B + 1) >> 1;  // 0,1,1,2
#pragma unroll
            for (int ks = 0; ks < 2; ks++) {
                if (ks >= nks) break;
                bf16x8 af = *(const bf16x8*)&Tb[(B * 16 + rc) * 72 + ks * 32 + qd * 8];
#pragma unroll
                for (int cf = 0; cf < 4; cf++) {
                    bf16x8 bf_ = *(const bf16x8*)&Xb[(cf * 16 + rc) * 72 + ks * 32 + qd * 8];
                    tacc[cf] = __builtin_amdgcn_mfma_f32_16x16x32_bf16(af, bf_, tacc[cf], 0, 0, 0);
                }
            }
#pragma unroll
            for (int cf = 0; cf < 4; cf++)
#pragma unroll
                for (int r = 0; r < 4; r++)
                    RHS[(qd * 4 + r) * 68 + cf * 16 + rc] = tacc[cf][r];
            __builtin_amdgcn_s_waitcnt(0xc07f);  // RHS visible for transposed read
            {
                float d[16];
#pragma unroll
                for (int i2 = 0; i2 < 16; i2++) d[i2] = RHS[i2 * 68 + lane];
#pragma unroll
                for (int i2 = 1; i2 < 16; i2++)
#pragma unroll
                    for (int j2 = 0; j2 < i2; j2++)
                        d[i2] -= Td[B * 272 + i2 * 17 + j2] * d[j2];
#pragma unroll
                for (int i2 = 0; i2 < 16; i2++)
                    Xb[lane * 72 + B * 16 + i2] = f2bf(d[i2]);
            }
        }
        __builtin_amdgcn_s_waitcnt(0xc07f);
        // write out this wave's batch
        if (cb < 2) {  // Dloc^T rows [dv = cb*64+lane][tok]
#pragma unroll
            for (int j = 0; j < 8; j++) {
                uint4 u = *(const uint4*)&Xb[lane * 72 + j * 8];
                *(uint4*)(DlT + obase + (size_t)(cb * 64 + lane) * 64 + j * 8) = u;
            }
        } else {  // W rows [tok = lane][dk]: transpose from Xb
#pragma unroll
            for (int dq = 0; dq < 8; dq++) {
                unsigned short tmp[8];
#pragma unroll
                for (int e = 0; e < 8; e++)
                    tmp[e] = Xb[(dq * 8 + e) * 72 + lane];
                *(uint4*)(Wg + obase + (size_t)lane * 128 + (cb - 2) * 64 + dq * 8) = *(const uint4*)tmp;
            }
        }
    }
}

// ---------------- serial inter-chunk scan (lean) ----------------
__global__ __launch_bounds__(256, 2) void recb_kernel(
    const unsigned short* __restrict__ qb, const float* __restrict__ lamg,
    const float* __restrict__ l64g, const unsigned short* __restrict__ Wg,
    const unsigned short* __restrict__ DlT, const unsigned short* __restrict__ KtT,
    const unsigned short* __restrict__ Pt, float* __restrict__ oo) {
    __shared__ __align__(16) unsigned short St[16 * 136];  // S^T bf16 [dv][dk]
    __shared__ __align__(16) unsigned short Dls[16 * 72];  // Dloc^T -> D'^T slice
    int bid = blockIdx.x;
    int slice = bid >> 6;           // slice-major: same head -> same XCD
    int rest = bid & 63;
    int vh = rest & 31, b = rest >> 5;
    int bh = b * 32 + vh;
    int hk = vh >> 1, dvo = slice * 16, tb = b * 1024;
    int tid = threadIdx.x, wv = tid >> 6, lane = tid & 63;
    int qd = lane >> 4, rc = lane & 15;

    f32x4 sacc[2];
#pragma unroll
    for (int tm = 0; tm < 2; tm++)
#pragma unroll
        for (int r = 0; r < 4; r++) sacc[tm][r] = 0.f;
    for (int z = tid; z < 16 * 136 / 2; z += 256) ((unsigned int*)St)[z] = 0u;
    __syncthreads();

#pragma unroll 1
    for (int ch = 0; ch < 16; ch++) {
        int bhch = bh * 16 + ch;
        size_t obase = (size_t)bhch * 8192;
        size_t pbase = (size_t)bhch * 4096;
        int t0 = tb + ch * 64;
        if (tid < 128) {
            int row = tid >> 3, t8 = (tid & 7) * 8;
            uint4 u = *(const uint4*)(DlT + obase + (dvo + row) * 64 + t8);
            *(uint4*)&Dls[row * 72 + t8] = u;
        }
        __syncthreads();
        {
            f32x4 uacc;
#pragma unroll
            for (int r = 0; r < 4; r++) uacc[r] = 0.f;
#pragma unroll
            for (int ks = 0; ks < 4; ks++) {
                bf16x8 a_ = *(const bf16x8*)&St[rc * 136 + ks * 32 + qd * 8];
                bf16x8 b_ = *(const bf16x8*)(Wg + obase + (size_t)(wv * 16 + rc) * 128 + ks * 32 + qd * 8);
                uacc = __builtin_amdgcn_mfma_f32_16x16x32_bf16(a_, b_, uacc, 0, 0, 0);
            }
#pragma unroll
            for (int r = 0; r < 4; r++) {
                int idx = (qd * 4 + r) * 72 + wv * 16 + rc;
                Dls[idx] = f2bf(bf2f(Dls[idx]) - uacc[r]);
            }
        }
        __syncthreads();
        {
            f32x4 qacc;
#pragma unroll
            for (int r = 0; r < 4; r++) qacc[r] = 0.f;
#pragma unroll
            for (int ks = 0; ks < 4; ks++) {
                bf16x8 a_ = *(const bf16x8*)(qb + ((size_t)(t0 + wv * 16 + rc) * 16 + hk) * 128 + ks * 32 + qd * 8);
                bf16x8 b_ = *(const bf16x8*)&St[rc * 136 + ks * 32 + qd * 8];
                qacc = __builtin_amdgcn_mfma_f32_16x16x32_bf16(a_, b_, qacc, 0, 0, 0);
            }
            bf16x8 bd[2];
#pragma unroll
            for (int ks = 0; ks < 2; ks++)
                bd[ks] = *(const bf16x8*)&Dls[rc * 72 + ks * 32 + qd * 8];
            f32x4 oacc;
#pragma unroll
            for (int r = 0; r < 4; r++)
                oacc[r] = lamg[(size_t)bhch * 64 + wv * 16 + qd * 4 + r] * qacc[r];
#pragma unroll
            for (int ks = 0; ks < 2; ks++) {
                bf16x8 a_ = *(const bf16x8*)(Pt + pbase + (size_t)(wv * 16 + rc) * 64 + ks * 32 + qd * 8);
                oacc = __builtin_amdgcn_mfma_f32_16x16x32_bf16(a_, bd[ks], oacc, 0, 0, 0);
            }
#pragma unroll
            for (int r = 0; r < 4; r++)
                oo[((size_t)(t0 + wv * 16 + qd * 4 + r) * 32 + vh) * 128 + dvo + rc] = oacc[r];
            float l64 = l64g[bhch];
#pragma unroll
            for (int tm = 0; tm < 2; tm++) {
#pragma unroll
                for (int r = 0; r < 4; r++) sacc[tm][r] *= l64;
#pragma unroll
                for (int ks = 0; ks < 2; ks++) {
                    bf16x8 a_ = *(const bf16x8*)(KtT + obase + (size_t)(wv * 32 + tm * 16 + rc) * 64 + ks * 32 + qd * 8);
                    sacc[tm] = __builtin_amdgcn_mfma_f32_16x16x32_bf16(a_, bd[ks], sacc[tm], 0, 0, 0);
                }
            }
        }
        __syncthreads();
#pragma unroll
        for (int tm = 0; tm < 2; tm++)
#pragma unroll
            for (int r = 0; r < 4; r++)
                St[rc * 136 + wv * 32 + tm * 16 + qd * 4 + r] = f2bf(sacc[tm][r]);
        __syncthreads();
    }
}

// ---------------- gated RMSNorm + bf16 convert ----------------
__global__ __launch_bounds__(256) void norm_kernel(
    const float* __restrict__ oo, const unsigned short* __restrict__ qkvz,
    const float* __restrict__ norm_w, unsigned short* __restrict__ yb) {
    int w = threadIdx.x >> 6, lane = threadIdx.x & 63;
    int g = blockIdx.x * 4 + w;
    int t = g >> 5, vh = g & 31;
    size_t ob = (size_t)g * 128;
    size_t zb = (size_t)t * 12288 + (size_t)(vh >> 1) * 768 + 512 + (vh & 1) * 128;
    float x0 = oo[ob + lane], x1 = oo[ob + 64 + lane];
    float z0 = bf2f(qkvz[zb + lane]), z1 = bf2f(qkvz[zb + 64 + lane]);
    float xg0 = x0 * (z0 / (1.f + expf(-z0)));
    float xg1 = x1 * (z1 / (1.f + expf(-z1)));
    float s = xg0 * xg0 + xg1 * xg1;
    s += __shfl_xor(s, 1);
    s += __shfl_xor(s, 2);
    s += __shfl_xor(s, 4);
    s += __shfl_xor(s, 8);
    s += __shfl_xor(s, 16);
    s += __shfl_xor(s, 32);
    float r = rsqrtf(s * (1.f / 128.f) + 1e-6f);
    size_t y0 = (size_t)t * 4096 + (size_t)vh * 128;
    yb[y0 + lane] = f2bf(xg0 * r * norm_w[lane]);
    yb[y0 + 64 + lane] = f2bf(xg1 * r * norm_w[64 + lane]);
}

extern "C" void kernel_launch(void* const* d_in, const int* in_sizes, int n_in,
                              void* d_out, int out_size, void* d_ws, size_t ws_size,
                              hipStream_t stream) {
    const float* hs      = (const float*)d_in[0];
    const float* w_qkvz  = (const float*)d_in[1];
    const float* w_ba    = (const float*)d_in[2];
    const float* conv_w  = (const float*)d_in[3];
    const float* dt_bias = (const float*)d_in[4];
    const float* A_log   = (const float*)d_in[5];
    const float* norm_w  = (const float*)d_in[6];
    const float* w_out   = (const float*)d_in[7];
    float* out = (float*)d_out;
    (void)in_sizes; (void)n_in; (void)out_size; (void)ws_size;

    char* p = (char*)d_ws;
    auto alloc = [&](size_t b) { char* r = p; p += (b + 255) & ~(size_t)255; return r; };
    float* gg = (float*)alloc(2048ull * 32 * 4);                         // log-decay
    float* bb = (float*)alloc(2048ull * 32 * 4);                         // beta
    unsigned short* hsb  = (unsigned short*)alloc(2048ull * 2048 * 2);   // hs bf16
    unsigned short* woT  = (unsigned short*)alloc(2048ull * 4096 * 2);   // w_out^T bf16
    unsigned short* wqT  = (unsigned short*)alloc(12288ull * 2048 * 2);  // w_qkvz^T bf16
    unsigned short* qkvz = (unsigned short*)alloc(2048ull * 12288 * 2);  // projections bf16
    unsigned short* qb16 = (unsigned short*)alloc(2048ull * 2048 * 2);   // q normed bf16
    unsigned short* kb16 = (unsigned short*)alloc(2048ull * 2048 * 2);   // k normed bf16
    float* vv = (float*)alloc(2048ull * 4096 * 4);                       // v fp32
    float* oo = (float*)alloc(2048ull * 4096 * 4);                       // recurrence out
    unsigned short* yb = (unsigned short*)alloc(2048ull * 4096 * 2);     // normed bf16
    unsigned short* Wg  = (unsigned short*)alloc(1024ull * 8192 * 2);    // W [bhch][64][128]
    unsigned short* DlT = (unsigned short*)alloc(1024ull * 8192 * 2);    // Dloc^T [bhch][128][64]
    unsigned short* KtT = (unsigned short*)alloc(1024ull * 8192 * 2);    // Ktil^T [bhch][128][64]
    unsigned short* Pt  = (unsigned short*)alloc(1024ull * 4096 * 2);    // Ptil [bhch][64][64]
    float* lamg = (float*)alloc(1024ull * 64 * 4);                       // lambda per token
    float* l64g = (float*)alloc(1024ull * 4);                            // chunk decay
    // gemm2 split-K-4 partials (67.1 MB) reuse wqT (48 MB, dead after gemm1)
    // + head of qkvz (dead after norm_kernel) — contiguous since woT precedes.
    float* gpart = (float*)wqT;

    cvt_bf16_kernel<<<4096, 256, 0, stream>>>(hs, hsb, 2048 * 2048 / 4);
    transpose_cvt_kernel<<<dim3(12288 / 32, 2048 / 32), 256, 0, stream>>>(w_qkvz, wqT, 2048, 12288);
    transpose_cvt_kernel<<<dim3(2048 / 32, 4096 / 32), 256, 0, stream>>>(w_out, woT, 4096, 2048);
    gemm384_kernel<<<512, 512, 0, stream>>>(hsb, wqT, qkvz, 2048, 12288, 2048);
    bag_kernel<<<256, 256, 0, stream>>>(hs, w_ba, A_log, dt_bias, gg, bb);
    conv_kernel<<<2048, 256, 0, stream>>>(qkvz, conv_w, qb16, kb16, vv);
    prep_kernel<<<1024, 256, 0, stream>>>(qb16, kb16, vv, gg, bb, Wg, DlT, KtT, Pt, lamg, l64g);
    recb_kernel<<<512, 256, 0, stream>>>(qb16, lamg, l64g, Wg, DlT, KtT, Pt, oo);
    norm_kernel<<<16384, 256, 0, stream>>>(oo, qkvz, norm_w, yb);
    gemm256_kernel<<<256, 512, 0, stream>>>(yb, woT, gpart, 2048, 2048, 4096, 1024);
    add_out4_kernel<<<4096, 256, 0, stream>>>(gpart, out, 2048 * 2048 / 4);
}

// Round 4
// 691.997 us; speedup vs baseline: 1.0982x; 1.0399x over previous
//
#include <hip/hip_runtime.h>
#include <stdint.h>

#define AS1 __attribute__((address_space(1)))
#define AS3 __attribute__((address_space(3)))

typedef __bf16 bf16x8 __attribute__((ext_vector_type(8)));
typedef float f32x4 __attribute__((ext_vector_type(4)));

static __device__ __forceinline__ float bf2f(unsigned short u) {
    union { unsigned int i; float f; } x; x.i = ((unsigned int)u) << 16; return x.f;
}
static __device__ __forceinline__ unsigned short f2bf(float f) {
    union { float f; unsigned int i; } x; x.f = f;
    unsigned int u = x.i;
    unsigned int r = (u + 0x7fffu + ((u >> 16) & 1u)) >> 16;  // RNE
    return (unsigned short)r;
}

static __device__ __forceinline__ void gll16(const void* g, void* l) {
    __builtin_amdgcn_global_load_lds((const AS1 unsigned int*)g,
                                     (AS3 unsigned int*)l, 16, 0, 0);
}

// ---------------- f32 -> bf16 elementwise (vec4) ----------------
__global__ __launch_bounds__(256) void cvt_bf16_kernel(
    const float* __restrict__ src, unsigned short* __restrict__ dst, int n4) {
    int i = blockIdx.x * 256 + threadIdx.x;
    if (i >= n4) return;
    float4 v = ((const float4*)src)[i];
    ushort4 o;
    o.x = f2bf(v.x); o.y = f2bf(v.y); o.z = f2bf(v.z); o.w = f2bf(v.w);
    ((ushort4*)dst)[i] = o;
}

// ---------------- f32 [R,C] -> bf16 [C,R] transpose ----------------
__global__ __launch_bounds__(256) void transpose_cvt_kernel(
    const float* __restrict__ src, unsigned short* __restrict__ dst, int R, int C) {
    __shared__ float tile[32][33];
    int x = threadIdx.x & 31, y = threadIdx.x >> 5;
    int c0 = blockIdx.x * 32, r0 = blockIdx.y * 32;
#pragma unroll
    for (int i = 0; i < 4; i++)
        tile[y + i * 8][x] = src[(size_t)(r0 + y + i * 8) * C + (c0 + x)];
    __syncthreads();
#pragma unroll
    for (int i = 0; i < 4; i++)
        dst[(size_t)(c0 + y + i * 8) * R + (r0 + x)] = f2bf(tile[x][y + i * 8]);
}

// ---------------- f32 [R,C] -> f32 [C,R] transpose (for w_ba) ----------------
__global__ __launch_bounds__(256) void transpose_f32_kernel(
    const float* __restrict__ src, float* __restrict__ dst, int R, int C) {
    __shared__ float tile[32][33];
    int x = threadIdx.x & 31, y = threadIdx.x >> 5;
    int c0 = blockIdx.x * 32, r0 = blockIdx.y * 32;
#pragma unroll
    for (int i = 0; i < 4; i++)
        tile[y + i * 8][x] = src[(size_t)(r0 + y + i * 8) * C + (c0 + x)];
    __syncthreads();
#pragma unroll
    for (int i = 0; i < 4; i++)
        dst[(size_t)(c0 + y + i * 8) * R + (r0 + x)] = tile[x][y + i * 8];
}

#define FENCE asm volatile("" ::: "memory")
#define BARRIER { FENCE; __builtin_amdgcn_s_barrier(); FENCE; }
#define LGKM0 asm volatile("s_waitcnt lgkmcnt(0)" ::: "memory")

// ---------------- 128x384 8-phase bf16 GEMM: C = A[M,K] * Bt[N,K]^T --------
// m201-class schedule retiled so gemm1's grid is 16 x 32 = 512 tiles =
// EXACTLY 2 full rounds on 256 CUs. Half-tile unit: 128 rows x 64 k = 16 KB,
// 16 subtiles [16][32], st_16x32 swizzle, staged linearly by global_load_lds
// with inverse-swizzled global source (rule #21). LDS = 8 slots x 16 KB.
// Per K-tile: ph1 stage A(g+1); ph2 B0(g+2); ph3 B1(g+2); ph4 B2(g+2) +
// vmcnt(6). 8 waves as 2(m) x 4(n): wave tile 64 x 96, acc[4][6].
__global__ __launch_bounds__(512, 2) void gemm384_kernel(
    const unsigned short* __restrict__ A, const unsigned short* __restrict__ Bt,
    unsigned short* __restrict__ C, int M, int N, int K) {
    __shared__ __align__(16) unsigned short SH[65536];  // 128 KiB
    int tid = threadIdx.x;
    int lane = tid & 63, w = tid >> 6;
    int wr = w >> 2, wc = w & 3;
    int qd = lane >> 4, rc = lane & 15;

    int wg = blockIdx.x;                 // 512 = 8 xcd * (16 m * 4 nsub)
    int xcd = wg & 7, loc = wg >> 3;
    int m0 = (loc & 15) * 128;
    int n0 = (xcd * 4 + (loc >> 4)) * 384;

    const int NT = K >> 6;               // K-tiles
    const int sK = K << 7;               // u16 elems per 128-row half-tile

    size_t sr[2];
#pragma unroll
    for (int j = 0; j < 2; j++) {
        int bu = j * 4096 + tid * 8;     // u16 offset within half-tile
        int sub = bu >> 9;
        int b = bu & 511;
        int bp = b ^ (((b >> 8) & 1) << 4);
        int row = ((sub >> 1) << 4) + (bp >> 5);
        int col = ((sub & 1) << 5) + (bp & 31);
        sr[j] = (size_t)row * K + col;
    }
    const unsigned short* Ab = A + (size_t)m0 * K;
    const unsigned short* Bb = Bt + (size_t)n0 * K;

    const int foff = (rc * 32 + qd * 8) ^ (((rc >> 3) & 1) << 4);
    int bC[6];
#pragma unroll
    for (int fj = 0; fj < 6; fj++) {
        int nb = wc * 96 + fj * 16;
        bC[fj] = (1 + (nb >> 7)) * 16384 + ((nb & 127) >> 4) * 1024 + foff;
    }

    f32x4 acc[4][6];
#pragma unroll
    for (int i = 0; i < 4; i++)
#pragma unroll
        for (int j = 0; j < 6; j++)
#pragma unroll
            for (int r = 0; r < 4; r++) acc[i][j][r] = 0.f;

    bf16x8 aq[2][2], bq[6][2];

#define STG(u, t)                                                             \
    {                                                                         \
        const unsigned short* s_ =                                            \
            ((u) == 0 ? Ab : Bb + (size_t)((u)-1) * sK) + (size_t)(t) * 64;   \
        int d_ = (((u)*2 + ((t)&1)) << 13) + tid * 8;                         \
        gll16(s_ + sr[0], &SH[d_]);                                           \
        gll16(s_ + sr[1], &SH[d_ + 4096]);                                    \
    }

#define LDAQ(p, QR)                                                           \
    {                                                                         \
        _Pragma("unroll") for (int fi = 0; fi < 2; fi++)                      \
            _Pragma("unroll") for (int ks = 0; ks < 2; ks++)                  \
                aq[fi][ks] = *(const bf16x8*)&SH[(p)*8192 +                   \
                    (wr * 4 + (QR)*2 + fi) * 1024 + ks * 512 + foff];         \
    }

#define LDBQ(p)                                                               \
    {                                                                         \
        _Pragma("unroll") for (int fj = 0; fj < 6; fj++)                      \
            _Pragma("unroll") for (int ks = 0; ks < 2; ks++)                  \
                bq[fj][ks] = *(const bf16x8*)&SH[bC[fj] + (p)*8192 + ks*512]; \
    }

#define MFMAQ(QR, QC)                                                         \
    {                                                                         \
        _Pragma("unroll") for (int fi = 0; fi < 2; fi++)                      \
            _Pragma("unroll") for (int fj = 0; fj < 3; fj++)                  \
                _Pragma("unroll") for (int ks = 0; ks < 2; ks++)              \
                    acc[(QR)*2 + fi][(QC)*3 + fj] =                           \
                        __builtin_amdgcn_mfma_f32_16x16x32_bf16(              \
                            aq[fi][ks], bq[(QC)*3 + fj][ks],                  \
                            acc[(QR)*2 + fi][(QC)*3 + fj], 0, 0, 0);          \
    }

    // ---- prologue: tile0 full + B0,B1,B2 of tile1; 3 stages left in flight
    STG(0, 0); STG(1, 0); STG(2, 0); STG(3, 0);
    STG(1, 1); STG(2, 1); STG(3, 1);
    asm volatile("s_waitcnt vmcnt(6)" ::: "memory");
    BARRIER;

    for (int g = 0; g < NT; ++g) {
        const int p = g & 1;
        // phase 1: quadrant (0,0)
        LDAQ(p, 0);
        LDBQ(p);
        if (g + 1 < NT) STG(0, g + 1);
        BARRIER; LGKM0;
        __builtin_amdgcn_s_setprio(1);
        MFMAQ(0, 0);
        __builtin_amdgcn_s_setprio(0);
        BARRIER;
        // phase 2: quadrant (0,1)
        if (g + 2 < NT) STG(1, g + 2);
        BARRIER; LGKM0;
        __builtin_amdgcn_s_setprio(1);
        MFMAQ(0, 1);
        __builtin_amdgcn_s_setprio(0);
        BARRIER;
        // phase 3: quadrant (1,0)
        LDAQ(p, 1);
        if (g + 2 < NT) STG(2, g + 2);
        BARRIER; LGKM0;
        __builtin_amdgcn_s_setprio(1);
        MFMAQ(1, 0);
        __builtin_amdgcn_s_setprio(0);
        BARRIER;
        // phase 4: quadrant (1,1) + K-tile boundary counted wait
        if (g + 2 < NT) STG(3, g + 2);
        if (g < NT - 2) { asm volatile("s_waitcnt vmcnt(6)" ::: "memory"); }
        else            { asm volatile("s_waitcnt vmcnt(0)" ::: "memory"); }
        BARRIER; LGKM0;
        __builtin_amdgcn_s_setprio(1);
        MFMAQ(1, 1);
        __builtin_amdgcn_s_setprio(0);
        BARRIER;
    }

#undef STG
#undef LDAQ
#undef LDBQ
#undef MFMAQ

#pragma unroll
    for (int mi = 0; mi < 4; mi++) {
        int row = m0 + wr * 64 + mi * 16 + qd * 4;
#pragma unroll
        for (int fj = 0; fj < 6; fj++) {
            int col = n0 + wc * 96 + fj * 16 + rc;
#pragma unroll
            for (int r = 0; r < 4; r++)
                C[(size_t)(row + r) * N + col] = f2bf(acc[mi][fj][r]);
        }
    }
}

// ---------------- 256x256 8-phase bf16 GEMM, split-K f32 partials ----------
__global__ __launch_bounds__(512, 2) void gemm256_kernel(
    const unsigned short* __restrict__ A, const unsigned short* __restrict__ Bt,
    float* __restrict__ C, int M, int N, int K, int Ksl) {
    __shared__ __align__(16) unsigned short SH[65536];  // 128 KiB
    int tid = threadIdx.x;
    int lane = tid & 63, w = tid >> 6;
    int wr = w >> 2, wc = w & 3;
    int qd = lane >> 4, rc = lane & 15;

    int wg = blockIdx.x;                 // 256 = 4 k-slices x 64 tiles
    int zz = wg >> 6;
    int loc = wg & 63;
    int m0 = (loc >> 3) * 256;
    int n0 = (loc & 7) * 256;
    const int NT = Ksl >> 6;
    const int sK = K << 7;

    size_t sr[2];
#pragma unroll
    for (int j = 0; j < 2; j++) {
        int bu = j * 4096 + tid * 8;
        int sub = bu >> 9;
        int b = bu & 511;
        int bp = b ^ (((b >> 8) & 1) << 4);
        int row = ((sub >> 1) << 4) + (bp >> 5);
        int col = ((sub & 1) << 5) + (bp & 31);
        sr[j] = (size_t)row * K + col;
    }
    const unsigned short* Ab = A + (size_t)m0 * K + (size_t)zz * Ksl;
    const unsigned short* Bb = Bt + (size_t)n0 * K + (size_t)zz * Ksl;

    const int foff = (rc * 32 + qd * 8) ^ (((rc >> 3) & 1) << 4);
    const int Ah = wr;
    const int Bh = wc >> 1;
    const int brow4 = (wc & 1) * 4;

    f32x4 acc[8][4];
#pragma unroll
    for (int i = 0; i < 8; i++)
#pragma unroll
        for (int j = 0; j < 4; j++)
#pragma unroll
            for (int r = 0; r < 4; r++) acc[i][j][r] = 0.f;

    bf16x8 aq[4][2], bq[4][2];

#define STG(mat, h, t)                                                        \
    {                                                                         \
        const unsigned short* s_ = ((mat) ? Bb : Ab) + (h) * sK + (t) * 64;   \
        int d_ = ((mat) << 15) + (((((t) & 1) * 2 + (h))) << 13) + tid * 8;   \
        gll16(s_ + sr[0], &SH[d_]);                                           \
        gll16(s_ + sr[1], &SH[d_ + 4096]);                                    \
    }

#define LDAQ(p, QR)                                                           \
    {                                                                         \
        int ab_ = ((p) * 2 + Ah) * 8192 + (QR) * 4096 + foff;                 \
        _Pragma("unroll") for (int fi = 0; fi < 4; fi++)                      \
            _Pragma("unroll") for (int ks = 0; ks < 2; ks++)                  \
                aq[fi][ks] = *(const bf16x8*)&SH[ab_ + (fi * 2 + ks) * 512];  \
    }

#define LDBQ(p)                                                               \
    {                                                                         \
        int bb_ = 32768 + ((p) * 2 + Bh) * 8192 + brow4 * 1024 + foff;        \
        _Pragma("unroll") for (int fg = 0; fg < 4; fg++)                      \
            _Pragma("unroll") for (int ks = 0; ks < 2; ks++)                  \
                bq[fg][ks] = *(const bf16x8*)&SH[bb_ + (fg * 2 + ks) * 512];  \
    }

#define MFMAQ(QR, QC)                                                         \
    {                                                                         \
        _Pragma("unroll") for (int fi = 0; fi < 4; fi++)                      \
            _Pragma("unroll") for (int fj = 0; fj < 2; fj++)                  \
                _Pragma("unroll") for (int ks = 0; ks < 2; ks++)              \
                    acc[(QR) * 4 + fi][(QC) * 2 + fj] =                       \
                        __builtin_amdgcn_mfma_f32_16x16x32_bf16(              \
                            aq[fi][ks], bq[(QC) * 2 + fj][ks],                \
                            acc[(QR) * 4 + fi][(QC) * 2 + fj], 0, 0, 0);      \
    }

    STG(0, 0, 0); STG(0, 1, 0); STG(1, 0, 0); STG(1, 1, 0);
    STG(1, 0, 1); STG(1, 1, 1); STG(0, 0, 1);
    asm volatile("s_waitcnt vmcnt(6)" ::: "memory");
    BARRIER;

    for (int g = 0; g < NT; ++g) {
        const int p = g & 1;
        LDAQ(p, 0);
        LDBQ(p);
        if (g + 1 < NT) STG(0, 1, g + 1);
        BARRIER; LGKM0;
        __builtin_amdgcn_s_setprio(1);
        MFMAQ(0, 0);
        __builtin_amdgcn_s_setprio(0);
        BARRIER;
        if (g + 2 < NT) STG(1, 0, g + 2);
        BARRIER; LGKM0;
        __builtin_amdgcn_s_setprio(1);
        MFMAQ(0, 1);
        __builtin_amdgcn_s_setprio(0);
        BARRIER;
        LDAQ(p, 1);
        if (g + 2 < NT) STG(1, 1, g + 2);
        BARRIER; LGKM0;
        __builtin_amdgcn_s_setprio(1);
        MFMAQ(1, 0);
        __builtin_amdgcn_s_setprio(0);
        BARRIER;
        if (g + 2 < NT) STG(0, 0, g + 2);
        if (g < NT - 2) { asm volatile("s_waitcnt vmcnt(6)" ::: "memory"); }
        else            { asm volatile("s_waitcnt vmcnt(0)" ::: "memory"); }
        BARRIER; LGKM0;
        __builtin_amdgcn_s_setprio(1);
        MFMAQ(1, 1);
        __builtin_amdgcn_s_setprio(0);
        BARRIER;
    }

#undef STG
#undef LDAQ
#undef LDBQ
#undef MFMAQ

    float* Cf = C + (size_t)zz * M * N;
#pragma unroll
    for (int mi = 0; mi < 8; mi++) {
        int row = m0 + wr * 128 + mi * 16 + qd * 4;
#pragma unroll
        for (int fg = 0; fg < 4; fg++) {
            int col = n0 + wc * 64 + fg * 16 + rc;
#pragma unroll
            for (int r = 0; r < 4; r++)
                Cf[(size_t)(row + r) * N + col] = acc[mi][fg][r];
        }
    }
}

// ---------------- split-K partial sum: out = p[0]+p[1]+p[2]+p[3] ----------------
__global__ __launch_bounds__(256) void add_out4_kernel(
    const float* __restrict__ p, float* __restrict__ out, int n4) {
    int i = blockIdx.x * 256 + threadIdx.x;
    if (i >= n4) return;
    size_t st = (size_t)n4 * 4;
    float4 a = ((const float4*)p)[i];
    float4 b = ((const float4*)(p + st))[i];
    float4 c = ((const float4*)(p + 2 * st))[i];
    float4 d = ((const float4*)(p + 3 * st))[i];
    ((float4*)out)[i] = make_float4(a.x + b.x + c.x + d.x, a.y + b.y + c.y + d.y,
                                    a.z + b.z + c.z + d.z, a.w + b.w + c.w + d.w);
}

// ---------------- ba GEMM + beta/g computation (split-K vectorized) --------
// out[t][c] = sum_k hs[t][k] * w_baT[c][k].  Grid 1024 (2 tokens/block),
// thread = (col 0..63, kc 0..3 of 512-k chunks); 128 float4 FMAs per token
// per thread; LDS reduce over kc; sigmoid/softplus epilogue.
// hs addresses are wave-uniform (one broadcast line per iter); w_baT streams
// are per-lane contiguous 2 KB and the whole table (512 KB) is L2-resident.
__global__ __launch_bounds__(256) void bag_kernel(
    const float* __restrict__ hs, const float* __restrict__ w_baT,
    const float* __restrict__ A_log, const float* __restrict__ dt_bias,
    float* __restrict__ gg, float* __restrict__ bb) {
    __shared__ float ps[4][2][64];
    int tid = threadIdx.x;
    int col = tid & 63, kc = tid >> 6;
    int t0 = blockIdx.x * 2;
    const float4* wp = (const float4*)(w_baT + (size_t)col * 2048 + kc * 512);
    const float4* h0 = (const float4*)(hs + (size_t)t0 * 2048 + kc * 512);
    const float4* h1 = (const float4*)(hs + (size_t)(t0 + 1) * 2048 + kc * 512);
    float a0 = 0.f, a1 = 0.f;
#pragma unroll 4
    for (int i = 0; i < 128; i++) {
        float4 wv = wp[i];
        float4 x0 = h0[i];
        float4 x1 = h1[i];
        a0 += wv.x * x0.x + wv.y * x0.y + wv.z * x0.z + wv.w * x0.w;
        a1 += wv.x * x1.x + wv.y * x1.y + wv.z * x1.z + wv.w * x1.w;
    }
    ps[kc][0][col] = a0;
    ps[kc][1][col] = a1;
    __syncthreads();
    if (tid < 128) {
        int j = tid >> 6, c = tid & 63;
        float acc = ps[0][j][c] + ps[1][j][c] + ps[2][j][c] + ps[3][j][c];
        int t = t0 + j;
        int h = c >> 2, idx = c & 3;
        int vh = h * 2 + (idx & 1);
        if (idx < 2) {
            bb[t * 32 + vh] = 1.f / (1.f + expf(-acc));
        } else {
            float x = acc + dt_bias[vh];
            float sp = fmaxf(x, 0.f) + log1pf(expf(-fabsf(x)));
            gg[t * 32 + vh] = -expf(A_log[vh]) * sp;
        }
    }
}

// ---------------- depthwise causal conv(4) + silu + l2norm(q,k) ----------------
// blockIdx remapped so each XCD owns a contiguous 256-token span: the 3-row
// causal re-read of qkvz then hits the local L2 instead of re-fetching HBM.
__global__ __launch_bounds__(256) void conv_kernel(
    const unsigned short* __restrict__ qkvz, const float* __restrict__ conv_w,
    unsigned short* __restrict__ qb, unsigned short* __restrict__ kb,
    float* __restrict__ vv) {
    __shared__ float xs[8192];
    __shared__ float rs[32];
    int t = ((blockIdx.x & 7) << 8) + (blockIdx.x >> 3);  // XCD-chunked
    int s = t & 1023;
    int tid = threadIdx.x;
    size_t rowbase = (size_t)t * 12288;
#pragma unroll
    for (int i = 0; i < 4; i++) {
        int c = (i * 256 + tid) * 8;
        int d = c & 127;
        int col;
        if (c < 2048) col = (c >> 7) * 768 + d;
        else if (c < 4096) col = ((c - 2048) >> 7) * 768 + 128 + d;
        else { int vh2 = (c - 4096) >> 7; col = (vh2 >> 1) * 768 + 256 + (vh2 & 1) * 128 + d; }
        float wts[8][4];
#pragma unroll
        for (int e = 0; e < 8; e++) {
            float4 t4 = *(const float4*)(conv_w + (size_t)(c + e) * 4);
            wts[e][0] = t4.x; wts[e][1] = t4.y; wts[e][2] = t4.z; wts[e][3] = t4.w;
        }
        float acc[8] = {0.f, 0.f, 0.f, 0.f, 0.f, 0.f, 0.f, 0.f};
#pragma unroll
        for (int j = 0; j < 4; j++) {
            int ss = s - 3 + j;
            if (ss >= 0) {
                uint4 u = *(const uint4*)(qkvz + rowbase + (size_t)(j - 3) * 12288 + col);
                const unsigned short* us = (const unsigned short*)&u;
#pragma unroll
                for (int e = 0; e < 8; e++) acc[e] += bf2f(us[e]) * wts[e][j];
            }
        }
#pragma unroll
        for (int e = 0; e < 8; e++) xs[c + e] = acc[e] / (1.f + expf(-acc[e]));
    }
    __syncthreads();
    {
        int seg = tid >> 3, part = tid & 7;
        const float* pp = xs + seg * 128 + part * 16;
        float s2 = 0.f;
#pragma unroll
        for (int j = 0; j < 16; j++) s2 += pp[j] * pp[j];
        s2 += __shfl_xor(s2, 1);
        s2 += __shfl_xor(s2, 2);
        s2 += __shfl_xor(s2, 4);
        if (part == 0) rs[seg] = rsqrtf(s2 + 1e-6f);
    }
    __syncthreads();
    const float QS = 0.08838834764831845f;  // 128^-0.5
#pragma unroll
    for (int i = 0; i < 4; i++) {
        int c = (i * 256 + tid) * 8;
        float x[8];
#pragma unroll
        for (int e = 0; e < 8; e++) x[e] = xs[c + e];
        if (c < 4096) {
            float sc = (c < 2048) ? rs[c >> 7] * QS : rs[((c - 2048) >> 7) + 16];
            uint4 o;
            o.x = (unsigned)f2bf(x[0] * sc) | ((unsigned)f2bf(x[1] * sc) << 16);
            o.y = (unsigned)f2bf(x[2] * sc) | ((unsigned)f2bf(x[3] * sc) << 16);
            o.z = (unsigned)f2bf(x[4] * sc) | ((unsigned)f2bf(x[5] * sc) << 16);
            o.w = (unsigned)f2bf(x[6] * sc) | ((unsigned)f2bf(x[7] * sc) << 16);
            if (c < 2048) *(uint4*)(qb + (size_t)t * 2048 + c) = o;
            else *(uint4*)(kb + (size_t)t * 2048 + c - 2048) = o;
        } else {
            float* vp = vv + (size_t)t * 4096 + c - 4096;
            *(float4*)vp = make_float4(x[0], x[1], x[2], x[3]);
            *(float4*)(vp + 4) = make_float4(x[4], x[5], x[6], x[7]);
        }
    }
}

// ---------------- delta-rule prep (parallel over 64 bh x 16 chunks) ----------------
__global__ __launch_bounds__(256, 2) void prep_kernel(
    const unsigned short* __restrict__ qb, const unsigned short* __restrict__ kb,
    const float* __restrict__ vv, const float* __restrict__ gg,
    const float* __restrict__ bb,
    unsigned short* __restrict__ Wg, unsigned short* __restrict__ DlT,
    unsigned short* __restrict__ KtT, unsigned short* __restrict__ Pt,
    float* __restrict__ lamg, float* __restrict__ l64g) {
    __shared__ __align__(16) unsigned short Tb[64 * 72];    // -beta_i E_ij A_ij (i>j)
    __shared__ __align__(16) unsigned short Xw[4][64 * 72]; // per-wave solutions [col][tok]
    __shared__ float Td[4 * 16 * 17];                       // +T diag blocks fp32
    __shared__ float RHSw[4][16 * 68];                      // per-wave stage scratch
    __shared__ float cc[64], bet[64], lam_s[64], ex64[64];

    int bid = blockIdx.x;            // bh*16 + ch
    int ch = bid & 15, bh = bid >> 4;
    int vh = bh & 31, b = bh >> 5;
    int hk = vh >> 1;
    int t0 = b * 1024 + ch * 64;
    int tid = threadIdx.x, wv = tid >> 6, lane = tid & 63;
    int qd = lane >> 4, rc = lane & 15;
    int rowb = (wv & 1) * 32;
    size_t obase = (size_t)bid * 8192;
    size_t pbase = (size_t)bid * 4096;

    // decay metadata (wave 0)
    if (tid < 64) {
        float x = gg[(size_t)(t0 + tid) * 32 + vh];
#pragma unroll
        for (int ofs = 1; ofs < 64; ofs <<= 1) {
            float up = __shfl_up(x, ofs, 64);
            if (tid >= ofs) x += up;
        }
        cc[tid] = x;
        float l = __expf(x);
        lam_s[tid] = l;
        float tot = __shfl(x, 63, 64);
        ex64[tid] = __expf(tot - x);
        bet[tid] = bb[(size_t)(t0 + tid) * 32 + vh];
        lamg[(size_t)bid * 64 + tid] = l;
        if (tid == 0) l64g[bid] = __expf(tot);
    }
    __syncthreads();

    // phase A: A = K K^T (waves 0,1) -> Tb/Td ; P = Q K^T (waves 2,3) -> Pt
    {
        const unsigned short* src = (wv >= 2) ? qb : kb;
        f32x4 acc[2][4];
#pragma unroll
        for (int tm = 0; tm < 2; tm++)
#pragma unroll
            for (int tn = 0; tn < 4; tn++)
#pragma unroll
                for (int r = 0; r < 4; r++) acc[tm][tn][r] = 0.f;
#pragma unroll
        for (int ks = 0; ks < 4; ks++) {
            bf16x8 af[2], bfr[4];
#pragma unroll
            for (int tm = 0; tm < 2; tm++) {
                int row = rowb + tm * 16 + rc;
                af[tm] = *(const bf16x8*)(src + ((size_t)(t0 + row) * 16 + hk) * 128 + ks * 32 + qd * 8);
            }
#pragma unroll
            for (int tn = 0; tn < 4; tn++)
                bfr[tn] = *(const bf16x8*)(kb + ((size_t)(t0 + tn * 16 + rc) * 16 + hk) * 128 + ks * 32 + qd * 8);
#pragma unroll
            for (int tm = 0; tm < 2; tm++)
#pragma unroll
                for (int tn = 0; tn < 4; tn++)
                    acc[tm][tn] = __builtin_amdgcn_mfma_f32_16x16x32_bf16(af[tm], bfr[tn], acc[tm][tn], 0, 0, 0);
        }
        if (wv < 2) {
#pragma unroll
            for (int tm = 0; tm < 2; tm++)
#pragma unroll
                for (int tn = 0; tn < 4; tn++)
#pragma unroll
                    for (int r = 0; r < 4; r++) {
                        int i = rowb + tm * 16 + qd * 4 + r;
                        int j = tn * 16 + rc;
                        float val = acc[tm][tn][r];
                        float tv = 0.f;
                        if (i > j) tv = bet[i] * __expf(cc[i] - cc[j]) * val;
                        Tb[i * 72 + j] = f2bf(-tv);
                        if ((i >> 4) == (j >> 4) && i > j)
                            Td[(i >> 4) * 272 + (i & 15) * 17 + (j & 15)] = tv;
                    }
        } else {
#pragma unroll
            for (int tm = 0; tm < 2; tm++)
#pragma unroll
                for (int tn = 0; tn < 4; tn++)
#pragma unroll
                    for (int r = 0; r < 4; r++) {
                        int i = rowb + tm * 16 + qd * 4 + r;
                        int j = tn * 16 + rc;
                        float ev = (i >= j) ? __expf(cc[i] - cc[j]) : 0.f;
                        Pt[pbase + i * 64 + j] = f2bf(ev * acc[tm][tn][r]);
                    }
        }
    }
    // KtT: Etil-folded K^T [dk][tok] straight from global (L2-hot)
    {
        int dk = tid >> 1, half = tid & 1;
#pragma unroll
        for (int j = 0; j < 4; j++) {
            unsigned short tmp[8];
#pragma unroll
            for (int e = 0; e < 8; e++) {
                int tok = half * 32 + j * 8 + e;
                tmp[e] = f2bf(bf2f(kb[((size_t)(t0 + tok) * 16 + hk) * 128 + dk]) * ex64[tok]);
            }
            *(uint4*)(KtT + obase + dk * 64 + half * 32 + j * 8) = *(const uint4*)tmp;
        }
    }
    __syncthreads();   // Tb/Td ready for all waves

    // per-wave forward substitution: wave wv owns col-batch cb = wv (64 cols)
    {
        int cb = wv;
        unsigned short* Xb = Xw[wv];
        float* RHS = RHSw[wv];
        for (int z = lane; z < 64 * 72 / 2; z += 64) ((unsigned int*)Xb)[z] = 0u;
#pragma unroll
        for (int B = 0; B < 4; B++) {
            f32x4 tacc[4];
#pragma unroll
            for (int cf = 0; cf < 4; cf++)
#pragma unroll
                for (int r = 0; r < 4; r++) {
                    int i = B * 16 + qd * 4 + r;
                    int c = cf * 16 + rc;
                    float v;
                    if (cb < 2)
                        v = bet[i] * vv[((size_t)(t0 + i) * 32 + vh) * 128 + cb * 64 + c];
                    else
                        v = bet[i] * lam_s[i] * bf2f(kb[((size_t)(t0 + i) * 16 + hk) * 128 + (cb - 2) * 64 + c]);
                    tacc[cf][r] = v;
                }
            __builtin_amdgcn_s_waitcnt(0xc07f);  // prior Xb writes (same wave) visible
            const int nks = (B + 1) >> 1;  // 0,1,1,2
#pragma unroll
            for (int ks = 0; ks < 2; ks++) {
                if (ks >= nks) break;
                bf16x8 af = *(const bf16x8*)&Tb[(B * 16 + rc) * 72 + ks * 32 + qd * 8];
#pragma unroll
                for (int cf = 0; cf < 4; cf++) {
                    bf16x8 bf_ = *(const bf16x8*)&Xb[(cf * 16 + rc) * 72 + ks * 32 + qd * 8];
                    tacc[cf] = __builtin_amdgcn_mfma_f32_16x16x32_bf16(af, bf_, tacc[cf], 0, 0, 0);
                }
            }
#pragma unroll
            for (int cf = 0; cf < 4; cf++)
#pragma unroll
                for (int r = 0; r < 4; r++)
                    RHS[(qd * 4 + r) * 68 + cf * 16 + rc] = tacc[cf][r];
            __builtin_amdgcn_s_waitcnt(0xc07f);  // RHS visible for transposed read
            {
                float d[16];
#pragma unroll
                for (int i2 = 0; i2 < 16; i2++) d[i2] = RHS[i2 * 68 + lane];
#pragma unroll
                for (int i2 = 1; i2 < 16; i2++)
#pragma unroll
                    for (int j2 = 0; j2 < i2; j2++)
                        d[i2] -= Td[B * 272 + i2 * 17 + j2] * d[j2];
#pragma unroll
                for (int i2 = 0; i2 < 16; i2++)
                    Xb[lane * 72 + B * 16 + i2] = f2bf(d[i2]);
            }
        }
        __builtin_amdgcn_s_waitcnt(0xc07f);
        // write out this wave's batch
        if (cb < 2) {  // Dloc^T rows [dv = cb*64+lane][tok]
#pragma unroll
            for (int j = 0; j < 8; j++) {
                uint4 u = *(const uint4*)&Xb[lane * 72 + j * 8];
                *(uint4*)(DlT + obase + (size_t)(cb * 64 + lane) * 64 + j * 8) = u;
            }
        } else {  // W rows [tok = lane][dk]: transpose from Xb
#pragma unroll
            for (int dq = 0; dq < 8; dq++) {
                unsigned short tmp[8];
#pragma unroll
                for (int e = 0; e < 8; e++)
                    tmp[e] = Xb[(dq * 8 + e) * 72 + lane];
                *(uint4*)(Wg + obase + (size_t)lane * 128 + (cb - 2) * 64 + dq * 8) = *(const uint4*)tmp;
            }
        }
    }
}

// ---------------- serial inter-chunk scan (lean) ----------------
__global__ __launch_bounds__(256, 2) void recb_kernel(
    const unsigned short* __restrict__ qb, const float* __restrict__ lamg,
    const float* __restrict__ l64g, const unsigned short* __restrict__ Wg,
    const unsigned short* __restrict__ DlT, const unsigned short* __restrict__ KtT,
    const unsigned short* __restrict__ Pt, float* __restrict__ oo) {
    __shared__ __align__(16) unsigned short St[16 * 136];  // S^T bf16 [dv][dk]
    __shared__ __align__(16) unsigned short Dls[16 * 72];  // Dloc^T -> D'^T slice
    int bid = blockIdx.x;
    int slice = bid >> 6;           // slice-major: same head -> same XCD
    int rest = bid & 63;
    int vh = rest & 31, b = rest >> 5;
    int bh = b * 32 + vh;
    int hk = vh >> 1, dvo = slice * 16, tb = b * 1024;
    int tid = threadIdx.x, wv = tid >> 6, lane = tid & 63;
    int qd = lane >> 4, rc = lane & 15;

    f32x4 sacc[2];
#pragma unroll
    for (int tm = 0; tm < 2; tm++)
#pragma unroll
        for (int r = 0; r < 4; r++) sacc[tm][r] = 0.f;
    for (int z = tid; z < 16 * 136 / 2; z += 256) ((unsigned int*)St)[z] = 0u;
    __syncthreads();

#pragma unroll 1
    for (int ch = 0; ch < 16; ch++) {
        int bhch = bh * 16 + ch;
        size_t obase = (size_t)bhch * 8192;
        size_t pbase = (size_t)bhch * 4096;
        int t0 = tb + ch * 64;
        if (tid < 128) {
            int row = tid >> 3, t8 = (tid & 7) * 8;
            uint4 u = *(const uint4*)(DlT + obase + (dvo + row) * 64 + t8);
            *(uint4*)&Dls[row * 72 + t8] = u;
        }
        __syncthreads();
        {
            f32x4 uacc;
#pragma unroll
            for (int r = 0; r < 4; r++) uacc[r] = 0.f;
#pragma unroll
            for (int ks = 0; ks < 4; ks++) {
                bf16x8 a_ = *(const bf16x8*)&St[rc * 136 + ks * 32 + qd * 8];
                bf16x8 b_ = *(const bf16x8*)(Wg + obase + (size_t)(wv * 16 + rc) * 128 + ks * 32 + qd * 8);
                uacc = __builtin_amdgcn_mfma_f32_16x16x32_bf16(a_, b_, uacc, 0, 0, 0);
            }
#pragma unroll
            for (int r = 0; r < 4; r++) {
                int idx = (qd * 4 + r) * 72 + wv * 16 + rc;
                Dls[idx] = f2bf(bf2f(Dls[idx]) - uacc[r]);
            }
        }
        __syncthreads();
        {
            f32x4 qacc;
#pragma unroll
            for (int r = 0; r < 4; r++) qacc[r] = 0.f;
#pragma unroll
            for (int ks = 0; ks < 4; ks++) {
                bf16x8 a_ = *(const bf16x8*)(qb + ((size_t)(t0 + wv * 16 + rc) * 16 + hk) * 128 + ks * 32 + qd * 8);
                bf16x8 b_ = *(const bf16x8*)&St[rc * 136 + ks * 32 + qd * 8];
                qacc = __builtin_amdgcn_mfma_f32_16x16x32_bf16(a_, b_, qacc, 0, 0, 0);
            }
            bf16x8 bd[2];
#pragma unroll
            for (int ks = 0; ks < 2; ks++)
                bd[ks] = *(const bf16x8*)&Dls[rc * 72 + ks * 32 + qd * 8];
            f32x4 oacc;
#pragma unroll
            for (int r = 0; r < 4; r++)
                oacc[r] = lamg[(size_t)bhch * 64 + wv * 16 + qd * 4 + r] * qacc[r];
#pragma unroll
            for (int ks = 0; ks < 2; ks++) {
                bf16x8 a_ = *(const bf16x8*)(Pt + pbase + (size_t)(wv * 16 + rc) * 64 + ks * 32 + qd * 8);
                oacc = __builtin_amdgcn_mfma_f32_16x16x32_bf16(a_, bd[ks], oacc, 0, 0, 0);
            }
#pragma unroll
            for (int r = 0; r < 4; r++)
                oo[((size_t)(t0 + wv * 16 + qd * 4 + r) * 32 + vh) * 128 + dvo + rc] = oacc[r];
            float l64 = l64g[bhch];
#pragma unroll
            for (int tm = 0; tm < 2; tm++) {
#pragma unroll
                for (int r = 0; r < 4; r++) sacc[tm][r] *= l64;
#pragma unroll
                for (int ks = 0; ks < 2; ks++) {
                    bf16x8 a_ = *(const bf16x8*)(KtT + obase + (size_t)(wv * 32 + tm * 16 + rc) * 64 + ks * 32 + qd * 8);
                    sacc[tm] = __builtin_amdgcn_mfma_f32_16x16x32_bf16(a_, bd[ks], sacc[tm], 0, 0, 0);
                }
            }
        }
        __syncthreads();
#pragma unroll
        for (int tm = 0; tm < 2; tm++)
#pragma unroll
            for (int r = 0; r < 4; r++)
                St[rc * 136 + wv * 32 + tm * 16 + qd * 4 + r] = f2bf(sacc[tm][r]);
        __syncthreads();
    }
}

// ---------------- gated RMSNorm + bf16 convert ----------------
__global__ __launch_bounds__(256) void norm_kernel(
    const float* __restrict__ oo, const unsigned short* __restrict__ qkvz,
    const float* __restrict__ norm_w, unsigned short* __restrict__ yb) {
    int w = threadIdx.x >> 6, lane = threadIdx.x & 63;
    int g = blockIdx.x * 4 + w;
    int t = g >> 5, vh = g & 31;
    size_t ob = (size_t)g * 128;
    size_t zb = (size_t)t * 12288 + (size_t)(vh >> 1) * 768 + 512 + (vh & 1) * 128;
    float x0 = oo[ob + lane], x1 = oo[ob + 64 + lane];
    float z0 = bf2f(qkvz[zb + lane]), z1 = bf2f(qkvz[zb + 64 + lane]);
    float xg0 = x0 * (z0 / (1.f + expf(-z0)));
    float xg1 = x1 * (z1 / (1.f + expf(-z1)));
    float s = xg0 * xg0 + xg1 * xg1;
    s += __shfl_xor(s, 1);
    s += __shfl_xor(s, 2);
    s += __shfl_xor(s, 4);
    s += __shfl_xor(s, 8);
    s += __shfl_xor(s, 16);
    s += __shfl_xor(s, 32);
    float r = rsqrtf(s * (1.f / 128.f) + 1e-6f);
    size_t y0 = (size_t)t * 4096 + (size_t)vh * 128;
    yb[y0 + lane] = f2bf(xg0 * r * norm_w[lane]);
    yb[y0 + 64 + lane] = f2bf(xg1 * r * norm_w[64 + lane]);
}

extern "C" void kernel_launch(void* const* d_in, const int* in_sizes, int n_in,
                              void* d_out, int out_size, void* d_ws, size_t ws_size,
                              hipStream_t stream) {
    const float* hs      = (const float*)d_in[0];
    const float* w_qkvz  = (const float*)d_in[1];
    const float* w_ba    = (const float*)d_in[2];
    const float* conv_w  = (const float*)d_in[3];
    const float* dt_bias = (const float*)d_in[4];
    const float* A_log   = (const float*)d_in[5];
    const float* norm_w  = (const float*)d_in[6];
    const float* w_out   = (const float*)d_in[7];
    float* out = (float*)d_out;
    (void)in_sizes; (void)n_in; (void)out_size; (void)ws_size;

    char* p = (char*)d_ws;
    auto alloc = [&](size_t b) { char* r = p; p += (b + 255) & ~(size_t)255; return r; };
    float* gg = (float*)alloc(2048ull * 32 * 4);                         // log-decay
    float* bb = (float*)alloc(2048ull * 32 * 4);                         // beta
    float* w_baT = (float*)alloc(64ull * 2048 * 4);                      // w_ba^T f32
    unsigned short* hsb  = (unsigned short*)alloc(2048ull * 2048 * 2);   // hs bf16
    unsigned short* woT  = (unsigned short*)alloc(2048ull * 4096 * 2);   // w_out^T bf16
    unsigned short* wqT  = (unsigned short*)alloc(12288ull * 2048 * 2);  // w_qkvz^T bf16
    unsigned short* qkvz = (unsigned short*)alloc(2048ull * 12288 * 2);  // projections bf16
    unsigned short* qb16 = (unsigned short*)alloc(2048ull * 2048 * 2);   // q normed bf16
    unsigned short* kb16 = (unsigned short*)alloc(2048ull * 2048 * 2);   // k normed bf16
    float* vv = (float*)alloc(2048ull * 4096 * 4);                       // v fp32
    float* oo = (float*)alloc(2048ull * 4096 * 4);                       // recurrence out
    unsigned short* yb = (unsigned short*)alloc(2048ull * 4096 * 2);     // normed bf16
    unsigned short* Wg  = (unsigned short*)alloc(1024ull * 8192 * 2);    // W [bhch][64][128]
    unsigned short* DlT = (unsigned short*)alloc(1024ull * 8192 * 2);    // Dloc^T [bhch][128][64]
    unsigned short* KtT = (unsigned short*)alloc(1024ull * 8192 * 2);    // Ktil^T [bhch][128][64]
    unsigned short* Pt  = (unsigned short*)alloc(1024ull * 4096 * 2);    // Ptil [bhch][64][64]
    float* lamg = (float*)alloc(1024ull * 64 * 4);                       // lambda per token
    float* l64g = (float*)alloc(1024ull * 4);                            // chunk decay
    // gemm2 split-K-4 partials (67.1 MB) reuse wqT (48 MB, dead after gemm1)
    // + head of qkvz (dead after norm_kernel) — contiguous since woT precedes.
    float* gpart = (float*)wqT;

    cvt_bf16_kernel<<<4096, 256, 0, stream>>>(hs, hsb, 2048 * 2048 / 4);
    transpose_cvt_kernel<<<dim3(12288 / 32, 2048 / 32), 256, 0, stream>>>(w_qkvz, wqT, 2048, 12288);
    transpose_cvt_kernel<<<dim3(2048 / 32, 4096 / 32), 256, 0, stream>>>(w_out, woT, 4096, 2048);
    transpose_f32_kernel<<<dim3(64 / 32, 2048 / 32), 256, 0, stream>>>(w_ba, w_baT, 2048, 64);
    gemm384_kernel<<<512, 512, 0, stream>>>(hsb, wqT, qkvz, 2048, 12288, 2048);
    bag_kernel<<<1024, 256, 0, stream>>>(hs, w_baT, A_log, dt_bias, gg, bb);
    conv_kernel<<<2048, 256, 0, stream>>>(qkvz, conv_w, qb16, kb16, vv);
    prep_kernel<<<1024, 256, 0, stream>>>(qb16, kb16, vv, gg, bb, Wg, DlT, KtT, Pt, lamg, l64g);
    recb_kernel<<<512, 256, 0, stream>>>(qb16, lamg, l64g, Wg, DlT, KtT, Pt, oo);
    norm_kernel<<<16384, 256, 0, stream>>>(oo, qkvz, norm_w, yb);
    gemm256_kernel<<<256, 512, 0, stream>>>(yb, woT, gpart, 2048, 2048, 4096, 1024);
    add_out4_kernel<<<4096, 256, 0, stream>>>(gpart, out, 2048 * 2048 / 4);
}

// Round 6
// 646.419 us; speedup vs baseline: 1.1756x; 1.0705x over previous
//
#include <hip/hip_runtime.h>
#include <stdint.h>

#define AS1 __attribute__((address_space(1)))
#define AS3 __attribute__((address_space(3)))

typedef __bf16 bf16x8 __attribute__((ext_vector_type(8)));
typedef float f32x4 __attribute__((ext_vector_type(4)));

static __device__ __forceinline__ float bf2f(unsigned short u) {
    union { unsigned int i; float f; } x; x.i = ((unsigned int)u) << 16; return x.f;
}
static __device__ __forceinline__ unsigned short f2bf(float f) {
    union { float f; unsigned int i; } x; x.f = f;
    unsigned int u = x.i;
    unsigned int r = (u + 0x7fffu + ((u >> 16) & 1u)) >> 16;  // RNE
    return (unsigned short)r;
}

static __device__ __forceinline__ void gll16(const void* g, void* l) {
    __builtin_amdgcn_global_load_lds((const AS1 unsigned int*)g,
                                     (AS3 unsigned int*)l, 16, 0, 0);
}

// ---------------- f32 -> bf16 elementwise (vec4) ----------------
__global__ __launch_bounds__(256) void cvt_bf16_kernel(
    const float* __restrict__ src, unsigned short* __restrict__ dst, int n4) {
    int i = blockIdx.x * 256 + threadIdx.x;
    if (i >= n4) return;
    float4 v = ((const float4*)src)[i];
    ushort4 o;
    o.x = f2bf(v.x); o.y = f2bf(v.y); o.z = f2bf(v.z); o.w = f2bf(v.w);
    ((ushort4*)dst)[i] = o;
}

// ---------------- f32 [R,C] -> bf16 [C,R] transpose ----------------
__global__ __launch_bounds__(256) void transpose_cvt_kernel(
    const float* __restrict__ src, unsigned short* __restrict__ dst, int R, int C) {
    __shared__ float tile[32][33];
    int x = threadIdx.x & 31, y = threadIdx.x >> 5;
    int c0 = blockIdx.x * 32, r0 = blockIdx.y * 32;
#pragma unroll
    for (int i = 0; i < 4; i++)
        tile[y + i * 8][x] = src[(size_t)(r0 + y + i * 8) * C + (c0 + x)];
    __syncthreads();
#pragma unroll
    for (int i = 0; i < 4; i++)
        dst[(size_t)(c0 + y + i * 8) * R + (r0 + x)] = f2bf(tile[x][y + i * 8]);
}

// ---------------- pack w_ba [2048][64] -> interleaved float4 stream --------
// w_pk float4[g], g = i*64 + c  holds {w_ba[4i+0][c], .., w_ba[4i+3][c]}.
// In bag's inner loop lane c reads g = i*64 + c: 64 consecutive float4 =
// one coalesced 1 KB transaction (the round-4 layout was 64 lines/instr).
__global__ __launch_bounds__(256) void pack_wba_kernel(
    const float* __restrict__ src, float* __restrict__ dst) {
    int g = blockIdx.x * 256 + threadIdx.x;  // [0, 32768)
    int i = g >> 6, c = g & 63;
    float4 v;
    v.x = src[(size_t)(4 * i + 0) * 64 + c];
    v.y = src[(size_t)(4 * i + 1) * 64 + c];
    v.z = src[(size_t)(4 * i + 2) * 64 + c];
    v.w = src[(size_t)(4 * i + 3) * 64 + c];
    ((float4*)dst)[g] = v;
}

#define FENCE asm volatile("" ::: "memory")
#define BARRIER { FENCE; __builtin_amdgcn_s_barrier(); FENCE; }
#define LGKM0 asm volatile("s_waitcnt lgkmcnt(0)" ::: "memory")

// ---------------- 128x384 8-phase bf16 GEMM: C = A[M,K] * Bt[N,K]^T --------
// m201-class schedule retiled so gemm1's grid is 16 x 32 = 512 tiles =
// EXACTLY 2 full rounds on 256 CUs. Half-tile unit: 128 rows x 64 k = 16 KB,
// 16 subtiles [16][32], st_16x32 swizzle, staged linearly by global_load_lds
// with inverse-swizzled global source (rule #21). LDS = 8 slots x 16 KB.
// Per K-tile: ph1 stage A(g+1); ph2 B0(g+2); ph3 B1(g+2); ph4 B2(g+2) +
// vmcnt(6). 8 waves as 2(m) x 4(n): wave tile 64 x 96, acc[4][6].
__global__ __launch_bounds__(512, 2) void gemm384_kernel(
    const unsigned short* __restrict__ A, const unsigned short* __restrict__ Bt,
    unsigned short* __restrict__ C, int M, int N, int K) {
    __shared__ __align__(16) unsigned short SH[65536];  // 128 KiB
    int tid = threadIdx.x;
    int lane = tid & 63, w = tid >> 6;
    int wr = w >> 2, wc = w & 3;
    int qd = lane >> 4, rc = lane & 15;

    int wg = blockIdx.x;                 // 512 = 8 xcd * (16 m * 4 nsub)
    int xcd = wg & 7, loc = wg >> 3;
    int m0 = (loc & 15) * 128;
    int n0 = (xcd * 4 + (loc >> 4)) * 384;

    const int NT = K >> 6;               // K-tiles
    const int sK = K << 7;               // u16 elems per 128-row half-tile

    size_t sr[2];
#pragma unroll
    for (int j = 0; j < 2; j++) {
        int bu = j * 4096 + tid * 8;     // u16 offset within half-tile
        int sub = bu >> 9;
        int b = bu & 511;
        int bp = b ^ (((b >> 8) & 1) << 4);
        int row = ((sub >> 1) << 4) + (bp >> 5);
        int col = ((sub & 1) << 5) + (bp & 31);
        sr[j] = (size_t)row * K + col;
    }
    const unsigned short* Ab = A + (size_t)m0 * K;
    const unsigned short* Bb = Bt + (size_t)n0 * K;

    const int foff = (rc * 32 + qd * 8) ^ (((rc >> 3) & 1) << 4);
    int bC[6];
#pragma unroll
    for (int fj = 0; fj < 6; fj++) {
        int nb = wc * 96 + fj * 16;
        bC[fj] = (1 + (nb >> 7)) * 16384 + ((nb & 127) >> 4) * 1024 + foff;
    }

    f32x4 acc[4][6];
#pragma unroll
    for (int i = 0; i < 4; i++)
#pragma unroll
        for (int j = 0; j < 6; j++)
#pragma unroll
            for (int r = 0; r < 4; r++) acc[i][j][r] = 0.f;

    bf16x8 aq[2][2], bq[6][2];

#define STG(u, t)                                                             \
    {                                                                         \
        const unsigned short* s_ =                                            \
            ((u) == 0 ? Ab : Bb + (size_t)((u)-1) * sK) + (size_t)(t) * 64;   \
        int d_ = (((u)*2 + ((t)&1)) << 13) + tid * 8;                         \
        gll16(s_ + sr[0], &SH[d_]);                                           \
        gll16(s_ + sr[1], &SH[d_ + 4096]);                                    \
    }

#define LDAQ(p, QR)                                                           \
    {                                                                         \
        _Pragma("unroll") for (int fi = 0; fi < 2; fi++)                      \
            _Pragma("unroll") for (int ks = 0; ks < 2; ks++)                  \
                aq[fi][ks] = *(const bf16x8*)&SH[(p)*8192 +                   \
                    (wr * 4 + (QR)*2 + fi) * 1024 + ks * 512 + foff];         \
    }

#define LDBQ(p)                                                               \
    {                                                                         \
        _Pragma("unroll") for (int fj = 0; fj < 6; fj++)                      \
            _Pragma("unroll") for (int ks = 0; ks < 2; ks++)                  \
                bq[fj][ks] = *(const bf16x8*)&SH[bC[fj] + (p)*8192 + ks*512]; \
    }

#define MFMAQ(QR, QC)                                                         \
    {                                                                         \
        _Pragma("unroll") for (int fi = 0; fi < 2; fi++)                      \
            _Pragma("unroll") for (int fj = 0; fj < 3; fj++)                  \
                _Pragma("unroll") for (int ks = 0; ks < 2; ks++)              \
                    acc[(QR)*2 + fi][(QC)*3 + fj] =                           \
                        __builtin_amdgcn_mfma_f32_16x16x32_bf16(              \
                            aq[fi][ks], bq[(QC)*3 + fj][ks],                  \
                            acc[(QR)*2 + fi][(QC)*3 + fj], 0, 0, 0);          \
    }

    // ---- prologue: tile0 full + B0,B1,B2 of tile1; 3 stages left in flight
    STG(0, 0); STG(1, 0); STG(2, 0); STG(3, 0);
    STG(1, 1); STG(2, 1); STG(3, 1);
    asm volatile("s_waitcnt vmcnt(6)" ::: "memory");
    BARRIER;

    for (int g = 0; g < NT; ++g) {
        const int p = g & 1;
        // phase 1: quadrant (0,0)
        LDAQ(p, 0);
        LDBQ(p);
        if (g + 1 < NT) STG(0, g + 1);
        BARRIER; LGKM0;
        __builtin_amdgcn_s_setprio(1);
        MFMAQ(0, 0);
        __builtin_amdgcn_s_setprio(0);
        BARRIER;
        // phase 2: quadrant (0,1)
        if (g + 2 < NT) STG(1, g + 2);
        BARRIER; LGKM0;
        __builtin_amdgcn_s_setprio(1);
        MFMAQ(0, 1);
        __builtin_amdgcn_s_setprio(0);
        BARRIER;
        // phase 3: quadrant (1,0)
        LDAQ(p, 1);
        if (g + 2 < NT) STG(2, g + 2);
        BARRIER; LGKM0;
        __builtin_amdgcn_s_setprio(1);
        MFMAQ(1, 0);
        __builtin_amdgcn_s_setprio(0);
        BARRIER;
        // phase 4: quadrant (1,1) + K-tile boundary counted wait
        if (g + 2 < NT) STG(3, g + 2);
        if (g < NT - 2) { asm volatile("s_waitcnt vmcnt(6)" ::: "memory"); }
        else            { asm volatile("s_waitcnt vmcnt(0)" ::: "memory"); }
        BARRIER; LGKM0;
        __builtin_amdgcn_s_setprio(1);
        MFMAQ(1, 1);
        __builtin_amdgcn_s_setprio(0);
        BARRIER;
    }

#undef STG
#undef LDAQ
#undef LDBQ
#undef MFMAQ

#pragma unroll
    for (int mi = 0; mi < 4; mi++) {
        int row = m0 + wr * 64 + mi * 16 + qd * 4;
#pragma unroll
        for (int fj = 0; fj < 6; fj++) {
            int col = n0 + wc * 96 + fj * 16 + rc;
#pragma unroll
            for (int r = 0; r < 4; r++)
                C[(size_t)(row + r) * N + col] = f2bf(acc[mi][fj][r]);
        }
    }
}

// ---------------- 256x256 8-phase bf16 GEMM, split-K f32 partials ----------
__global__ __launch_bounds__(512, 2) void gemm256_kernel(
    const unsigned short* __restrict__ A, const unsigned short* __restrict__ Bt,
    float* __restrict__ C, int M, int N, int K, int Ksl) {
    __shared__ __align__(16) unsigned short SH[65536];  // 128 KiB
    int tid = threadIdx.x;
    int lane = tid & 63, w = tid >> 6;
    int wr = w >> 2, wc = w & 3;
    int qd = lane >> 4, rc = lane & 15;

    int wg = blockIdx.x;                 // 256 = 4 k-slices x 64 tiles
    int zz = wg >> 6;
    int loc = wg & 63;
    int m0 = (loc >> 3) * 256;
    int n0 = (loc & 7) * 256;
    const int NT = Ksl >> 6;
    const int sK = K << 7;

    size_t sr[2];
#pragma unroll
    for (int j = 0; j < 2; j++) {
        int bu = j * 4096 + tid * 8;
        int sub = bu >> 9;
        int b = bu & 511;
        int bp = b ^ (((b >> 8) & 1) << 4);
        int row = ((sub >> 1) << 4) + (bp >> 5);
        int col = ((sub & 1) << 5) + (bp & 31);
        sr[j] = (size_t)row * K + col;
    }
    const unsigned short* Ab = A + (size_t)m0 * K + (size_t)zz * Ksl;
    const unsigned short* Bb = Bt + (size_t)n0 * K + (size_t)zz * Ksl;

    const int foff = (rc * 32 + qd * 8) ^ (((rc >> 3) & 1) << 4);
    const int Ah = wr;
    const int Bh = wc >> 1;
    const int brow4 = (wc & 1) * 4;

    f32x4 acc[8][4];
#pragma unroll
    for (int i = 0; i < 8; i++)
#pragma unroll
        for (int j = 0; j < 4; j++)
#pragma unroll
            for (int r = 0; r < 4; r++) acc[i][j][r] = 0.f;

    bf16x8 aq[4][2], bq[4][2];

#define STG(mat, h, t)                                                        \
    {                                                                         \
        const unsigned short* s_ = ((mat) ? Bb : Ab) + (h) * sK + (t) * 64;   \
        int d_ = ((mat) << 15) + (((((t) & 1) * 2 + (h))) << 13) + tid * 8;   \
        gll16(s_ + sr[0], &SH[d_]);                                           \
        gll16(s_ + sr[1], &SH[d_ + 4096]);                                    \
    }

#define LDAQ(p, QR)                                                           \
    {                                                                         \
        int ab_ = ((p) * 2 + Ah) * 8192 + (QR) * 4096 + foff;                 \
        _Pragma("unroll") for (int fi = 0; fi < 4; fi++)                      \
            _Pragma("unroll") for (int ks = 0; ks < 2; ks++)                  \
                aq[fi][ks] = *(const bf16x8*)&SH[ab_ + (fi * 2 + ks) * 512];  \
    }

#define LDBQ(p)                                                               \
    {                                                                         \
        int bb_ = 32768 + ((p) * 2 + Bh) * 8192 + brow4 * 1024 + foff;        \
        _Pragma("unroll") for (int fg = 0; fg < 4; fg++)                      \
            _Pragma("unroll") for (int ks = 0; ks < 2; ks++)                  \
                bq[fg][ks] = *(const bf16x8*)&SH[bb_ + (fg * 2 + ks) * 512];  \
    }

#define MFMAQ(QR, QC)                                                         \
    {                                                                         \
        _Pragma("unroll") for (int fi = 0; fi < 4; fi++)                      \
            _Pragma("unroll") for (int fj = 0; fj < 2; fj++)                  \
                _Pragma("unroll") for (int ks = 0; ks < 2; ks++)              \
                    acc[(QR) * 4 + fi][(QC) * 2 + fj] =                       \
                        __builtin_amdgcn_mfma_f32_16x16x32_bf16(              \
                            aq[fi][ks], bq[(QC) * 2 + fj][ks],                \
                            acc[(QR) * 4 + fi][(QC) * 2 + fj], 0, 0, 0);      \
    }

    STG(0, 0, 0); STG(0, 1, 0); STG(1, 0, 0); STG(1, 1, 0);
    STG(1, 0, 1); STG(1, 1, 1); STG(0, 0, 1);
    asm volatile("s_waitcnt vmcnt(6)" ::: "memory");
    BARRIER;

    for (int g = 0; g < NT; ++g) {
        const int p = g & 1;
        LDAQ(p, 0);
        LDBQ(p);
        if (g + 1 < NT) STG(0, 1, g + 1);
        BARRIER; LGKM0;
        __builtin_amdgcn_s_setprio(1);
        MFMAQ(0, 0);
        __builtin_amdgcn_s_setprio(0);
        BARRIER;
        if (g + 2 < NT) STG(1, 0, g + 2);
        BARRIER; LGKM0;
        __builtin_amdgcn_s_setprio(1);
        MFMAQ(0, 1);
        __builtin_amdgcn_s_setprio(0);
        BARRIER;
        LDAQ(p, 1);
        if (g + 2 < NT) STG(1, 1, g + 2);
        BARRIER; LGKM0;
        __builtin_amdgcn_s_setprio(1);
        MFMAQ(1, 0);
        __builtin_amdgcn_s_setprio(0);
        BARRIER;
        if (g + 2 < NT) STG(0, 0, g + 2);
        if (g < NT - 2) { asm volatile("s_waitcnt vmcnt(6)" ::: "memory"); }
        else            { asm volatile("s_waitcnt vmcnt(0)" ::: "memory"); }
        BARRIER; LGKM0;
        __builtin_amdgcn_s_setprio(1);
        MFMAQ(1, 1);
        __builtin_amdgcn_s_setprio(0);
        BARRIER;
    }

#undef STG
#undef LDAQ
#undef LDBQ
#undef MFMAQ

    float* Cf = C + (size_t)zz * M * N;
#pragma unroll
    for (int mi = 0; mi < 8; mi++) {
        int row = m0 + wr * 128 + mi * 16 + qd * 4;
#pragma unroll
        for (int fg = 0; fg < 4; fg++) {
            int col = n0 + wc * 64 + fg * 16 + rc;
#pragma unroll
            for (int r = 0; r < 4; r++)
                Cf[(size_t)(row + r) * N + col] = acc[mi][fg][r];
        }
    }
}

// ---------------- split-K partial sum: out = p[0]+p[1]+p[2]+p[3] ----------------
__global__ __launch_bounds__(256) void add_out4_kernel(
    const float* __restrict__ p, float* __restrict__ out, int n4) {
    int i = blockIdx.x * 256 + threadIdx.x;
    if (i >= n4) return;
    size_t st = (size_t)n4 * 4;
    float4 a = ((const float4*)p)[i];
    float4 b = ((const float4*)(p + st))[i];
    float4 c = ((const float4*)(p + 2 * st))[i];
    float4 d = ((const float4*)(p + 3 * st))[i];
    ((float4*)out)[i] = make_float4(a.x + b.x + c.x + d.x, a.y + b.y + c.y + d.y,
                                    a.z + b.z + c.z + d.z, a.w + b.w + c.w + d.w);
}

// ---------------- ba GEMM + beta/g computation (coalesced w_pk) ------------
// out[t][c] = sum_k hs[t][k] * w_ba[k][c].  Grid 512 (4 tokens/block),
// thread = (col c 0..63, kc 0..3 of 512-k chunks).  w_pk is the interleaved
// pack: lane c's float4 at iter i sits at (kc*128+i)*64 + c -> 64 consecutive
// float4 = one coalesced 1 KB transaction (fixes round-4's 64-lines/instr).
// hs addresses are wave-uniform (broadcast).  LDS reduce over kc.
__global__ __launch_bounds__(256) void bag_kernel(
    const float* __restrict__ hs, const float* __restrict__ w_pk,
    const float* __restrict__ A_log, const float* __restrict__ dt_bias,
    float* __restrict__ gg, float* __restrict__ bb) {
    __shared__ float ps[4][4][64];
    int tid = threadIdx.x;
    int col = tid & 63, kc = tid >> 6;
    int t0 = blockIdx.x * 4;
    const float4* wp = (const float4*)w_pk + (size_t)kc * 128 * 64 + col;
    const float4* h0 = (const float4*)(hs + (size_t)(t0 + 0) * 2048 + kc * 512);
    const float4* h1 = (const float4*)(hs + (size_t)(t0 + 1) * 2048 + kc * 512);
    const float4* h2 = (const float4*)(hs + (size_t)(t0 + 2) * 2048 + kc * 512);
    const float4* h3 = (const float4*)(hs + (size_t)(t0 + 3) * 2048 + kc * 512);
    float a0 = 0.f, a1 = 0.f, a2 = 0.f, a3 = 0.f;
#pragma unroll 4
    for (int i = 0; i < 128; i++) {
        float4 wv = wp[(size_t)i * 64];
        float4 x0 = h0[i];
        float4 x1 = h1[i];
        float4 x2 = h2[i];
        float4 x3 = h3[i];
        a0 += wv.x * x0.x + wv.y * x0.y + wv.z * x0.z + wv.w * x0.w;
        a1 += wv.x * x1.x + wv.y * x1.y + wv.z * x1.z + wv.w * x1.w;
        a2 += wv.x * x2.x + wv.y * x2.y + wv.z * x2.z + wv.w * x2.w;
        a3 += wv.x * x3.x + wv.y * x3.y + wv.z * x3.z + wv.w * x3.w;
    }
    ps[kc][0][col] = a0;
    ps[kc][1][col] = a1;
    ps[kc][2][col] = a2;
    ps[kc][3][col] = a3;
    __syncthreads();
    {
        int j = tid >> 6, c = tid & 63;
        float acc = ps[0][j][c] + ps[1][j][c] + ps[2][j][c] + ps[3][j][c];
        int t = t0 + j;
        int h = c >> 2, idx = c & 3;
        int vh = h * 2 + (idx & 1);
        if (idx < 2) {
            bb[t * 32 + vh] = 1.f / (1.f + expf(-acc));
        } else {
            float x = acc + dt_bias[vh];
            float sp = fmaxf(x, 0.f) + log1pf(expf(-fabsf(x)));
            gg[t * 32 + vh] = -expf(A_log[vh]) * sp;
        }
    }
}

// ---------------- depthwise causal conv(4) + silu + l2norm(q,k) ----------------
// blockIdx remapped so each XCD owns a contiguous 256-token span: the 3-row
// causal re-read of qkvz then hits the local L2 instead of re-fetching HBM.
__global__ __launch_bounds__(256) void conv_kernel(
    const unsigned short* __restrict__ qkvz, const float* __restrict__ conv_w,
    unsigned short* __restrict__ qb, unsigned short* __restrict__ kb,
    float* __restrict__ vv) {
    __shared__ float xs[8192];
    __shared__ float rs[32];
    int t = ((blockIdx.x & 7) << 8) + (blockIdx.x >> 3);  // XCD-chunked
    int s = t & 1023;
    int tid = threadIdx.x;
    size_t rowbase = (size_t)t * 12288;
#pragma unroll
    for (int i = 0; i < 4; i++) {
        int c = (i * 256 + tid) * 8;
        int d = c & 127;
        int col;
        if (c < 2048) col = (c >> 7) * 768 + d;
        else if (c < 4096) col = ((c - 2048) >> 7) * 768 + 128 + d;
        else { int vh2 = (c - 4096) >> 7; col = (vh2 >> 1) * 768 + 256 + (vh2 & 1) * 128 + d; }
        float wts[8][4];
#pragma unroll
        for (int e = 0; e < 8; e++) {
            float4 t4 = *(const float4*)(conv_w + (size_t)(c + e) * 4);
            wts[e][0] = t4.x; wts[e][1] = t4.y; wts[e][2] = t4.z; wts[e][3] = t4.w;
        }
        float acc[8] = {0.f, 0.f, 0.f, 0.f, 0.f, 0.f, 0.f, 0.f};
#pragma unroll
        for (int j = 0; j < 4; j++) {
            int ss = s - 3 + j;
            if (ss >= 0) {
                uint4 u = *(const uint4*)(qkvz + rowbase + (size_t)(j - 3) * 12288 + col);
                const unsigned short* us = (const unsigned short*)&u;
#pragma unroll
                for (int e = 0; e < 8; e++) acc[e] += bf2f(us[e]) * wts[e][j];
            }
        }
#pragma unroll
        for (int e = 0; e < 8; e++) xs[c + e] = acc[e] / (1.f + expf(-acc[e]));
    }
    __syncthreads();
    {
        int seg = tid >> 3, part = tid & 7;
        const float* pp = xs + seg * 128 + part * 16;
        float s2 = 0.f;
#pragma unroll
        for (int j = 0; j < 16; j++) s2 += pp[j] * pp[j];
        s2 += __shfl_xor(s2, 1);
        s2 += __shfl_xor(s2, 2);
        s2 += __shfl_xor(s2, 4);
        if (part == 0) rs[seg] = rsqrtf(s2 + 1e-6f);
    }
    __syncthreads();
    const float QS = 0.08838834764831845f;  // 128^-0.5
#pragma unroll
    for (int i = 0; i < 4; i++) {
        int c = (i * 256 + tid) * 8;
        float x[8];
#pragma unroll
        for (int e = 0; e < 8; e++) x[e] = xs[c + e];
        if (c < 4096) {
            float sc = (c < 2048) ? rs[c >> 7] * QS : rs[((c - 2048) >> 7) + 16];
            uint4 o;
            o.x = (unsigned)f2bf(x[0] * sc) | ((unsigned)f2bf(x[1] * sc) << 16);
            o.y = (unsigned)f2bf(x[2] * sc) | ((unsigned)f2bf(x[3] * sc) << 16);
            o.z = (unsigned)f2bf(x[4] * sc) | ((unsigned)f2bf(x[5] * sc) << 16);
            o.w = (unsigned)f2bf(x[6] * sc) | ((unsigned)f2bf(x[7] * sc) << 16);
            if (c < 2048) *(uint4*)(qb + (size_t)t * 2048 + c) = o;
            else *(uint4*)(kb + (size_t)t * 2048 + c - 2048) = o;
        } else {
            float* vp = vv + (size_t)t * 4096 + c - 4096;
            *(float4*)vp = make_float4(x[0], x[1], x[2], x[3]);
            *(float4*)(vp + 4) = make_float4(x[4], x[5], x[6], x[7]);
        }
    }
}

// ---------------- delta-rule prep (parallel over 64 bh x 16 chunks) ----------------
__global__ __launch_bounds__(256, 2) void prep_kernel(
    const unsigned short* __restrict__ qb, const unsigned short* __restrict__ kb,
    const float* __restrict__ vv, const float* __restrict__ gg,
    const float* __restrict__ bb,
    unsigned short* __restrict__ Wg, unsigned short* __restrict__ DlT,
    unsigned short* __restrict__ KtT, unsigned short* __restrict__ Pt,
    float* __restrict__ lamg, float* __restrict__ l64g) {
    __shared__ __align__(16) unsigned short Tb[64 * 72];    // -beta_i E_ij A_ij (i>j)
    __shared__ __align__(16) unsigned short Xw[4][64 * 72]; // per-wave solutions [col][tok]
    __shared__ float Td[4 * 16 * 17];                       // +T diag blocks fp32
    __shared__ float RHSw[4][16 * 68];                      // per-wave stage scratch
    __shared__ float cc[64], bet[64], lam_s[64], ex64[64];

    int bid = blockIdx.x;            // bh*16 + ch
    int ch = bid & 15, bh = bid >> 4;
    int vh = bh & 31, b = bh >> 5;
    int hk = vh >> 1;
    int t0 = b * 1024 + ch * 64;
    int tid = threadIdx.x, wv = tid >> 6, lane = tid & 63;
    int qd = lane >> 4, rc = lane & 15;
    int rowb = (wv & 1) * 32;
    size_t obase = (size_t)bid * 8192;
    size_t pbase = (size_t)bid * 4096;

    // decay metadata (wave 0)
    if (tid < 64) {
        float x = gg[(size_t)(t0 + tid) * 32 + vh];
#pragma unroll
        for (int ofs = 1; ofs < 64; ofs <<= 1) {
            float up = __shfl_up(x, ofs, 64);
            if (tid >= ofs) x += up;
        }
        cc[tid] = x;
        float l = __expf(x);
        lam_s[tid] = l;
        float tot = __shfl(x, 63, 64);
        ex64[tid] = __expf(tot - x);
        bet[tid] = bb[(size_t)(t0 + tid) * 32 + vh];
        lamg[(size_t)bid * 64 + tid] = l;
        if (tid == 0) l64g[bid] = __expf(tot);
    }
    __syncthreads();

    // phase A: A = K K^T (waves 0,1) -> Tb/Td ; P = Q K^T (waves 2,3) -> Pt
    {
        const unsigned short* src = (wv >= 2) ? qb : kb;
        f32x4 acc[2][4];
#pragma unroll
        for (int tm = 0; tm < 2; tm++)
#pragma unroll
            for (int tn = 0; tn < 4; tn++)
#pragma unroll
                for (int r = 0; r < 4; r++) acc[tm][tn][r] = 0.f;
#pragma unroll
        for (int ks = 0; ks < 4; ks++) {
            bf16x8 af[2], bfr[4];
#pragma unroll
            for (int tm = 0; tm < 2; tm++) {
                int row = rowb + tm * 16 + rc;
                af[tm] = *(const bf16x8*)(src + ((size_t)(t0 + row) * 16 + hk) * 128 + ks * 32 + qd * 8);
            }
#pragma unroll
            for (int tn = 0; tn < 4; tn++)
                bfr[tn] = *(const bf16x8*)(kb + ((size_t)(t0 + tn * 16 + rc) * 16 + hk) * 128 + ks * 32 + qd * 8);
#pragma unroll
            for (int tm = 0; tm < 2; tm++)
#pragma unroll
                for (int tn = 0; tn < 4; tn++)
                    acc[tm][tn] = __builtin_amdgcn_mfma_f32_16x16x32_bf16(af[tm], bfr[tn], acc[tm][tn], 0, 0, 0);
        }
        if (wv < 2) {
#pragma unroll
            for (int tm = 0; tm < 2; tm++)
#pragma unroll
                for (int tn = 0; tn < 4; tn++)
#pragma unroll
                    for (int r = 0; r < 4; r++) {
                        int i = rowb + tm * 16 + qd * 4 + r;
                        int j = tn * 16 + rc;
                        float val = acc[tm][tn][r];
                        float tv = 0.f;
                        if (i > j) tv = bet[i] * __expf(cc[i] - cc[j]) * val;
                        Tb[i * 72 + j] = f2bf(-tv);
                        if ((i >> 4) == (j >> 4) && i > j)
                            Td[(i >> 4) * 272 + (i & 15) * 17 + (j & 15)] = tv;
                    }
        } else {
#pragma unroll
            for (int tm = 0; tm < 2; tm++)
#pragma unroll
                for (int tn = 0; tn < 4; tn++)
#pragma unroll
                    for (int r = 0; r < 4; r++) {
                        int i = rowb + tm * 16 + qd * 4 + r;
                        int j = tn * 16 + rc;
                        float ev = (i >= j) ? __expf(cc[i] - cc[j]) : 0.f;
                        Pt[pbase + i * 64 + j] = f2bf(ev * acc[tm][tn][r]);
                    }
        }
    }
    // KtT: Etil-folded K^T [dk][tok] straight from global (L2-hot)
    {
        int dk = tid >> 1, half = tid & 1;
#pragma unroll
        for (int j = 0; j < 4; j++) {
            unsigned short tmp[8];
#pragma unroll
            for (int e = 0; e < 8; e++) {
                int tok = half * 32 + j * 8 + e;
                tmp[e] = f2bf(bf2f(kb[((size_t)(t0 + tok) * 16 + hk) * 128 + dk]) * ex64[tok]);
            }
            *(uint4*)(KtT + obase + dk * 64 + half * 32 + j * 8) = *(const uint4*)tmp;
        }
    }
    __syncthreads();   // Tb/Td ready for all waves

    // per-wave forward substitution: wave wv owns col-batch cb = wv (64 cols)
    {
        int cb = wv;
        unsigned short* Xb = Xw[wv];
        float* RHS = RHSw[wv];
        for (int z = lane; z < 64 * 72 / 2; z += 64) ((unsigned int*)Xb)[z] = 0u;
#pragma unroll
        for (int B = 0; B < 4; B++) {
            f32x4 tacc[4];
#pragma unroll
            for (int cf = 0; cf < 4; cf++)
#pragma unroll
                for (int r = 0; r < 4; r++) {
                    int i = B * 16 + qd * 4 + r;
                    int c = cf * 16 + rc;
                    float v;
                    if (cb < 2)
                        v = bet[i] * vv[((size_t)(t0 + i) * 32 + vh) * 128 + cb * 64 + c];
                    else
                        v = bet[i] * lam_s[i] * bf2f(kb[((size_t)(t0 + i) * 16 + hk) * 128 + (cb - 2) * 64 + c]);
                    tacc[cf][r] = v;
                }
            __builtin_amdgcn_s_waitcnt(0xc07f);  // prior Xb writes (same wave) visible
            const int nks = (B + 1) >> 1;  // 0,1,1,2
#pragma unroll
            for (int ks = 0; ks < 2; ks++) {
                if (ks >= nks) break;
                bf16x8 af = *(const bf16x8*)&Tb[(B * 16 + rc) * 72 + ks * 32 + qd * 8];
#pragma unroll
                for (int cf = 0; cf < 4; cf++) {
                    bf16x8 bf_ = *(const bf16x8*)&Xb[(cf * 16 + rc) * 72 + ks * 32 + qd * 8];
                    tacc[cf] = __builtin_amdgcn_mfma_f32_16x16x32_bf16(af, bf_, tacc[cf], 0, 0, 0);
                }
            }
#pragma unroll
            for (int cf = 0; cf < 4; cf++)
#pragma unroll
                for (int r = 0; r < 4; r++)
                    RHS[(qd * 4 + r) * 68 + cf * 16 + rc] = tacc[cf][r];
            __builtin_amdgcn_s_waitcnt(0xc07f);  // RHS visible for transposed read
            {
                float d[16];
#pragma unroll
                for (int i2 = 0; i2 < 16; i2++) d[i2] = RHS[i2 * 68 + lane];
#pragma unroll
                for (int i2 = 1; i2 < 16; i2++)
#pragma unroll
                    for (int j2 = 0; j2 < i2; j2++)
                        d[i2] -= Td[B * 272 + i2 * 17 + j2] * d[j2];
#pragma unroll
                for (int i2 = 0; i2 < 16; i2++)
                    Xb[lane * 72 + B * 16 + i2] = f2bf(d[i2]);
            }
        }
        __builtin_amdgcn_s_waitcnt(0xc07f);
        // write out this wave's batch
        if (cb < 2) {  // Dloc^T rows [dv = cb*64+lane][tok]
#pragma unroll
            for (int j = 0; j < 8; j++) {
                uint4 u = *(const uint4*)&Xb[lane * 72 + j * 8];
                *(uint4*)(DlT + obase + (size_t)(cb * 64 + lane) * 64 + j * 8) = u;
            }
        } else {  // W rows [tok = lane][dk]: transpose from Xb
#pragma unroll
            for (int dq = 0; dq < 8; dq++) {
                unsigned short tmp[8];
#pragma unroll
                for (int e = 0; e < 8; e++)
                    tmp[e] = Xb[(dq * 8 + e) * 72 + lane];
                *(uint4*)(Wg + obase + (size_t)lane * 128 + (cb - 2) * 64 + dq * 8) = *(const uint4*)tmp;
            }
        }
    }
}

// ---------------- serial inter-chunk scan (lean) ----------------
__global__ __launch_bounds__(256, 2) void recb_kernel(
    const unsigned short* __restrict__ qb, const float* __restrict__ lamg,
    const float* __restrict__ l64g, const unsigned short* __restrict__ Wg,
    const unsigned short* __restrict__ DlT, const unsigned short* __restrict__ KtT,
    const unsigned short* __restrict__ Pt, float* __restrict__ oo) {
    __shared__ __align__(16) unsigned short St[16 * 136];  // S^T bf16 [dv][dk]
    __shared__ __align__(16) unsigned short Dls[16 * 72];  // Dloc^T -> D'^T slice
    int bid = blockIdx.x;
    int slice = bid >> 6;           // slice-major: same head -> same XCD
    int rest = bid & 63;
    int vh = rest & 31, b = rest >> 5;
    int bh = b * 32 + vh;
    int hk = vh >> 1, dvo = slice * 16, tb = b * 1024;
    int tid = threadIdx.x, wv = tid >> 6, lane = tid & 63;
    int qd = lane >> 4, rc = lane & 15;

    f32x4 sacc[2];
#pragma unroll
    for (int tm = 0; tm < 2; tm++)
#pragma unroll
        for (int r = 0; r < 4; r++) sacc[tm][r] = 0.f;
    for (int z = tid; z < 16 * 136 / 2; z += 256) ((unsigned int*)St)[z] = 0u;
    __syncthreads();

#pragma unroll 1
    for (int ch = 0; ch < 16; ch++) {
        int bhch = bh * 16 + ch;
        size_t obase = (size_t)bhch * 8192;
        size_t pbase = (size_t)bhch * 4096;
        int t0 = tb + ch * 64;
        if (tid < 128) {
            int row = tid >> 3, t8 = (tid & 7) * 8;
            uint4 u = *(const uint4*)(DlT + obase + (dvo + row) * 64 + t8);
            *(uint4*)&Dls[row * 72 + t8] = u;
        }
        __syncthreads();
        {
            f32x4 uacc;
#pragma unroll
            for (int r = 0; r < 4; r++) uacc[r] = 0.f;
#pragma unroll
            for (int ks = 0; ks < 4; ks++) {
                bf16x8 a_ = *(const bf16x8*)&St[rc * 136 + ks * 32 + qd * 8];
                bf16x8 b_ = *(const bf16x8*)(Wg + obase + (size_t)(wv * 16 + rc) * 128 + ks * 32 + qd * 8);
                uacc = __builtin_amdgcn_mfma_f32_16x16x32_bf16(a_, b_, uacc, 0, 0, 0);
            }
#pragma unroll
            for (int r = 0; r < 4; r++) {
                int idx = (qd * 4 + r) * 72 + wv * 16 + rc;
                Dls[idx] = f2bf(bf2f(Dls[idx]) - uacc[r]);
            }
        }
        __syncthreads();
        {
            f32x4 qacc;
#pragma unroll
            for (int r = 0; r < 4; r++) qacc[r] = 0.f;
#pragma unroll
            for (int ks = 0; ks < 4; ks++) {
                bf16x8 a_ = *(const bf16x8*)(qb + ((size_t)(t0 + wv * 16 + rc) * 16 + hk) * 128 + ks * 32 + qd * 8);
                bf16x8 b_ = *(const bf16x8*)&St[rc * 136 + ks * 32 + qd * 8];
                qacc = __builtin_amdgcn_mfma_f32_16x16x32_bf16(a_, b_, qacc, 0, 0, 0);
            }
            bf16x8 bd[2];
#pragma unroll
            for (int ks = 0; ks < 2; ks++)
                bd[ks] = *(const bf16x8*)&Dls[rc * 72 + ks * 32 + qd * 8];
            f32x4 oacc;
#pragma unroll
            for (int r = 0; r < 4; r++)
                oacc[r] = lamg[(size_t)bhch * 64 + wv * 16 + qd * 4 + r] * qacc[r];
#pragma unroll
            for (int ks = 0; ks < 2; ks++) {
                bf16x8 a_ = *(const bf16x8*)(Pt + pbase + (size_t)(wv * 16 + rc) * 64 + ks * 32 + qd * 8);
                oacc = __builtin_amdgcn_mfma_f32_16x16x32_bf16(a_, bd[ks], oacc, 0, 0, 0);
            }
#pragma unroll
            for (int r = 0; r < 4; r++)
                oo[((size_t)(t0 + wv * 16 + qd * 4 + r) * 32 + vh) * 128 + dvo + rc] = oacc[r];
            float l64 = l64g[bhch];
#pragma unroll
            for (int tm = 0; tm < 2; tm++) {
#pragma unroll
                for (int r = 0; r < 4; r++) sacc[tm][r] *= l64;
#pragma unroll
                for (int ks = 0; ks < 2; ks++) {
                    bf16x8 a_ = *(const bf16x8*)(KtT + obase + (size_t)(wv * 32 + tm * 16 + rc) * 64 + ks * 32 + qd * 8);
                    sacc[tm] = __builtin_amdgcn_mfma_f32_16x16x32_bf16(a_, bd[ks], sacc[tm], 0, 0, 0);
                }
            }
        }
        __syncthreads();
#pragma unroll
        for (int tm = 0; tm < 2; tm++)
#pragma unroll
            for (int r = 0; r < 4; r++)
                St[rc * 136 + wv * 32 + tm * 16 + qd * 4 + r] = f2bf(sacc[tm][r]);
        __syncthreads();
    }
}

// ---------------- gated RMSNorm + bf16 convert ----------------
__global__ __launch_bounds__(256) void norm_kernel(
    const float* __restrict__ oo, const unsigned short* __restrict__ qkvz,
    const float* __restrict__ norm_w, unsigned short* __restrict__ yb) {
    int w = threadIdx.x >> 6, lane = threadIdx.x & 63;
    int g = blockIdx.x * 4 + w;
    int t = g >> 5, vh = g & 31;
    size_t ob = (size_t)g * 128;
    size_t zb = (size_t)t * 12288 + (size_t)(vh >> 1) * 768 + 512 + (vh & 1) * 128;
    float x0 = oo[ob + lane], x1 = oo[ob + 64 + lane];
    float z0 = bf2f(qkvz[zb + lane]), z1 = bf2f(qkvz[zb + 64 + lane]);
    float xg0 = x0 * (z0 / (1.f + expf(-z0)));
    float xg1 = x1 * (z1 / (1.f + expf(-z1)));
    float s = xg0 * xg0 + xg1 * xg1;
    s += __shfl_xor(s, 1);
    s += __shfl_xor(s, 2);
    s += __shfl_xor(s, 4);
    s += __shfl_xor(s, 8);
    s += __shfl_xor(s, 16);
    s += __shfl_xor(s, 32);
    float r = rsqrtf(s * (1.f / 128.f) + 1e-6f);
    size_t y0 = (size_t)t * 4096 + (size_t)vh * 128;
    yb[y0 + lane] = f2bf(xg0 * r * norm_w[lane]);
    yb[y0 + 64 + lane] = f2bf(xg1 * r * norm_w[64 + lane]);
}

extern "C" void kernel_launch(void* const* d_in, const int* in_sizes, int n_in,
                              void* d_out, int out_size, void* d_ws, size_t ws_size,
                              hipStream_t stream) {
    const float* hs      = (const float*)d_in[0];
    const float* w_qkvz  = (const float*)d_in[1];
    const float* w_ba    = (const float*)d_in[2];
    const float* conv_w  = (const float*)d_in[3];
    const float* dt_bias = (const float*)d_in[4];
    const float* A_log   = (const float*)d_in[5];
    const float* norm_w  = (const float*)d_in[6];
    const float* w_out   = (const float*)d_in[7];
    float* out = (float*)d_out;
    (void)in_sizes; (void)n_in; (void)out_size; (void)ws_size;

    char* p = (char*)d_ws;
    auto alloc = [&](size_t b) { char* r = p; p += (b + 255) & ~(size_t)255; return r; };
    float* gg = (float*)alloc(2048ull * 32 * 4);                         // log-decay
    float* bb = (float*)alloc(2048ull * 32 * 4);                         // beta
    float* w_pk = (float*)alloc(64ull * 2048 * 4);                       // w_ba packed
    unsigned short* hsb  = (unsigned short*)alloc(2048ull * 2048 * 2);   // hs bf16
    unsigned short* woT  = (unsigned short*)alloc(2048ull * 4096 * 2);   // w_out^T bf16
    unsigned short* wqT  = (unsigned short*)alloc(12288ull * 2048 * 2);  // w_qkvz^T bf16
    unsigned short* qkvz = (unsigned short*)alloc(2048ull * 12288 * 2);  // projections bf16
    unsigned short* qb16 = (unsigned short*)alloc(2048ull * 2048 * 2);   // q normed bf16
    unsigned short* kb16 = (unsigned short*)alloc(2048ull * 2048 * 2);   // k normed bf16
    float* vv = (float*)alloc(2048ull * 4096 * 4);                       // v fp32
    float* oo = (float*)alloc(2048ull * 4096 * 4);                       // recurrence out
    unsigned short* yb = (unsigned short*)alloc(2048ull * 4096 * 2);     // normed bf16
    unsigned short* Wg  = (unsigned short*)alloc(1024ull * 8192 * 2);    // W [bhch][64][128]
    unsigned short* DlT = (unsigned short*)alloc(1024ull * 8192 * 2);    // Dloc^T [bhch][128][64]
    unsigned short* KtT = (unsigned short*)alloc(1024ull * 8192 * 2);    // Ktil^T [bhch][128][64]
    unsigned short* Pt  = (unsigned short*)alloc(1024ull * 4096 * 2);    // Ptil [bhch][64][64]
    float* lamg = (float*)alloc(1024ull * 64 * 4);                       // lambda per token
    float* l64g = (float*)alloc(1024ull * 4);                            // chunk decay
    // gemm2 split-K-4 partials (67.1 MB) reuse wqT (48 MB, dead after gemm1)
    // + head of qkvz (dead after norm_kernel) — contiguous since woT precedes.
    float* gpart = (float*)wqT;

    cvt_bf16_kernel<<<4096, 256, 0, stream>>>(hs, hsb, 2048 * 2048 / 4);
    transpose_cvt_kernel<<<dim3(12288 / 32, 2048 / 32), 256, 0, stream>>>(w_qkvz, wqT, 2048, 12288);
    transpose_cvt_kernel<<<dim3(2048 / 32, 4096 / 32), 256, 0, stream>>>(w_out, woT, 4096, 2048);
    pack_wba_kernel<<<128, 256, 0, stream>>>(w_ba, w_pk);
    gemm384_kernel<<<512, 512, 0, stream>>>(hsb, wqT, qkvz, 2048, 12288, 2048);
    bag_kernel<<<512, 256, 0, stream>>>(hs, w_pk, A_log, dt_bias, gg, bb);
    conv_kernel<<<2048, 256, 0, stream>>>(qkvz, conv_w, qb16, kb16, vv);
    prep_kernel<<<1024, 256, 0, stream>>>(qb16, kb16, vv, gg, bb, Wg, DlT, KtT, Pt, lamg, l64g);
    recb_kernel<<<512, 256, 0, stream>>>(qb16, lamg, l64g, Wg, DlT, KtT, Pt, oo);
    norm_kernel<<<16384, 256, 0, stream>>>(oo, qkvz, norm_w, yb);
    gemm256_kernel<<<256, 512, 0, stream>>>(yb, woT, gpart, 2048, 2048, 4096, 1024);
    add_out4_kernel<<<4096, 256, 0, stream>>>(gpart, out, 2048 * 2048 / 4);
}

// Round 7
// 645.681 us; speedup vs baseline: 1.1769x; 1.0011x over previous
//
#include <hip/hip_runtime.h>
#include <stdint.h>

#define AS1 __attribute__((address_space(1)))
#define AS3 __attribute__((address_space(3)))

typedef __bf16 bf16x8 __attribute__((ext_vector_type(8)));
typedef float f32x4 __attribute__((ext_vector_type(4)));

static __device__ __forceinline__ float bf2f(unsigned short u) {
    union { unsigned int i; float f; } x; x.i = ((unsigned int)u) << 16; return x.f;
}
static __device__ __forceinline__ unsigned short f2bf(float f) {
    union { float f; unsigned int i; } x; x.f = f;
    unsigned int u = x.i;
    unsigned int r = (u + 0x7fffu + ((u >> 16) & 1u)) >> 16;  // RNE
    return (unsigned short)r;
}

static __device__ __forceinline__ void gll16(const void* g, void* l) {
    __builtin_amdgcn_global_load_lds((const AS1 unsigned int*)g,
                                     (AS3 unsigned int*)l, 16, 0, 0);
}

// ---------------- f32 -> bf16 elementwise (vec4) ----------------
__global__ __launch_bounds__(256) void cvt_bf16_kernel(
    const float* __restrict__ src, unsigned short* __restrict__ dst, int n4) {
    int i = blockIdx.x * 256 + threadIdx.x;
    if (i >= n4) return;
    float4 v = ((const float4*)src)[i];
    ushort4 o;
    o.x = f2bf(v.x); o.y = f2bf(v.y); o.z = f2bf(v.z); o.w = f2bf(v.w);
    ((ushort4*)dst)[i] = o;
}

// ---------------- f32 [R,C] -> bf16 [C,R] transpose ----------------
__global__ __launch_bounds__(256) void transpose_cvt_kernel(
    const float* __restrict__ src, unsigned short* __restrict__ dst, int R, int C) {
    __shared__ float tile[32][33];
    int x = threadIdx.x & 31, y = threadIdx.x >> 5;
    int c0 = blockIdx.x * 32, r0 = blockIdx.y * 32;
#pragma unroll
    for (int i = 0; i < 4; i++)
        tile[y + i * 8][x] = src[(size_t)(r0 + y + i * 8) * C + (c0 + x)];
    __syncthreads();
#pragma unroll
    for (int i = 0; i < 4; i++)
        dst[(size_t)(c0 + y + i * 8) * R + (r0 + x)] = f2bf(tile[x][y + i * 8]);
}

// ---------------- pack w_ba [2048][64] -> interleaved float4 stream --------
__global__ __launch_bounds__(256) void pack_wba_kernel(
    const float* __restrict__ src, float* __restrict__ dst) {
    int g = blockIdx.x * 256 + threadIdx.x;  // [0, 32768)
    int i = g >> 6, c = g & 63;
    float4 v;
    v.x = src[(size_t)(4 * i + 0) * 64 + c];
    v.y = src[(size_t)(4 * i + 1) * 64 + c];
    v.z = src[(size_t)(4 * i + 2) * 64 + c];
    v.w = src[(size_t)(4 * i + 3) * 64 + c];
    ((float4*)dst)[g] = v;
}

#define FENCE asm volatile("" ::: "memory")
#define BARRIER { FENCE; __builtin_amdgcn_s_barrier(); FENCE; }
#define LGKM0 asm volatile("s_waitcnt lgkmcnt(0)" ::: "memory")

// ---------------- 128x384 merged-phase bf16 GEMM: C = A * Bt^T -------------
// Round-6 post-mortem: 8 barriers/K-tile with 12 MFMA per barrier-pair left
// MfmaUtil at 36% (barrier/drain stall, cf. m233). Merged to 2 phases per
// K-tile (4 barriers, 24 MFMA per pair). Hazard proof:
//  - STG A(g+1) (parity ~p) in phA: slot's readers were g-1's LDAQ, drained
//    per-wave by lgkm0 before their MFMAs, all waves past g-1's closing
//    barrier before any wave enters g's phA.
//  - STG B0/B1/B2(g+2) (parity p) ALL in phB: phA's LDBQ readers drained
//    per-wave (lgkm0 before MFMAs) and all waves past phA's closing barrier
//    before any wave issues the phB stages.
//  - vmcnt(6) at phB = the 3 newest stage-units = B*(g+2); everything older
//    (A(g+1) from phA, B*(g+1) from g-1 phB) complete => tile g+1 certified.
// Prologue identical to the verified round-6 kernel.
__global__ __launch_bounds__(512, 2) void gemm384_kernel(
    const unsigned short* __restrict__ A, const unsigned short* __restrict__ Bt,
    unsigned short* __restrict__ C, int M, int N, int K) {
    __shared__ __align__(16) unsigned short SH[65536];  // 128 KiB
    int tid = threadIdx.x;
    int lane = tid & 63, w = tid >> 6;
    int wr = w >> 2, wc = w & 3;
    int qd = lane >> 4, rc = lane & 15;

    int wg = blockIdx.x;                 // 512 = 8 xcd * (16 m * 4 nsub)
    int xcd = wg & 7, loc = wg >> 3;
    int m0 = (loc & 15) * 128;
    int n0 = (xcd * 4 + (loc >> 4)) * 384;

    const int NT = K >> 6;               // K-tiles
    const int sK = K << 7;               // u16 elems per 128-row half-tile

    size_t sr[2];
#pragma unroll
    for (int j = 0; j < 2; j++) {
        int bu = j * 4096 + tid * 8;     // u16 offset within half-tile
        int sub = bu >> 9;
        int b = bu & 511;
        int bp = b ^ (((b >> 8) & 1) << 4);
        int row = ((sub >> 1) << 4) + (bp >> 5);
        int col = ((sub & 1) << 5) + (bp & 31);
        sr[j] = (size_t)row * K + col;
    }
    const unsigned short* Ab = A + (size_t)m0 * K;
    const unsigned short* Bb = Bt + (size_t)n0 * K;

    const int foff = (rc * 32 + qd * 8) ^ (((rc >> 3) & 1) << 4);
    int bC[6];
#pragma unroll
    for (int fj = 0; fj < 6; fj++) {
        int nb = wc * 96 + fj * 16;
        bC[fj] = (1 + (nb >> 7)) * 16384 + ((nb & 127) >> 4) * 1024 + foff;
    }

    f32x4 acc[4][6];
#pragma unroll
    for (int i = 0; i < 4; i++)
#pragma unroll
        for (int j = 0; j < 6; j++)
#pragma unroll
            for (int r = 0; r < 4; r++) acc[i][j][r] = 0.f;

    bf16x8 aq[2][2], bq[6][2];

#define STG(u, t)                                                             \
    {                                                                         \
        const unsigned short* s_ =                                            \
            ((u) == 0 ? Ab : Bb + (size_t)((u)-1) * sK) + (size_t)(t) * 64;   \
        int d_ = (((u)*2 + ((t)&1)) << 13) + tid * 8;                         \
        gll16(s_ + sr[0], &SH[d_]);                                           \
        gll16(s_ + sr[1], &SH[d_ + 4096]);                                    \
    }

#define LDAQ(p, QR)                                                           \
    {                                                                         \
        _Pragma("unroll") for (int fi = 0; fi < 2; fi++)                      \
            _Pragma("unroll") for (int ks = 0; ks < 2; ks++)                  \
                aq[fi][ks] = *(const bf16x8*)&SH[(p)*8192 +                   \
                    (wr * 4 + (QR)*2 + fi) * 1024 + ks * 512 + foff];         \
    }

#define LDBQ(p)                                                               \
    {                                                                         \
        _Pragma("unroll") for (int fj = 0; fj < 6; fj++)                      \
            _Pragma("unroll") for (int ks = 0; ks < 2; ks++)                  \
                bq[fj][ks] = *(const bf16x8*)&SH[bC[fj] + (p)*8192 + ks*512]; \
    }

#define MFMAQ(QR, QC)                                                         \
    {                                                                         \
        _Pragma("unroll") for (int fi = 0; fi < 2; fi++)                      \
            _Pragma("unroll") for (int fj = 0; fj < 3; fj++)                  \
                _Pragma("unroll") for (int ks = 0; ks < 2; ks++)              \
                    acc[(QR)*2 + fi][(QC)*3 + fj] =                           \
                        __builtin_amdgcn_mfma_f32_16x16x32_bf16(              \
                            aq[fi][ks], bq[(QC)*3 + fj][ks],                  \
                            acc[(QR)*2 + fi][(QC)*3 + fj], 0, 0, 0);          \
    }

    // ---- prologue: tile0 full + B0,B1,B2 of tile1; 3 stages left in flight
    STG(0, 0); STG(1, 0); STG(2, 0); STG(3, 0);
    STG(1, 1); STG(2, 1); STG(3, 1);
    asm volatile("s_waitcnt vmcnt(6)" ::: "memory");
    BARRIER;

    for (int g = 0; g < NT; ++g) {
        const int p = g & 1;
        // phase A: quadrants (0,0)+(0,1)  [24 MFMA]
        LDAQ(p, 0);
        LDBQ(p);
        if (g + 1 < NT) STG(0, g + 1);
        BARRIER; LGKM0;
        __builtin_amdgcn_s_setprio(1);
        MFMAQ(0, 0);
        MFMAQ(0, 1);
        __builtin_amdgcn_s_setprio(0);
        BARRIER;
        // phase B: quadrants (1,0)+(1,1)  [24 MFMA] + all B(g+2) stages
        LDAQ(p, 1);
        if (g + 2 < NT) { STG(1, g + 2); STG(2, g + 2); STG(3, g + 2); }
        if (g < NT - 2) { asm volatile("s_waitcnt vmcnt(6)" ::: "memory"); }
        else            { asm volatile("s_waitcnt vmcnt(0)" ::: "memory"); }
        BARRIER; LGKM0;
        __builtin_amdgcn_s_setprio(1);
        MFMAQ(1, 0);
        MFMAQ(1, 1);
        __builtin_amdgcn_s_setprio(0);
        BARRIER;
    }

#undef STG
#undef LDAQ
#undef LDBQ
#undef MFMAQ

#pragma unroll
    for (int mi = 0; mi < 4; mi++) {
        int row = m0 + wr * 64 + mi * 16 + qd * 4;
#pragma unroll
        for (int fj = 0; fj < 6; fj++) {
            int col = n0 + wc * 96 + fj * 16 + rc;
#pragma unroll
            for (int r = 0; r < 4; r++)
                C[(size_t)(row + r) * N + col] = f2bf(acc[mi][fj][r]);
        }
    }
}

// ---------------- 256x256 merged-phase bf16 GEMM, split-K f32 partials -----
// Same merge: 2 phases/K-tile, 32 MFMA per barrier-pair. Stage plan:
// phA stages BOTH A halves of g+1 (parity ~p; readers drained at g-1 close);
// phB stages BOTH B halves of g+2 (parity p; phA's LDBQ drained before phB).
// vmcnt(4) = the 2 newest stage-units = B*(g+2); older (A*(g+1) from phA,
// B*(g+1) from g-1 phB) complete => tile g+1 certified.
// Prologue: tile0 (4 units) + B*(1) (2 units) = 12 loads; vmcnt(4).
__global__ __launch_bounds__(512, 2) void gemm256_kernel(
    const unsigned short* __restrict__ A, const unsigned short* __restrict__ Bt,
    float* __restrict__ C, int M, int N, int K, int Ksl) {
    __shared__ __align__(16) unsigned short SH[65536];  // 128 KiB
    int tid = threadIdx.x;
    int lane = tid & 63, w = tid >> 6;
    int wr = w >> 2, wc = w & 3;
    int qd = lane >> 4, rc = lane & 15;

    int wg = blockIdx.x;                 // 256 = 4 k-slices x 64 tiles
    int zz = wg >> 6;
    int loc = wg & 63;
    int m0 = (loc >> 3) * 256;
    int n0 = (loc & 7) * 256;
    const int NT = Ksl >> 6;
    const int sK = K << 7;

    size_t sr[2];
#pragma unroll
    for (int j = 0; j < 2; j++) {
        int bu = j * 4096 + tid * 8;
        int sub = bu >> 9;
        int b = bu & 511;
        int bp = b ^ (((b >> 8) & 1) << 4);
        int row = ((sub >> 1) << 4) + (bp >> 5);
        int col = ((sub & 1) << 5) + (bp & 31);
        sr[j] = (size_t)row * K + col;
    }
    const unsigned short* Ab = A + (size_t)m0 * K + (size_t)zz * Ksl;
    const unsigned short* Bb = Bt + (size_t)n0 * K + (size_t)zz * Ksl;

    const int foff = (rc * 32 + qd * 8) ^ (((rc >> 3) & 1) << 4);
    const int Ah = wr;
    const int Bh = wc >> 1;
    const int brow4 = (wc & 1) * 4;

    f32x4 acc[8][4];
#pragma unroll
    for (int i = 0; i < 8; i++)
#pragma unroll
        for (int j = 0; j < 4; j++)
#pragma unroll
            for (int r = 0; r < 4; r++) acc[i][j][r] = 0.f;

    bf16x8 aq[4][2], bq[4][2];

#define STG(mat, h, t)                                                        \
    {                                                                         \
        const unsigned short* s_ = ((mat) ? Bb : Ab) + (h) * sK + (t) * 64;   \
        int d_ = ((mat) << 15) + (((((t) & 1) * 2 + (h))) << 13) + tid * 8;   \
        gll16(s_ + sr[0], &SH[d_]);                                           \
        gll16(s_ + sr[1], &SH[d_ + 4096]);                                    \
    }

#define LDAQ(p, QR)                                                           \
    {                                                                         \
        int ab_ = ((p) * 2 + Ah) * 8192 + (QR) * 4096 + foff;                 \
        _Pragma("unroll") for (int fi = 0; fi < 4; fi++)                      \
            _Pragma("unroll") for (int ks = 0; ks < 2; ks++)                  \
                aq[fi][ks] = *(const bf16x8*)&SH[ab_ + (fi * 2 + ks) * 512];  \
    }

#define LDBQ(p)                                                               \
    {                                                                         \
        int bb_ = 32768 + ((p) * 2 + Bh) * 8192 + brow4 * 1024 + foff;        \
        _Pragma("unroll") for (int fg = 0; fg < 4; fg++)                      \
            _Pragma("unroll") for (int ks = 0; ks < 2; ks++)                  \
                bq[fg][ks] = *(const bf16x8*)&SH[bb_ + (fg * 2 + ks) * 512];  \
    }

#define MFMAQ(QR, QC)                                                         \
    {                                                                         \
        _Pragma("unroll") for (int fi = 0; fi < 4; fi++)                      \
            _Pragma("unroll") for (int fj = 0; fj < 2; fj++)                  \
                _Pragma("unroll") for (int ks = 0; ks < 2; ks++)              \
                    acc[(QR) * 4 + fi][(QC) * 2 + fj] =                       \
                        __builtin_amdgcn_mfma_f32_16x16x32_bf16(              \
                            aq[fi][ks], bq[(QC) * 2 + fj][ks],                \
                            acc[(QR) * 4 + fi][(QC) * 2 + fj], 0, 0, 0);      \
    }

    // prologue: tile0 A0,A1,B0,B1 + tile1 B0,B1; 2 stage-units in flight
    STG(0, 0, 0); STG(0, 1, 0); STG(1, 0, 0); STG(1, 1, 0);
    STG(1, 0, 1); STG(1, 1, 1);
    asm volatile("s_waitcnt vmcnt(4)" ::: "memory");
    BARRIER;

    for (int g = 0; g < NT; ++g) {
        const int p = g & 1;
        // phase A: quadrants (0,0)+(0,1)  [32 MFMA] + A*(g+1) stages
        LDAQ(p, 0);
        LDBQ(p);
        if (g + 1 < NT) { STG(0, 0, g + 1); STG(0, 1, g + 1); }
        BARRIER; LGKM0;
        __builtin_amdgcn_s_setprio(1);
        MFMAQ(0, 0);
        MFMAQ(0, 1);
        __builtin_amdgcn_s_setprio(0);
        BARRIER;
        // phase B: quadrants (1,0)+(1,1)  [32 MFMA] + B*(g+2) stages
        LDAQ(p, 1);
        if (g + 2 < NT) { STG(1, 0, g + 2); STG(1, 1, g + 2); }
        if (g < NT - 2) { asm volatile("s_waitcnt vmcnt(4)" ::: "memory"); }
        else            { asm volatile("s_waitcnt vmcnt(0)" ::: "memory"); }
        BARRIER; LGKM0;
        __builtin_amdgcn_s_setprio(1);
        MFMAQ(1, 0);
        MFMAQ(1, 1);
        __builtin_amdgcn_s_setprio(0);
        BARRIER;
    }

#undef STG
#undef LDAQ
#undef LDBQ
#undef MFMAQ

    float* Cf = C + (size_t)zz * M * N;
#pragma unroll
    for (int mi = 0; mi < 8; mi++) {
        int row = m0 + wr * 128 + mi * 16 + qd * 4;
#pragma unroll
        for (int fg = 0; fg < 4; fg++) {
            int col = n0 + wc * 64 + fg * 16 + rc;
#pragma unroll
            for (int r = 0; r < 4; r++)
                Cf[(size_t)(row + r) * N + col] = acc[mi][fg][r];
        }
    }
}

// ---------------- split-K partial sum: out = p[0]+p[1]+p[2]+p[3] ----------------
__global__ __launch_bounds__(256) void add_out4_kernel(
    const float* __restrict__ p, float* __restrict__ out, int n4) {
    int i = blockIdx.x * 256 + threadIdx.x;
    if (i >= n4) return;
    size_t st = (size_t)n4 * 4;
    float4 a = ((const float4*)p)[i];
    float4 b = ((const float4*)(p + st))[i];
    float4 c = ((const float4*)(p + 2 * st))[i];
    float4 d = ((const float4*)(p + 3 * st))[i];
    ((float4*)out)[i] = make_float4(a.x + b.x + c.x + d.x, a.y + b.y + c.y + d.y,
                                    a.z + b.z + c.z + d.z, a.w + b.w + c.w + d.w);
}

// ---------------- ba GEMM + beta/g computation (coalesced w_pk) ------------
__global__ __launch_bounds__(256) void bag_kernel(
    const float* __restrict__ hs, const float* __restrict__ w_pk,
    const float* __restrict__ A_log, const float* __restrict__ dt_bias,
    float* __restrict__ gg, float* __restrict__ bb) {
    __shared__ float ps[4][4][64];
    int tid = threadIdx.x;
    int col = tid & 63, kc = tid >> 6;
    int t0 = blockIdx.x * 4;
    const float4* wp = (const float4*)w_pk + (size_t)kc * 128 * 64 + col;
    const float4* h0 = (const float4*)(hs + (size_t)(t0 + 0) * 2048 + kc * 512);
    const float4* h1 = (const float4*)(hs + (size_t)(t0 + 1) * 2048 + kc * 512);
    const float4* h2 = (const float4*)(hs + (size_t)(t0 + 2) * 2048 + kc * 512);
    const float4* h3 = (const float4*)(hs + (size_t)(t0 + 3) * 2048 + kc * 512);
    float a0 = 0.f, a1 = 0.f, a2 = 0.f, a3 = 0.f;
#pragma unroll 4
    for (int i = 0; i < 128; i++) {
        float4 wv = wp[(size_t)i * 64];
        float4 x0 = h0[i];
        float4 x1 = h1[i];
        float4 x2 = h2[i];
        float4 x3 = h3[i];
        a0 += wv.x * x0.x + wv.y * x0.y + wv.z * x0.z + wv.w * x0.w;
        a1 += wv.x * x1.x + wv.y * x1.y + wv.z * x1.z + wv.w * x1.w;
        a2 += wv.x * x2.x + wv.y * x2.y + wv.z * x2.z + wv.w * x2.w;
        a3 += wv.x * x3.x + wv.y * x3.y + wv.z * x3.z + wv.w * x3.w;
    }
    ps[kc][0][col] = a0;
    ps[kc][1][col] = a1;
    ps[kc][2][col] = a2;
    ps[kc][3][col] = a3;
    __syncthreads();
    {
        int j = tid >> 6, c = tid & 63;
        float acc = ps[0][j][c] + ps[1][j][c] + ps[2][j][c] + ps[3][j][c];
        int t = t0 + j;
        int h = c >> 2, idx = c & 3;
        int vh = h * 2 + (idx & 1);
        if (idx < 2) {
            bb[t * 32 + vh] = 1.f / (1.f + expf(-acc));
        } else {
            float x = acc + dt_bias[vh];
            float sp = fmaxf(x, 0.f) + log1pf(expf(-fabsf(x)));
            gg[t * 32 + vh] = -expf(A_log[vh]) * sp;
        }
    }
}

// ---------------- depthwise causal conv(4) + silu + l2norm(q,k) ----------------
__global__ __launch_bounds__(256) void conv_kernel(
    const unsigned short* __restrict__ qkvz, const float* __restrict__ conv_w,
    unsigned short* __restrict__ qb, unsigned short* __restrict__ kb,
    float* __restrict__ vv) {
    __shared__ float xs[8192];
    __shared__ float rs[32];
    int t = ((blockIdx.x & 7) << 8) + (blockIdx.x >> 3);  // XCD-chunked
    int s = t & 1023;
    int tid = threadIdx.x;
    size_t rowbase = (size_t)t * 12288;
#pragma unroll
    for (int i = 0; i < 4; i++) {
        int c = (i * 256 + tid) * 8;
        int d = c & 127;
        int col;
        if (c < 2048) col = (c >> 7) * 768 + d;
        else if (c < 4096) col = ((c - 2048) >> 7) * 768 + 128 + d;
        else { int vh2 = (c - 4096) >> 7; col = (vh2 >> 1) * 768 + 256 + (vh2 & 1) * 128 + d; }
        float wts[8][4];
#pragma unroll
        for (int e = 0; e < 8; e++) {
            float4 t4 = *(const float4*)(conv_w + (size_t)(c + e) * 4);
            wts[e][0] = t4.x; wts[e][1] = t4.y; wts[e][2] = t4.z; wts[e][3] = t4.w;
        }
        float acc[8] = {0.f, 0.f, 0.f, 0.f, 0.f, 0.f, 0.f, 0.f};
#pragma unroll
        for (int j = 0; j < 4; j++) {
            int ss = s - 3 + j;
            if (ss >= 0) {
                uint4 u = *(const uint4*)(qkvz + rowbase + (size_t)(j - 3) * 12288 + col);
                const unsigned short* us = (const unsigned short*)&u;
#pragma unroll
                for (int e = 0; e < 8; e++) acc[e] += bf2f(us[e]) * wts[e][j];
            }
        }
#pragma unroll
        for (int e = 0; e < 8; e++) xs[c + e] = acc[e] / (1.f + expf(-acc[e]));
    }
    __syncthreads();
    {
        int seg = tid >> 3, part = tid & 7;
        const float* pp = xs + seg * 128 + part * 16;
        float s2 = 0.f;
#pragma unroll
        for (int j = 0; j < 16; j++) s2 += pp[j] * pp[j];
        s2 += __shfl_xor(s2, 1);
        s2 += __shfl_xor(s2, 2);
        s2 += __shfl_xor(s2, 4);
        if (part == 0) rs[seg] = rsqrtf(s2 + 1e-6f);
    }
    __syncthreads();
    const float QS = 0.08838834764831845f;  // 128^-0.5
#pragma unroll
    for (int i = 0; i < 4; i++) {
        int c = (i * 256 + tid) * 8;
        float x[8];
#pragma unroll
        for (int e = 0; e < 8; e++) x[e] = xs[c + e];
        if (c < 4096) {
            float sc = (c < 2048) ? rs[c >> 7] * QS : rs[((c - 2048) >> 7) + 16];
            uint4 o;
            o.x = (unsigned)f2bf(x[0] * sc) | ((unsigned)f2bf(x[1] * sc) << 16);
            o.y = (unsigned)f2bf(x[2] * sc) | ((unsigned)f2bf(x[3] * sc) << 16);
            o.z = (unsigned)f2bf(x[4] * sc) | ((unsigned)f2bf(x[5] * sc) << 16);
            o.w = (unsigned)f2bf(x[6] * sc) | ((unsigned)f2bf(x[7] * sc) << 16);
            if (c < 2048) *(uint4*)(qb + (size_t)t * 2048 + c) = o;
            else *(uint4*)(kb + (size_t)t * 2048 + c - 2048) = o;
        } else {
            float* vp = vv + (size_t)t * 4096 + c - 4096;
            *(float4*)vp = make_float4(x[0], x[1], x[2], x[3]);
            *(float4*)(vp + 4) = make_float4(x[4], x[5], x[6], x[7]);
        }
    }
}

// ---------------- delta-rule prep (parallel over 64 bh x 16 chunks) ----------------
__global__ __launch_bounds__(256, 2) void prep_kernel(
    const unsigned short* __restrict__ qb, const unsigned short* __restrict__ kb,
    const float* __restrict__ vv, const float* __restrict__ gg,
    const float* __restrict__ bb,
    unsigned short* __restrict__ Wg, unsigned short* __restrict__ DlT,
    unsigned short* __restrict__ KtT, unsigned short* __restrict__ Pt,
    float* __restrict__ lamg, float* __restrict__ l64g) {
    __shared__ __align__(16) unsigned short Tb[64 * 72];    // -beta_i E_ij A_ij (i>j)
    __shared__ __align__(16) unsigned short Xw[4][64 * 72]; // per-wave solutions [col][tok]
    __shared__ float Td[4 * 16 * 17];                       // +T diag blocks fp32
    __shared__ float RHSw[4][16 * 68];                      // per-wave stage scratch
    __shared__ float cc[64], bet[64], lam_s[64], ex64[64];

    int bid = blockIdx.x;            // bh*16 + ch
    int ch = bid & 15, bh = bid >> 4;
    int vh = bh & 31, b = bh >> 5;
    int hk = vh >> 1;
    int t0 = b * 1024 + ch * 64;
    int tid = threadIdx.x, wv = tid >> 6, lane = tid & 63;
    int qd = lane >> 4, rc = lane & 15;
    int rowb = (wv & 1) * 32;
    size_t obase = (size_t)bid * 8192;
    size_t pbase = (size_t)bid * 4096;

    // decay metadata (wave 0)
    if (tid < 64) {
        float x = gg[(size_t)(t0 + tid) * 32 + vh];
#pragma unroll
        for (int ofs = 1; ofs < 64; ofs <<= 1) {
            float up = __shfl_up(x, ofs, 64);
            if (tid >= ofs) x += up;
        }
        cc[tid] = x;
        float l = __expf(x);
        lam_s[tid] = l;
        float tot = __shfl(x, 63, 64);
        ex64[tid] = __expf(tot - x);
        bet[tid] = bb[(size_t)(t0 + tid) * 32 + vh];
        lamg[(size_t)bid * 64 + tid] = l;
        if (tid == 0) l64g[bid] = __expf(tot);
    }
    __syncthreads();

    // phase A: A = K K^T (waves 0,1) -> Tb/Td ; P = Q K^T (waves 2,3) -> Pt
    {
        const unsigned short* src = (wv >= 2) ? qb : kb;
        f32x4 acc[2][4];
#pragma unroll
        for (int tm = 0; tm < 2; tm++)
#pragma unroll
            for (int tn = 0; tn < 4; tn++)
#pragma unroll
                for (int r = 0; r < 4; r++) acc[tm][tn][r] = 0.f;
#pragma unroll
        for (int ks = 0; ks < 4; ks++) {
            bf16x8 af[2], bfr[4];
#pragma unroll
            for (int tm = 0; tm < 2; tm++) {
                int row = rowb + tm * 16 + rc;
                af[tm] = *(const bf16x8*)(src + ((size_t)(t0 + row) * 16 + hk) * 128 + ks * 32 + qd * 8);
            }
#pragma unroll
            for (int tn = 0; tn < 4; tn++)
                bfr[tn] = *(const bf16x8*)(kb + ((size_t)(t0 + tn * 16 + rc) * 16 + hk) * 128 + ks * 32 + qd * 8);
#pragma unroll
            for (int tm = 0; tm < 2; tm++)
#pragma unroll
                for (int tn = 0; tn < 4; tn++)
                    acc[tm][tn] = __builtin_amdgcn_mfma_f32_16x16x32_bf16(af[tm], bfr[tn], acc[tm][tn], 0, 0, 0);
        }
        if (wv < 2) {
#pragma unroll
            for (int tm = 0; tm < 2; tm++)
#pragma unroll
                for (int tn = 0; tn < 4; tn++)
#pragma unroll
                    for (int r = 0; r < 4; r++) {
                        int i = rowb + tm * 16 + qd * 4 + r;
                        int j = tn * 16 + rc;
                        float val = acc[tm][tn][r];
                        float tv = 0.f;
                        if (i > j) tv = bet[i] * __expf(cc[i] - cc[j]) * val;
                        Tb[i * 72 + j] = f2bf(-tv);
                        if ((i >> 4) == (j >> 4) && i > j)
                            Td[(i >> 4) * 272 + (i & 15) * 17 + (j & 15)] = tv;
                    }
        } else {
#pragma unroll
            for (int tm = 0; tm < 2; tm++)
#pragma unroll
                for (int tn = 0; tn < 4; tn++)
#pragma unroll
                    for (int r = 0; r < 4; r++) {
                        int i = rowb + tm * 16 + qd * 4 + r;
                        int j = tn * 16 + rc;
                        float ev = (i >= j) ? __expf(cc[i] - cc[j]) : 0.f;
                        Pt[pbase + i * 64 + j] = f2bf(ev * acc[tm][tn][r]);
                    }
        }
    }
    // KtT: Etil-folded K^T [dk][tok] straight from global (L2-hot)
    {
        int dk = tid >> 1, half = tid & 1;
#pragma unroll
        for (int j = 0; j < 4; j++) {
            unsigned short tmp[8];
#pragma unroll
            for (int e = 0; e < 8; e++) {
                int tok = half * 32 + j * 8 + e;
                tmp[e] = f2bf(bf2f(kb[((size_t)(t0 + tok) * 16 + hk) * 128 + dk]) * ex64[tok]);
            }
            *(uint4*)(KtT + obase + dk * 64 + half * 32 + j * 8) = *(const uint4*)tmp;
        }
    }
    __syncthreads();   // Tb/Td ready for all waves

    // per-wave forward substitution: wave wv owns col-batch cb = wv (64 cols)
    {
        int cb = wv;
        unsigned short* Xb = Xw[wv];
        float* RHS = RHSw[wv];
        for (int z = lane; z < 64 * 72 / 2; z += 64) ((unsigned int*)Xb)[z] = 0u;
#pragma unroll
        for (int B = 0; B < 4; B++) {
            f32x4 tacc[4];
#pragma unroll
            for (int cf = 0; cf < 4; cf++)
#pragma unroll
                for (int r = 0; r < 4; r++) {
                    int i = B * 16 + qd * 4 + r;
                    int c = cf * 16 + rc;
                    float v;
                    if (cb < 2)
                        v = bet[i] * vv[((size_t)(t0 + i) * 32 + vh) * 128 + cb * 64 + c];
                    else
                        v = bet[i] * lam_s[i] * bf2f(kb[((size_t)(t0 + i) * 16 + hk) * 128 + (cb - 2) * 64 + c]);
                    tacc[cf][r] = v;
                }
            __builtin_amdgcn_s_waitcnt(0xc07f);  // prior Xb writes (same wave) visible
            const int nks = (B + 1) >> 1;  // 0,1,1,2
#pragma unroll
            for (int ks = 0; ks < 2; ks++) {
                if (ks >= nks) break;
                bf16x8 af = *(const bf16x8*)&Tb[(B * 16 + rc) * 72 + ks * 32 + qd * 8];
#pragma unroll
                for (int cf = 0; cf < 4; cf++) {
                    bf16x8 bf_ = *(const bf16x8*)&Xb[(cf * 16 + rc) * 72 + ks * 32 + qd * 8];
                    tacc[cf] = __builtin_amdgcn_mfma_f32_16x16x32_bf16(af, bf_, tacc[cf], 0, 0, 0);
                }
            }
#pragma unroll
            for (int cf = 0; cf < 4; cf++)
#pragma unroll
                for (int r = 0; r < 4; r++)
                    RHS[(qd * 4 + r) * 68 + cf * 16 + rc] = tacc[cf][r];
            __builtin_amdgcn_s_waitcnt(0xc07f);  // RHS visible for transposed read
            {
                float d[16];
#pragma unroll
                for (int i2 = 0; i2 < 16; i2++) d[i2] = RHS[i2 * 68 + lane];
#pragma unroll
                for (int i2 = 1; i2 < 16; i2++)
#pragma unroll
                    for (int j2 = 0; j2 < i2; j2++)
                        d[i2] -= Td[B * 272 + i2 * 17 + j2] * d[j2];
#pragma unroll
                for (int i2 = 0; i2 < 16; i2++)
                    Xb[lane * 72 + B * 16 + i2] = f2bf(d[i2]);
            }
        }
        __builtin_amdgcn_s_waitcnt(0xc07f);
        // write out this wave's batch
        if (cb < 2) {  // Dloc^T rows [dv = cb*64+lane][tok]
#pragma unroll
            for (int j = 0; j < 8; j++) {
                uint4 u = *(const uint4*)&Xb[lane * 72 + j * 8];
                *(uint4*)(DlT + obase + (size_t)(cb * 64 + lane) * 64 + j * 8) = u;
            }
        } else {  // W rows [tok = lane][dk]: transpose from Xb
#pragma unroll
            for (int dq = 0; dq < 8; dq++) {
                unsigned short tmp[8];
#pragma unroll
                for (int e = 0; e < 8; e++)
                    tmp[e] = Xb[(dq * 8 + e) * 72 + lane];
                *(uint4*)(Wg + obase + (size_t)lane * 128 + (cb - 2) * 64 + dq * 8) = *(const uint4*)tmp;
            }
        }
    }
}

// ---------------- serial inter-chunk scan (lean) ----------------
__global__ __launch_bounds__(256, 2) void recb_kernel(
    const unsigned short* __restrict__ qb, const float* __restrict__ lamg,
    const float* __restrict__ l64g, const unsigned short* __restrict__ Wg,
    const unsigned short* __restrict__ DlT, const unsigned short* __restrict__ KtT,
    const unsigned short* __restrict__ Pt, float* __restrict__ oo) {
    __shared__ __align__(16) unsigned short St[16 * 136];  // S^T bf16 [dv][dk]
    __shared__ __align__(16) unsigned short Dls[16 * 72];  // Dloc^T -> D'^T slice
    int bid = blockIdx.x;
    int slice = bid >> 6;           // slice-major: same head -> same XCD
    int rest = bid & 63;
    int vh = rest & 31, b = rest >> 5;
    int bh = b * 32 + vh;
    int hk = vh >> 1, dvo = slice * 16, tb = b * 1024;
    int tid = threadIdx.x, wv = tid >> 6, lane = tid & 63;
    int qd = lane >> 4, rc = lane & 15;

    f32x4 sacc[2];
#pragma unroll
    for (int tm = 0; tm < 2; tm++)
#pragma unroll
        for (int r = 0; r < 4; r++) sacc[tm][r] = 0.f;
    for (int z = tid; z < 16 * 136 / 2; z += 256) ((unsigned int*)St)[z] = 0u;
    __syncthreads();

#pragma unroll 1
    for (int ch = 0; ch < 16; ch++) {
        int bhch = bh * 16 + ch;
        size_t obase = (size_t)bhch * 8192;
        size_t pbase = (size_t)bhch * 4096;
        int t0 = tb + ch * 64;
        if (tid < 128) {
            int row = tid >> 3, t8 = (tid & 7) * 8;
            uint4 u = *(const uint4*)(DlT + obase + (dvo + row) * 64 + t8);
            *(uint4*)&Dls[row * 72 + t8] = u;
        }
        __syncthreads();
        {
            f32x4 uacc;
#pragma unroll
            for (int r = 0; r < 4; r++) uacc[r] = 0.f;
#pragma unroll
            for (int ks = 0; ks < 4; ks++) {
                bf16x8 a_ = *(const bf16x8*)&St[rc * 136 + ks * 32 + qd * 8];
                bf16x8 b_ = *(const bf16x8*)(Wg + obase + (size_t)(wv * 16 + rc) * 128 + ks * 32 + qd * 8);
                uacc = __builtin_amdgcn_mfma_f32_16x16x32_bf16(a_, b_, uacc, 0, 0, 0);
            }
#pragma unroll
            for (int r = 0; r < 4; r++) {
                int idx = (qd * 4 + r) * 72 + wv * 16 + rc;
                Dls[idx] = f2bf(bf2f(Dls[idx]) - uacc[r]);
            }
        }
        __syncthreads();
        {
            f32x4 qacc;
#pragma unroll
            for (int r = 0; r < 4; r++) qacc[r] = 0.f;
#pragma unroll
            for (int ks = 0; ks < 4; ks++) {
                bf16x8 a_ = *(const bf16x8*)(qb + ((size_t)(t0 + wv * 16 + rc) * 16 + hk) * 128 + ks * 32 + qd * 8);
                bf16x8 b_ = *(const bf16x8*)&St[rc * 136 + ks * 32 + qd * 8];
                qacc = __builtin_amdgcn_mfma_f32_16x16x32_bf16(a_, b_, qacc, 0, 0, 0);
            }
            bf16x8 bd[2];
#pragma unroll
            for (int ks = 0; ks < 2; ks++)
                bd[ks] = *(const bf16x8*)&Dls[rc * 72 + ks * 32 + qd * 8];
            f32x4 oacc;
#pragma unroll
            for (int r = 0; r < 4; r++)
                oacc[r] = lamg[(size_t)bhch * 64 + wv * 16 + qd * 4 + r] * qacc[r];
#pragma unroll
            for (int ks = 0; ks < 2; ks++) {
                bf16x8 a_ = *(const bf16x8*)(Pt + pbase + (size_t)(wv * 16 + rc) * 64 + ks * 32 + qd * 8);
                oacc = __builtin_amdgcn_mfma_f32_16x16x32_bf16(a_, bd[ks], oacc, 0, 0, 0);
            }
#pragma unroll
            for (int r = 0; r < 4; r++)
                oo[((size_t)(t0 + wv * 16 + qd * 4 + r) * 32 + vh) * 128 + dvo + rc] = oacc[r];
            float l64 = l64g[bhch];
#pragma unroll
            for (int tm = 0; tm < 2; tm++) {
#pragma unroll
                for (int r = 0; r < 4; r++) sacc[tm][r] *= l64;
#pragma unroll
                for (int ks = 0; ks < 2; ks++) {
                    bf16x8 a_ = *(const bf16x8*)(KtT + obase + (size_t)(wv * 32 + tm * 16 + rc) * 64 + ks * 32 + qd * 8);
                    sacc[tm] = __builtin_amdgcn_mfma_f32_16x16x32_bf16(a_, bd[ks], sacc[tm], 0, 0, 0);
                }
            }
        }
        __syncthreads();
#pragma unroll
        for (int tm = 0; tm < 2; tm++)
#pragma unroll
            for (int r = 0; r < 4; r++)
                St[rc * 136 + wv * 32 + tm * 16 + qd * 4 + r] = f2bf(sacc[tm][r]);
        __syncthreads();
    }
}

// ---------------- gated RMSNorm + bf16 convert ----------------
__global__ __launch_bounds__(256) void norm_kernel(
    const float* __restrict__ oo, const unsigned short* __restrict__ qkvz,
    const float* __restrict__ norm_w, unsigned short* __restrict__ yb) {
    int w = threadIdx.x >> 6, lane = threadIdx.x & 63;
    int g = blockIdx.x * 4 + w;
    int t = g >> 5, vh = g & 31;
    size_t ob = (size_t)g * 128;
    size_t zb = (size_t)t * 12288 + (size_t)(vh >> 1) * 768 + 512 + (vh & 1) * 128;
    float x0 = oo[ob + lane], x1 = oo[ob + 64 + lane];
    float z0 = bf2f(qkvz[zb + lane]), z1 = bf2f(qkvz[zb + 64 + lane]);
    float xg0 = x0 * (z0 / (1.f + expf(-z0)));
    float xg1 = x1 * (z1 / (1.f + expf(-z1)));
    float s = xg0 * xg0 + xg1 * xg1;
    s += __shfl_xor(s, 1);
    s += __shfl_xor(s, 2);
    s += __shfl_xor(s, 4);
    s += __shfl_xor(s, 8);
    s += __shfl_xor(s, 16);
    s += __shfl_xor(s, 32);
    float r = rsqrtf(s * (1.f / 128.f) + 1e-6f);
    size_t y0 = (size_t)t * 4096 + (size_t)vh * 128;
    yb[y0 + lane] = f2bf(xg0 * r * norm_w[lane]);
    yb[y0 + 64 + lane] = f2bf(xg1 * r * norm_w[64 + lane]);
}

extern "C" void kernel_launch(void* const* d_in, const int* in_sizes, int n_in,
                              void* d_out, int out_size, void* d_ws, size_t ws_size,
                              hipStream_t stream) {
    const float* hs      = (const float*)d_in[0];
    const float* w_qkvz  = (const float*)d_in[1];
    const float* w_ba    = (const float*)d_in[2];
    const float* conv_w  = (const float*)d_in[3];
    const float* dt_bias = (const float*)d_in[4];
    const float* A_log   = (const float*)d_in[5];
    const float* norm_w  = (const float*)d_in[6];
    const float* w_out   = (const float*)d_in[7];
    float* out = (float*)d_out;
    (void)in_sizes; (void)n_in; (void)out_size; (void)ws_size;

    char* p = (char*)d_ws;
    auto alloc = [&](size_t b) { char* r = p; p += (b + 255) & ~(size_t)255; return r; };
    float* gg = (float*)alloc(2048ull * 32 * 4);                         // log-decay
    float* bb = (float*)alloc(2048ull * 32 * 4);                         // beta
    float* w_pk = (float*)alloc(64ull * 2048 * 4);                       // w_ba packed
    unsigned short* hsb  = (unsigned short*)alloc(2048ull * 2048 * 2);   // hs bf16
    unsigned short* woT  = (unsigned short*)alloc(2048ull * 4096 * 2);   // w_out^T bf16
    unsigned short* wqT  = (unsigned short*)alloc(12288ull * 2048 * 2);  // w_qkvz^T bf16
    unsigned short* qkvz = (unsigned short*)alloc(2048ull * 12288 * 2);  // projections bf16
    unsigned short* qb16 = (unsigned short*)alloc(2048ull * 2048 * 2);   // q normed bf16
    unsigned short* kb16 = (unsigned short*)alloc(2048ull * 2048 * 2);   // k normed bf16
    float* vv = (float*)alloc(2048ull * 4096 * 4);                       // v fp32
    float* oo = (float*)alloc(2048ull * 4096 * 4);                       // recurrence out
    unsigned short* yb = (unsigned short*)alloc(2048ull * 4096 * 2);     // normed bf16
    unsigned short* Wg  = (unsigned short*)alloc(1024ull * 8192 * 2);    // W [bhch][64][128]
    unsigned short* DlT = (unsigned short*)alloc(1024ull * 8192 * 2);    // Dloc^T [bhch][128][64]
    unsigned short* KtT = (unsigned short*)alloc(1024ull * 8192 * 2);    // Ktil^T [bhch][128][64]
    unsigned short* Pt  = (unsigned short*)alloc(1024ull * 4096 * 2);    // Ptil [bhch][64][64]
    float* lamg = (float*)alloc(1024ull * 64 * 4);                       // lambda per token
    float* l64g = (float*)alloc(1024ull * 4);                            // chunk decay
    // gemm2 split-K-4 partials (67.1 MB) reuse wqT (48 MB, dead after gemm1)
    // + head of qkvz (dead after norm_kernel) — contiguous since woT precedes.
    float* gpart = (float*)wqT;

    cvt_bf16_kernel<<<4096, 256, 0, stream>>>(hs, hsb, 2048 * 2048 / 4);
    transpose_cvt_kernel<<<dim3(12288 / 32, 2048 / 32), 256, 0, stream>>>(w_qkvz, wqT, 2048, 12288);
    transpose_cvt_kernel<<<dim3(2048 / 32, 4096 / 32), 256, 0, stream>>>(w_out, woT, 4096, 2048);
    pack_wba_kernel<<<128, 256, 0, stream>>>(w_ba, w_pk);
    gemm384_kernel<<<512, 512, 0, stream>>>(hsb, wqT, qkvz, 2048, 12288, 2048);
    bag_kernel<<<512, 256, 0, stream>>>(hs, w_pk, A_log, dt_bias, gg, bb);
    conv_kernel<<<2048, 256, 0, stream>>>(qkvz, conv_w, qb16, kb16, vv);
    prep_kernel<<<1024, 256, 0, stream>>>(qb16, kb16, vv, gg, bb, Wg, DlT, KtT, Pt, lamg, l64g);
    recb_kernel<<<512, 256, 0, stream>>>(qb16, lamg, l64g, Wg, DlT, KtT, Pt, oo);
    norm_kernel<<<16384, 256, 0, stream>>>(oo, qkvz, norm_w, yb);
    gemm256_kernel<<<256, 512, 0, stream>>>(yb, woT, gpart, 2048, 2048, 4096, 1024);
    add_out4_kernel<<<4096, 256, 0, stream>>>(gpart, out, 2048 * 2048 / 4);
}